// Round 6
// baseline (12267.452 us; speedup 1.0000x reference)
//
#include <hip/hip_runtime.h>
#include <math.h>

// EBT_GRC beam-search forward, round 6: dispatch-count reduction.
// Content kept in fp16x2 split form; 5 kernels/iteration (was 9); score
// GEMM+reduce fused; gathers fused into GEMM A-staging via row indices.
// N=256, S=32, D=512, CH=2048, BEAM=5. WS ~207 MB.

#define NN   256
#define S0   32
#define WDIM 512
#define DD   512
#define CHID 2048
#define BEAM 5
#define NB   (NN*BEAM)   // 1280
#define RSCALE 2048.0f   // residual scale 2^11
#define RINV  (1.0f/2048.0f)

typedef __attribute__((ext_vector_type(8))) _Float16 f16x8;
typedef __attribute__((ext_vector_type(4))) _Float16 f16x4v;
typedef __attribute__((ext_vector_type(4))) float f32x4;

__device__ __forceinline__ float gelu_f(float x) {
    return 0.5f * x * (1.0f + erff(x * 0.7071067811865475f));
}
__device__ __forceinline__ _Float16 hi16(float v) { return (_Float16)v; }
__device__ __forceinline__ _Float16 lo16(float v, _Float16 h) {
    return (_Float16)((v - (float)h) * RSCALE);
}
__device__ __forceinline__ float recon(_Float16 h, _Float16 l) {
    return (float)h + RINV * (float)l;
}

__device__ __forceinline__ void gload_lds16(const void* g, void* l) {
    __builtin_amdgcn_global_load_lds(
        (const __attribute__((address_space(1))) unsigned*)g,
        (__attribute__((address_space(3))) unsigned*)l, 16, 0, 0);
}

__device__ __forceinline__ float block_reduce_sum(float v, float* sb) {
    #pragma unroll
    for (int o = 32; o > 0; o >>= 1) v += __shfl_down(v, o);
    const int lane = threadIdx.x & 63, wid = threadIdx.x >> 6;
    __syncthreads();
    if (lane == 0) sb[wid] = v;
    __syncthreads();
    return sb[0] + sb[1] + sb[2] + sb[3];
}

// ================= fp16x2 scaled-split MFMA GEMM =================
// A = Ah + RINV*Al (M x K fp16). B^T = Bh + RINV*Bl (N x K fp16).
// OUTMODE 0: fp32 store. 1: gelu -> fp16 h/l store.
// AIDX 1: A row m read at Ah[rowidx[m]*512 + k] (content rows; K must be 1024).
template<int OUTMODE, int AIDX>
__global__ __launch_bounds__(256, 1) void k_mfma_gemm(
    const _Float16* __restrict__ Ah, const _Float16* __restrict__ Al,
    const _Float16* __restrict__ Bh, const _Float16* __restrict__ Bl,
    const float* __restrict__ bias, float* __restrict__ Cf,
    _Float16* __restrict__ Oh, _Float16* __restrict__ Ol,
    const int* __restrict__ rowidx,
    int M, int N, int K)
{
    __shared__ __align__(16) _Float16 lds[4 * 4096]; // Ah,Al,Bh,Bl tiles [128][32]
    const int t = threadIdx.x, wave = t >> 6, lane = t & 63;
    const int bm = blockIdx.y * 128, bn = blockIdx.x * 128;
    const int wm = (wave >> 1) * 64, wn = (wave & 1) * 64;
    const int rsub = lane >> 2, seg = lane & 3;
    const int fm = lane & 15, fko = (lane >> 4) * 8;

    size_t abase[2];
    #pragma unroll
    for (int j = 0; j < 2; ++j) {
        const int q = wave * 2 + j;
        const int rowm = bm + q*16 + rsub;
        abase[j] = AIDX ? (size_t)rowidx[rowm] * 512
                        : (size_t)rowm * K;
    }

    f32x4 acc0[4][4], acc1[4][4];
    #pragma unroll
    for (int i = 0; i < 4; ++i)
        #pragma unroll
        for (int j = 0; j < 4; ++j) {
            acc0[i][j] = (f32x4){0.f, 0.f, 0.f, 0.f};
            acc1[i][j] = (f32x4){0.f, 0.f, 0.f, 0.f};
        }

    for (int k0 = 0; k0 < K; k0 += 32) {
        __syncthreads();
        #pragma unroll
        for (int j = 0; j < 2; ++j) {
            const int q = wave * 2 + j;
            const size_t aoff = abase[j] + k0 + seg * 8;
            const size_t boff = (size_t)(bn + q*16 + rsub) * K + k0 + seg * 8;
            gload_lds16(Ah + aoff, &lds[0*4096 + q*512]);
            gload_lds16(Al + aoff, &lds[1*4096 + q*512]);
            gload_lds16(Bh + boff, &lds[2*4096 + q*512]);
            gload_lds16(Bl + boff, &lds[3*4096 + q*512]);
        }
        __syncthreads();
        f16x8 ah[4], al[4];
        #pragma unroll
        for (int i = 0; i < 4; ++i) {
            const int ar = wm + i*16 + fm;
            ah[i] = *(const f16x8*)&lds[0*4096 + ar*32 + fko];
            al[i] = *(const f16x8*)&lds[1*4096 + ar*32 + fko];
        }
        #pragma unroll
        for (int j = 0; j < 4; ++j) {
            const int br = wn + j*16 + fm;
            f16x8 bh = *(const f16x8*)&lds[2*4096 + br*32 + fko];
            f16x8 bl = *(const f16x8*)&lds[3*4096 + br*32 + fko];
            #pragma unroll
            for (int i = 0; i < 4; ++i) {
                acc0[i][j] = __builtin_amdgcn_mfma_f32_16x16x32_f16(ah[i], bh, acc0[i][j], 0, 0, 0);
                acc1[i][j] = __builtin_amdgcn_mfma_f32_16x16x32_f16(ah[i], bl, acc1[i][j], 0, 0, 0);
                acc1[i][j] = __builtin_amdgcn_mfma_f32_16x16x32_f16(al[i], bh, acc1[i][j], 0, 0, 0);
            }
        }
    }
    // epilogue: C/D layout col=lane&15, row=(lane>>4)*4+reg
    #pragma unroll
    for (int i = 0; i < 4; ++i)
        #pragma unroll
        for (int j = 0; j < 4; ++j) {
            const int col = bn + wn + j*16 + fm;
            const float bv = bias[col];
            #pragma unroll
            for (int r = 0; r < 4; ++r) {
                const int row = bm + wm + i*16 + (lane >> 4)*4 + r;
                float v = acc0[i][j][r] + acc1[i][j][r] * RINV + bv;
                if (OUTMODE == 0) {
                    Cf[(size_t)row * N + col] = v;
                } else {
                    v = gelu_f(v);
                    _Float16 h = hi16(v);
                    Oh[(size_t)row * N + col] = h;
                    Ol[(size_t)row * N + col] = lo16(v, h);
                }
            }
        }
}

// ============ fused score: w = gelu(cat@Wd1 + bd1)@Wd2 + bd2 ============
// MODE 0 (init): row r -> n=r/31, s=r%31; content row n*ST+s; wi=n*BEAM*32+s.
// MODE 1 (incr): r -> nk=r>>1, jw=posb[nk]-1+(r&1); valid 0<=jw<Spairs.
// bn-loop over N=512; per-lane partials; shfl + 2-way LDS-atomic reduce
// (2-operand float add is commutative => deterministic).
template<int MODE>
__global__ __launch_bounds__(256, 1) void k_wscore(
    const _Float16* __restrict__ ch, const _Float16* __restrict__ cl,
    const int* __restrict__ posb,
    const _Float16* __restrict__ Bh, const _Float16* __restrict__ Bl,
    const float* __restrict__ bd1, const float* __restrict__ u512,
    const float* __restrict__ bd2, float* __restrict__ w,
    int Spairs, int ST)
{
    __shared__ __align__(16) _Float16 lds[4 * 4096];
    __shared__ float wsum[128];
    const int t = threadIdx.x, wave = t >> 6, lane = t & 63;
    const int bm = blockIdx.x * 128;
    const int wm = (wave >> 1) * 64, wn = (wave & 1) * 64;
    const int rsub = lane >> 2, seg = lane & 3;
    const int fm = lane & 15, quad = lane >> 4, fko = quad * 8;
    if (t < 128) wsum[t] = 0.f;

    size_t abase[2];
    #pragma unroll
    for (int j = 0; j < 2; ++j) {
        const int q = wave * 2 + j;
        const int rowm = bm + q*16 + rsub;
        int crow;
        if (MODE == 0) {
            const int n = rowm / 31, s = rowm - n * 31;
            crow = n * ST + s;
        } else {
            const int nk = rowm >> 1, slot = rowm & 1;
            const int s = posb[nk];
            int jw = s - 1 + slot;
            int jc = jw < 0 ? 0 : (jw > Spairs - 1 ? Spairs - 1 : jw);
            crow = nk * ST + jc;
        }
        abase[j] = (size_t)crow * 512;
    }

    float part[16];
    #pragma unroll
    for (int i = 0; i < 16; ++i) part[i] = 0.f;

    for (int bn = 0; bn < 4; ++bn) {
        f32x4 acc0[4][4], acc1[4][4];
        #pragma unroll
        for (int i = 0; i < 4; ++i)
            #pragma unroll
            for (int j = 0; j < 4; ++j) {
                acc0[i][j] = (f32x4){0.f, 0.f, 0.f, 0.f};
                acc1[i][j] = (f32x4){0.f, 0.f, 0.f, 0.f};
            }
        for (int k0 = 0; k0 < 1024; k0 += 32) {
            __syncthreads();
            #pragma unroll
            for (int j = 0; j < 2; ++j) {
                const int q = wave * 2 + j;
                const size_t aoff = abase[j] + k0 + seg * 8;
                const size_t boff = (size_t)(bn*128 + q*16 + rsub) * 1024 + k0 + seg * 8;
                gload_lds16(ch + aoff, &lds[0*4096 + q*512]);
                gload_lds16(cl + aoff, &lds[1*4096 + q*512]);
                gload_lds16(Bh + boff, &lds[2*4096 + q*512]);
                gload_lds16(Bl + boff, &lds[3*4096 + q*512]);
            }
            __syncthreads();
            f16x8 ah[4], al[4];
            #pragma unroll
            for (int i = 0; i < 4; ++i) {
                const int ar = wm + i*16 + fm;
                ah[i] = *(const f16x8*)&lds[0*4096 + ar*32 + fko];
                al[i] = *(const f16x8*)&lds[1*4096 + ar*32 + fko];
            }
            #pragma unroll
            for (int j = 0; j < 4; ++j) {
                const int br = wn + j*16 + fm;
                f16x8 bh = *(const f16x8*)&lds[2*4096 + br*32 + fko];
                f16x8 bl = *(const f16x8*)&lds[3*4096 + br*32 + fko];
                #pragma unroll
                for (int i = 0; i < 4; ++i) {
                    acc0[i][j] = __builtin_amdgcn_mfma_f32_16x16x32_f16(ah[i], bh, acc0[i][j], 0, 0, 0);
                    acc1[i][j] = __builtin_amdgcn_mfma_f32_16x16x32_f16(ah[i], bl, acc1[i][j], 0, 0, 0);
                    acc1[i][j] = __builtin_amdgcn_mfma_f32_16x16x32_f16(al[i], bh, acc1[i][j], 0, 0, 0);
                }
            }
        }
        // partial dot with Wd2 over this bn's 128 cols
        #pragma unroll
        for (int i = 0; i < 4; ++i)
            #pragma unroll
            for (int j = 0; j < 4; ++j) {
                const int col = bn*128 + wn + j*16 + fm;
                const float bv = bd1[col], uv = u512[col];
                #pragma unroll
                for (int r = 0; r < 4; ++r) {
                    float v = acc0[i][j][r] + acc1[i][j][r] * RINV + bv;
                    part[i*4 + r] += gelu_f(v) * uv;
                }
            }
    }
    // reduce over the 16 fm-lanes (within quad group)
    #pragma unroll
    for (int i = 0; i < 16; ++i) {
        float s = part[i];
        s += __shfl_xor(s, 1); s += __shfl_xor(s, 2);
        s += __shfl_xor(s, 4); s += __shfl_xor(s, 8);
        part[i] = s;
    }
    if (fm == 0) {
        #pragma unroll
        for (int i = 0; i < 4; ++i)
            #pragma unroll
            for (int r = 0; r < 4; ++r)
                atomicAdd(&wsum[wm + i*16 + quad*4 + r], part[i*4 + r]);
    }
    __syncthreads();
    if (t < 128) {
        const int rowm = bm + t;
        int wi = -1;
        if (MODE == 0) {
            const int n = rowm / 31, s = rowm - n * 31;
            wi = n * BEAM * S0 + s;
        } else {
            const int nk = rowm >> 1, slot = rowm & 1;
            const int s = posb[nk];
            const int jw = s - 1 + slot;
            if (jw >= 0 && jw < Spairs) wi = nk * S0 + jw;
        }
        if (wi >= 0) w[wi] = wsum[t] + bd2[0];
    }
}

// ============ weight transpose + fp16 split ============
__global__ __launch_bounds__(256) void k_tsplit(
    const float* __restrict__ in, _Float16* __restrict__ oh,
    _Float16* __restrict__ ol, int K, int N)
{
    __shared__ float tile[32][33];
    const int bx = blockIdx.x * 32, by = blockIdx.y * 32;
    const int t = threadIdx.x, r = t >> 5, c = t & 31;
    #pragma unroll
    for (int p = 0; p < 4; ++p)
        tile[r + p*8][c] = in[(size_t)(by + r + p*8) * N + bx + c];
    __syncthreads();
    #pragma unroll
    for (int p = 0; p < 4; ++p) {
        const int nl = r + p*8;
        float v = tile[c][nl];
        _Float16 h = hi16(v);
        oh[(size_t)(bx + nl) * K + by + c] = h;
        ol[(size_t)(bx + nl) * K + by + c] = lo16(v, h);
    }
}

// ============ elementwise fp16 split (x rows, init only) ============
__global__ __launch_bounds__(256) void k_xsplit(
    const float* __restrict__ in, _Float16* __restrict__ oh,
    _Float16* __restrict__ ol)
{
    const size_t i = ((size_t)blockIdx.x * 256 + threadIdx.x) * 4;
    float4 v = *(const float4*)(in + i);
    _Float16 h0 = hi16(v.x), h1 = hi16(v.y), h2 = hi16(v.z), h3 = hi16(v.w);
    f16x4v h = {h0, h1, h2, h3};
    f16x4v l = {lo16(v.x,h0), lo16(v.y,h1), lo16(v.z,h2), lo16(v.w,h3)};
    *(f16x4v*)(oh + i) = h;
    *(f16x4v*)(ol + i) = l;
}

// ============ init layernorm -> split content ============
__global__ __launch_bounds__(256) void k_ln_init(
    const float* __restrict__ y, const float* __restrict__ g,
    const float* __restrict__ b, _Float16* __restrict__ ch0,
    _Float16* __restrict__ cl0, int rowoff)
{
    const int row = rowoff + blockIdx.x;   // n*32 + s (stride-32 layout)
    const float* yr = y + (size_t)blockIdx.x * DD;
    const int t = threadIdx.x;
    float v0 = yr[t], v1 = yr[t + 256];
    __shared__ float sb[8];
    float s1 = block_reduce_sum(v0 + v1, sb);
    float s2 = block_reduce_sum(v0*v0 + v1*v1, sb);
    float mu = s1 * (1.f/512.f);
    float rstd = rsqrtf(s2 * (1.f/512.f) - mu*mu + 1e-5f);
    float a0 = (v0 - mu) * rstd * g[t]       + b[t];
    float a1 = (v1 - mu) * rstd * g[t + 256] + b[t + 256];
    _Float16 h0 = hi16(a0), h1 = hi16(a1);
    ch0[(size_t)row*DD + t]       = h0;
    cl0[(size_t)row*DD + t]       = lo16(a0, h0);
    ch0[(size_t)row*DD + t + 256] = h1;
    cl0[(size_t)row*DD + t + 256] = lo16(a1, h1);
}

__global__ void k_init_state(float* accu, float* bm, int* idxfin) {
    int i = blockIdx.x * blockDim.x + threadIdx.x;
    if (i < NB) { accu[i] = 0.f; bm[i] = 1.f; idxfin[i] = i * 31; }
}

// ============ top-k + beam selection + score-cache gather + rowidx ============
__global__ __launch_bounds__(64) void k_topk(
    const float* __restrict__ w, const float* __restrict__ accu,
    const float* __restrict__ bmask, const float* __restrict__ maskg,
    int iiter, int B, int S, int topk, int do_bsel,
    int* __restrict__ parent, int* __restrict__ posb, int* __restrict__ rowidx,
    int BAo, int STo,
    float* __restrict__ accu_out, float* __restrict__ bm_out,
    float* __restrict__ wnew, int Snew, int dow)
{
    const int n = blockIdx.x, lane = threadIdx.x;
    __shared__ int   selpos_s[BEAM][BEAM];
    __shared__ float nscore_s[BEAM][BEAM];
    __shared__ int   par_s[BEAM], pos_s[BEAM];
    const float* mrow = maskg + n*S0 + (iiter + 1);
    const float mk   = (lane < S) ? mrow[lane] : 0.f;
    const float done = 1.f - mrow[0];
    for (int b = 0; b < B; ++b) {
        float ml;
        if (lane < S) {
            float wv = w[(n*BEAM + b)*S0 + lane];
            ml = (mk > 0.f) ? wv : -1e9f;
        } else ml = -INFINITY;
        float mx = ml;
        #pragma unroll
        for (int o = 32; o > 0; o >>= 1) mx = fmaxf(mx, __shfl_xor(mx, o));
        float e = (lane < S) ? expf(ml - mx) * mk : 0.f;
        float es = e;
        #pragma unroll
        for (int o = 32; o > 0; o >>= 1) es += __shfl_xor(es, o);
        const float den = es + 1e-20f;
        float mlc = ml;
        for (int ts = 0; ts < topk; ++ts) {
            unsigned int fb = __float_as_uint(mlc);
            unsigned int ok = (fb & 0x80000000u) ? ~fb : (fb | 0x80000000u);
            unsigned long long key =
                ((unsigned long long)ok << 32) | (unsigned int)(63 - lane);
            if (lane >= S) key = 0ull;
            unsigned long long km = key;
            #pragma unroll
            for (int o = 32; o > 0; o >>= 1) {
                unsigned long long oth = __shfl_xor(km, o);
                km = (oth > km) ? oth : km;
            }
            int sidx = 63 - (int)(km & 0xffffffffull);
            float esel = __shfl(e, sidx);
            if (lane == 0) {
                selpos_s[b][ts] = sidx;
                nscore_s[b][ts] = logf(esel / den + 1e-20f);
            }
            if (lane == sidx) mlc = -INFINITY;
        }
    }
    __syncthreads();
    if (lane == 0) {
        float acand[BEAM*BEAM], bcand[BEAM*BEAM];
        const int C = B * topk;
        for (int b = 0; b < B; ++b)
            for (int tt = 0; tt < topk; ++tt) {
                int c = b*topk + tt;
                acand[c] = accu[n*BEAM + b] + nscore_s[b][tt];
                float nb = done * ((tt == 0) ? 1.f : 0.f) + (1.f - done);
                bcand[c] = bmask[n*BEAM + b] * nb;
            }
        bool used[BEAM*BEAM];
        for (int c = 0; c < C; ++c) used[c] = false;
        for (int k = 0; k < BEAM; ++k) {
            int bestc;
            if (do_bsel) {
                bestc = 0; float bv = -INFINITY;
                for (int c = 0; c < C; ++c) {
                    if (used[c]) continue;
                    float v = (bcand[c] > 0.f) ? acand[c] : -1e9f;
                    if (v > bv) { bv = v; bestc = c; }
                }
                used[bestc] = true;
            } else bestc = k;
            const int pp = bestc / topk, ss = selpos_s[bestc / topk][bestc % topk];
            parent[n*BEAM + k] = pp;
            posb[n*BEAM + k]   = ss;
            par_s[k] = pp; pos_s[k] = ss;
            accu_out[n*BEAM + k] = acand[bestc];
            bm_out[n*BEAM + k]   = bcand[bestc];
        }
    }
    __syncthreads();
    if (lane < BEAM)
        rowidx[n*BEAM + lane] = (n*BAo + par_s[lane]) * STo + pos_s[lane];
    if (dow) {
        for (int k = 0; k < BEAM; ++k) {
            const int p = par_s[k], s = pos_s[k];
            if (lane < Snew) {
                float v = 0.f;
                if (lane < s - 1)      v = w[(n*BEAM + p)*S0 + lane];
                else if (lane > s)     v = w[(n*BEAM + p)*S0 + lane + 1];
                wnew[(n*BEAM + k)*S0 + lane] = v;
            }
        }
    }
}

// ============ fused combine (gate softmax + mix + LN) + rebuild ============
__global__ __launch_bounds__(256) void k_crb(
    const float* __restrict__ cc,
    const _Float16* __restrict__ ch_old, const _Float16* __restrict__ cl_old,
    const int* __restrict__ parent, const int* __restrict__ posb,
    const int* __restrict__ rowidx,
    const float* __restrict__ maskg, int iiter, int Spnew, int BAo, int STo,
    const float* __restrict__ gp, const float* __restrict__ bp,
    _Float16* __restrict__ ch_new, _Float16* __restrict__ cl_new,
    int finalflag, float* __restrict__ nvout)
{
    __shared__ __align__(16) _Float16 nh[512], nl[512];
    __shared__ float sb[8];
    const int nk = blockIdx.x, t = threadIdx.x;
    const int n = nk / BEAM;
    const size_t lbase = (size_t)rowidx[nk] * 512;
    const float* c = cc + (size_t)nk * CHID;
    float o[2];
    #pragma unroll
    for (int e = 0; e < 2; ++e) {
        const int d = t + 256*e;
        const float lv = recon(ch_old[lbase + d],       cl_old[lbase + d]);
        const float rv = recon(ch_old[lbase + 512 + d], cl_old[lbase + 512 + d]);
        float c0 = c[d], c1 = c[DD + d], c2 = c[2*DD + d], c3 = c[3*DD + d];
        float m = fmaxf(c0, fmaxf(c1, c2));
        float e0 = expf(c0 - m), e1 = expf(c1 - m), e2 = expf(c2 - m);
        float inv = 1.f / (e0 + e1 + e2);
        o[e] = (e0*lv + e1*rv + e2*c3) * inv;
    }
    float s1 = block_reduce_sum(o[0] + o[1], sb);
    float s2 = block_reduce_sum(o[0]*o[0] + o[1]*o[1], sb);
    float mu = s1 * (1.f/512.f);
    float rstd = rsqrtf(s2 * (1.f/512.f) - mu*mu + 1e-5f);
    if (finalflag) {
        #pragma unroll
        for (int e = 0; e < 2; ++e) {
            const int d = t + 256*e;
            nvout[(size_t)nk*DD + d] = (o[e] - mu) * rstd * gp[d] + bp[d];
        }
        return;
    }
    #pragma unroll
    for (int e = 0; e < 2; ++e) {
        const int d = t + 256*e;
        float v = (o[e] - mu) * rstd * gp[d] + bp[d];
        _Float16 h = hi16(v);
        nh[d] = h; nl[d] = lo16(v, h);
    }
    __syncthreads();
    const int p = parent[nk], s = posb[nk];
    const float done = maskg[n*S0 + iiter + 1];
    const size_t obase = (size_t)(n*BAo + p) * STo * 512;   // halfs
    const size_t dbase = (size_t)nk * 31 * 512;
    if (done == 1.0f) {
        const uint4* oh4 = (const uint4*)(ch_old + obase);
        const uint4* ol4 = (const uint4*)(cl_old + obase);
        uint4* dh4 = (uint4*)(ch_new + dbase);
        uint4* dl4 = (uint4*)(cl_new + dbase);
        const uint4* nh4 = (const uint4*)nh;
        const uint4* nl4 = (const uint4*)nl;
        const int total = Spnew * 64;           // 64 uint4 per 512-half row
        for (int idx = t; idx < total; idx += 256) {
            const int j = idx >> 6, cch = idx & 63;
            uint4 vh, vl;
            if (j < s)       { vh = oh4[j*64 + cch];     vl = ol4[j*64 + cch]; }
            else if (j == s) { vh = nh4[cch];            vl = nl4[cch]; }
            else             { vh = oh4[(j+1)*64 + cch]; vl = ol4[(j+1)*64 + cch]; }
            dh4[j*64 + cch] = vh;
            dl4[j*64 + cch] = vl;
        }
    } else {
        for (int e2 = t; e2 < Spnew*512; e2 += 256) {
            const int j = e2 >> 9, d = e2 & 511;
            float newv;
            if (j < s)       newv = recon(ch_old[obase + j*512 + d],     cl_old[obase + j*512 + d]);
            else if (j == s) newv = recon(nh[d], nl[d]);
            else             newv = recon(ch_old[obase + (j+1)*512 + d], cl_old[obase + (j+1)*512 + d]);
            const float oldv = recon(ch_old[obase + j*512 + d], cl_old[obase + j*512 + d]);
            const float v = done*newv + (1.f - done)*oldv;
            _Float16 h = hi16(v);
            ch_new[dbase + j*512 + d] = h;
            cl_new[dbase + j*512 + d] = lo16(v, h);
        }
    }
}

// ============ final beam softmax mix (with done-blend vs old content) ========
__global__ __launch_bounds__(256) void k_final(
    const float* __restrict__ nv,
    const _Float16* __restrict__ ch, const _Float16* __restrict__ cl,
    const float* __restrict__ maskg,
    const float* __restrict__ accu, const float* __restrict__ bmv,
    float* __restrict__ out)
{
    const int n = blockIdx.x, t = threadIdx.x;
    const float done = maskg[n*S0 + 31];
    float sc[BEAM];
    #pragma unroll
    for (int k = 0; k < BEAM; ++k) {
        float m = bmv[n*BEAM + k];
        sc[k] = m * accu[n*BEAM + k] + (1.f - m) * (-999999.f);
    }
    float mx = sc[0];
    #pragma unroll
    for (int k = 1; k < BEAM; ++k) mx = fmaxf(mx, sc[k]);
    float e[BEAM], den = 0.f;
    #pragma unroll
    for (int k = 0; k < BEAM; ++k) { e[k] = expf(sc[k] - mx); den += e[k]; }
    const float inv = 1.f / den;
    #pragma unroll
    for (int i2 = 0; i2 < 2; ++i2) {
        const int d = t + 256*i2;
        float s = 0.f;
        #pragma unroll
        for (int k = 0; k < BEAM; ++k) {
            const int nk = n*BEAM + k;
            const float nvv  = nv[(size_t)nk*DD + d];
            const float oldv = recon(ch[(size_t)nk*31*512 + d], cl[(size_t)nk*31*512 + d]);
            s += e[k]*inv * (done*nvv + (1.f - done)*oldv);
        }
        out[(size_t)n*DD + d] = s;
    }
}

extern "C" void kernel_launch(void* const* d_in, const int* in_sizes, int n_in,
                              void* d_out, int out_size, void* d_ws, size_t ws_size,
                              hipStream_t stream) {
    (void)in_sizes; (void)n_in; (void)out_size; (void)ws_size;
    const float* x    = (const float*)d_in[0];
    const float* mask = (const float*)d_in[1];
    const float* Wi   = (const float*)d_in[2];
    const float* bi   = (const float*)d_in[3];
    const float* g1   = (const float*)d_in[4];
    const float* b1   = (const float*)d_in[5];
    const float* Wd1  = (const float*)d_in[6];
    const float* bd1  = (const float*)d_in[7];
    const float* Wd2  = (const float*)d_in[8];
    const float* bd2  = (const float*)d_in[9];
    const float* Wc1  = (const float*)d_in[10];
    const float* bc1  = (const float*)d_in[11];
    const float* Wc2  = (const float*)d_in[12];
    const float* bc2  = (const float*)d_in[13];
    const float* g2   = (const float*)d_in[14];
    const float* b2   = (const float*)d_in[15];
    float* out = (float*)d_out;

    // ---- workspace carve-up (bytes), ~207 MB ----
    const size_t CROWS = (size_t)NB * 31 * 512;         // 20,316,160 halfs
    char* p = (char*)d_ws;
    _Float16* chA = (_Float16*)p;        p += CROWS * 2;
    _Float16* clA = (_Float16*)p;        p += CROWS * 2;
    _Float16* chB = (_Float16*)p;        p += CROWS * 2;
    _Float16* clB = (_Float16*)p;        p += CROWS * 2;
    _Float16* ch0 = chB;                 // init content stride-32 alias (8.4 MB)
    _Float16* cl0 = clB;
    _Float16* Wc1th = (_Float16*)p;      p += (size_t)CHID*1024*2;
    _Float16* Wc1tl = (_Float16*)p;      p += (size_t)CHID*1024*2;
    _Float16* Wc2th = (_Float16*)p;      p += (size_t)CHID*CHID*2;
    _Float16* Wc2tl = (_Float16*)p;      p += (size_t)CHID*CHID*2;
    _Float16* Wd1th = (_Float16*)p;      p += (size_t)512*1024*2;
    _Float16* Wd1tl = (_Float16*)p;      p += (size_t)512*1024*2;
    _Float16* Wih = (_Float16*)p;        p += (size_t)WDIM*DD*2;
    _Float16* Wil = (_Float16*)p;        p += (size_t)WDIM*DD*2;
    _Float16* Hh  = (_Float16*)p;        p += (size_t)NB*CHID*2;
    _Float16* Hl  = (_Float16*)p;        p += (size_t)NB*CHID*2;
    float* cb   = (float*)p;             p += (size_t)NB*CHID*4;
    float* nvb  = (float*)p;             p += (size_t)NB*DD*4;
    float* wA   = (float*)p;             p += (size_t)NB*S0*4;
    float* wB   = (float*)p;             p += (size_t)NB*S0*4;
    float* accA = (float*)p;             p += NB*4;
    float* accB = (float*)p;             p += NB*4;
    float* bmA  = (float*)p;             p += NB*4;
    float* bmB  = (float*)p;             p += NB*4;
    int* parent = (int*)p;               p += NB*4;
    int* posb   = (int*)p;               p += NB*4;
    int* rowidx = (int*)p;               p += NB*4;
    int* idxfin = (int*)p;               p += NB*4;
    // init-only aliases:
    _Float16* xh = Hh;                   // 4096x512 halfs (4.2 MB <= Hh 5.2 MB)
    _Float16* xl = Hl;
    float* ybufc = cb;                   // 4096x512 fp32 (8.4 MB <= cb 10.5 MB)

    // ---- prep ----
    k_tsplit<<<dim3(CHID/32, 1024/32), 256, 0, stream>>>(Wc1, Wc1th, Wc1tl, 1024, CHID);
    k_tsplit<<<dim3(CHID/32, CHID/32), 256, 0, stream>>>(Wc2, Wc2th, Wc2tl, CHID, CHID);
    k_tsplit<<<dim3(512/32, 1024/32), 256, 0, stream>>>(Wd1, Wd1th, Wd1tl, 1024, 512);
    k_tsplit<<<dim3(DD/32, WDIM/32), 256, 0, stream>>>(Wi, Wih, Wil, WDIM, DD);
    k_init_state<<<(NB + 255)/256, 256, 0, stream>>>(accA, bmA, idxfin);

    // ---- init: content0 = LN(x@Wi+bi) -> split, 2 chunks of 4096 rows ----
    for (int c = 0; c < 2; ++c) {
        const float* xc = x + (size_t)c*4096*WDIM;
        k_xsplit<<<(4096*WDIM)/1024, 256, 0, stream>>>(xc, xh, xl);
        k_mfma_gemm<0,0><<<dim3(DD/128, 4096/128), 256, 0, stream>>>(
            xh, xl, Wih, Wil, bi, ybufc, nullptr, nullptr, nullptr, 4096, DD, WDIM);
        k_ln_init<<<4096, 256, 0, stream>>>(ybufc, g1, b1, ch0, cl0, c*4096);
    }
    // full scores at i=0: M = 256*31 = 7936 rows, content stride 32
    k_wscore<0><<<NN*31/128, 256, 0, stream>>>(
        ch0, cl0, nullptr, Wd1th, Wd1tl, bd1, Wd2, bd2, wA, 31, 32);

    _Float16 *chcur = ch0, *clcur = cl0, *chnxt = chA, *clnxt = clA;
    int BAo = 1, STo = 32;
    float *wcur = wA, *wnxt = wB;
    float *acur = accA, *anxt = accB, *bcur = bmA, *bnxt = bmB;
    for (int i = 0; i < 30; ++i) {
        const int B  = (i == 0) ? 1 : BEAM;
        const int S  = 31 - i;
        const int tk = (S < BEAM) ? S : BEAM;
        const int dob = (B*tk > BEAM) ? 1 : 0;
        k_topk<<<NN, 64, 0, stream>>>(wcur, acur, bcur, mask, i, B, S, tk, dob,
                                      parent, posb, rowidx, BAo, STo,
                                      anxt, bnxt, wnxt, S - 1, (i < 29) ? 1 : 0);
        k_mfma_gemm<1,1><<<dim3(CHID/128, NB/128), 256, 0, stream>>>(
            chcur, clcur, Wc1th, Wc1tl, bc1, nullptr, Hh, Hl, rowidx, NB, CHID, 2*DD);
        k_mfma_gemm<0,0><<<dim3(CHID/128, NB/128), 256, 0, stream>>>(
            Hh, Hl, Wc2th, Wc2tl, bc2, cb, nullptr, nullptr, nullptr, NB, CHID, CHID);
        k_crb<<<NB, 256, 0, stream>>>(cb, chcur, clcur, parent, posb, rowidx,
                                      mask, i, 31 - i, BAo, STo, g2, b2,
                                      chnxt, clnxt, 0, nullptr);
        if (i < 29)
            k_wscore<1><<<NB*2/128, 256, 0, stream>>>(
                chnxt, clnxt, posb, Wd1th, Wd1tl, bd1, Wd2, bd2, wnxt, S - 1, 31);
        // swap
        if (i == 0) { chcur = chA; clcur = clA; chnxt = chB; clnxt = clB; }
        else {
            _Float16* tq;
            tq = chcur; chcur = chnxt; chnxt = tq;
            tq = clcur; clcur = clnxt; clnxt = tq;
        }
        BAo = BEAM; STo = 31;
        float* tp;
        tp = wcur; wcur = wnxt; wnxt = tp;
        tp = acur; acur = anxt; anxt = tp;
        tp = bcur; bcur = bnxt; bnxt = tp;
    }
    // final compose: l,r = content positions 0,1 (rowidx = idxfin = nk*31)
    k_mfma_gemm<1,1><<<dim3(CHID/128, NB/128), 256, 0, stream>>>(
        chcur, clcur, Wc1th, Wc1tl, bc1, nullptr, Hh, Hl, idxfin, NB, CHID, 2*DD);
    k_mfma_gemm<0,0><<<dim3(CHID/128, NB/128), 256, 0, stream>>>(
        Hh, Hl, Wc2th, Wc2tl, bc2, cb, nullptr, nullptr, nullptr, NB, CHID, CHID);
    k_crb<<<NB, 256, 0, stream>>>(cb, chcur, clcur, parent, posb, idxfin,
                                  mask, 30, 0, BEAM, 31, g2, b2,
                                  nullptr, nullptr, 1, nvb);
    k_final<<<NN, 256, 0, stream>>>(nvb, chcur, clcur, mask, acur, bcur, out);
}

// Round 7
// 8057.198 us; speedup vs baseline: 1.5225x; 1.5225x over previous
//
#include <hip/hip_runtime.h>
#include <math.h>

// EBT_GRC beam-search forward, round 7: append-only content arena + index
// tables (kills the 162MB/iter rebuild copy that thrashed L2 and left the
// latency-bound score/gemm kernels reading cold HBM), ny-split score kernel
// (20 -> 80 blocks). 5 kernels/iter. N=256, S=32, D=512, CH=2048, BEAM=5.
// WS ~150 MB.

#define NN   256
#define S0   32
#define WDIM 512
#define DD   512
#define CHID 2048
#define BEAM 5
#define NB   (NN*BEAM)   // 1280
#define RSCALE 2048.0f
#define RINV  (1.0f/2048.0f)
#define AR_INIT 8192                 // arena rows from init (256*32)
#define AR_TOT  (AR_INIT + 30*NB)    // 46592 rows

typedef __attribute__((ext_vector_type(8))) _Float16 f16x8;
typedef __attribute__((ext_vector_type(4))) float f32x4;

__device__ __forceinline__ float gelu_f(float x) {
    return 0.5f * x * (1.0f + erff(x * 0.7071067811865475f));
}
__device__ __forceinline__ _Float16 hi16(float v) { return (_Float16)v; }
__device__ __forceinline__ _Float16 lo16(float v, _Float16 h) {
    return (_Float16)((v - (float)h) * RSCALE);
}
__device__ __forceinline__ float recon(_Float16 h, _Float16 l) {
    return (float)h + RINV * (float)l;
}

__device__ __forceinline__ void gload_lds16(const void* g, void* l) {
    __builtin_amdgcn_global_load_lds(
        (const __attribute__((address_space(1))) unsigned*)g,
        (__attribute__((address_space(3))) unsigned*)l, 16, 0, 0);
}

__device__ __forceinline__ float block_reduce_sum(float v, float* sb) {
    #pragma unroll
    for (int o = 32; o > 0; o >>= 1) v += __shfl_down(v, o);
    const int lane = threadIdx.x & 63, wid = threadIdx.x >> 6;
    __syncthreads();
    if (lane == 0) sb[wid] = v;
    __syncthreads();
    return sb[0] + sb[1] + sb[2] + sb[3];
}

// ================= fp16x2 scaled-split MFMA GEMM =================
// OUTMODE 0: fp32 store. 1: gelu -> fp16 h/l store.
// AIDX 0: A row m at Ah[m*K]. AIDX 1: cat row from arena rows lrid[m]/rrid[m]
// (K must be 1024: k<512 from l-row, k>=512 from r-row). AIDX 2: same but
// rows from idxt[m*31+0], idxt[m*31+1].
template<int OUTMODE, int AIDX>
__global__ __launch_bounds__(256, 1) void k_mfma_gemm(
    const _Float16* __restrict__ Ah, const _Float16* __restrict__ Al,
    const _Float16* __restrict__ Bh, const _Float16* __restrict__ Bl,
    const float* __restrict__ bias, float* __restrict__ Cf,
    _Float16* __restrict__ Oh, _Float16* __restrict__ Ol,
    const int* __restrict__ lrid, const int* __restrict__ rrid,
    const int* __restrict__ idxt,
    int M, int N, int K)
{
    __shared__ __align__(16) _Float16 lds[4 * 4096];
    const int t = threadIdx.x, wave = t >> 6, lane = t & 63;
    const int bm = blockIdx.y * 128, bn = blockIdx.x * 128;
    const int wm = (wave >> 1) * 64, wn = (wave & 1) * 64;
    const int rsub = lane >> 2, seg = lane & 3;
    const int fm = lane & 15, fko = (lane >> 4) * 8;

    size_t lb[2], rb[2];
    #pragma unroll
    for (int j = 0; j < 2; ++j) {
        const int q = wave * 2 + j;
        const int rowm = bm + q*16 + rsub;
        if (AIDX == 0) { lb[j] = (size_t)rowm * K; rb[j] = 0; }
        else if (AIDX == 1) {
            lb[j] = (size_t)lrid[rowm] * 512;
            rb[j] = (size_t)rrid[rowm] * 512;
        } else {
            lb[j] = (size_t)idxt[rowm*31 + 0] * 512;
            rb[j] = (size_t)idxt[rowm*31 + 1] * 512;
        }
    }

    f32x4 acc0[4][4], acc1[4][4];
    #pragma unroll
    for (int i = 0; i < 4; ++i)
        #pragma unroll
        for (int j = 0; j < 4; ++j) {
            acc0[i][j] = (f32x4){0.f, 0.f, 0.f, 0.f};
            acc1[i][j] = (f32x4){0.f, 0.f, 0.f, 0.f};
        }

    for (int k0 = 0; k0 < K; k0 += 32) {
        __syncthreads();
        #pragma unroll
        for (int j = 0; j < 2; ++j) {
            const int q = wave * 2 + j;
            const size_t aoff = ((AIDX == 0) ? lb[j] + k0
                                : (k0 < 512 ? lb[j] + k0 : rb[j] + (k0 - 512)))
                                + seg * 8;
            const size_t boff = (size_t)(bn + q*16 + rsub) * K + k0 + seg * 8;
            gload_lds16(Ah + aoff, &lds[0*4096 + q*512]);
            gload_lds16(Al + aoff, &lds[1*4096 + q*512]);
            gload_lds16(Bh + boff, &lds[2*4096 + q*512]);
            gload_lds16(Bl + boff, &lds[3*4096 + q*512]);
        }
        __syncthreads();
        f16x8 ah[4], al[4];
        #pragma unroll
        for (int i = 0; i < 4; ++i) {
            const int ar = wm + i*16 + fm;
            ah[i] = *(const f16x8*)&lds[0*4096 + ar*32 + fko];
            al[i] = *(const f16x8*)&lds[1*4096 + ar*32 + fko];
        }
        #pragma unroll
        for (int j = 0; j < 4; ++j) {
            const int br = wn + j*16 + fm;
            f16x8 bh = *(const f16x8*)&lds[2*4096 + br*32 + fko];
            f16x8 bl = *(const f16x8*)&lds[3*4096 + br*32 + fko];
            #pragma unroll
            for (int i = 0; i < 4; ++i) {
                acc0[i][j] = __builtin_amdgcn_mfma_f32_16x16x32_f16(ah[i], bh, acc0[i][j], 0, 0, 0);
                acc1[i][j] = __builtin_amdgcn_mfma_f32_16x16x32_f16(ah[i], bl, acc1[i][j], 0, 0, 0);
                acc1[i][j] = __builtin_amdgcn_mfma_f32_16x16x32_f16(al[i], bh, acc1[i][j], 0, 0, 0);
            }
        }
    }
    #pragma unroll
    for (int i = 0; i < 4; ++i)
        #pragma unroll
        for (int j = 0; j < 4; ++j) {
            const int col = bn + wn + j*16 + fm;
            const float bv = bias[col];
            #pragma unroll
            for (int r = 0; r < 4; ++r) {
                const int row = bm + wm + i*16 + (lane >> 4)*4 + r;
                float v = acc0[i][j][r] + acc1[i][j][r] * RINV + bv;
                if (OUTMODE == 0) {
                    Cf[(size_t)row * N + col] = v;
                } else {
                    v = gelu_f(v);
                    _Float16 h = hi16(v);
                    Oh[(size_t)row * N + col] = h;
                    Ol[(size_t)row * N + col] = lo16(v, h);
                }
            }
        }
}

// ============ fused score: w += partial of gelu(cat@Wd1+bd1)@Wd2 ============
// blockIdx.y = ny (0..3): cols [ny*128, ny*128+128). Target w slots must be
// pre-zeroed (k_init_state for init; k_topk's cache-gather zeroes the
// recompute slots). ny==0 also adds bd2.
// MODE 0 (init): row r -> n=r/31, s=r%31; arena rows n*32+s, +1; wi=n*160+s.
// MODE 1 (incr): r -> nk=r>>1, jw=posb[nk]-1+(r&1); rows from idxt (stride 31).
template<int MODE>
__global__ __launch_bounds__(256, 2) void k_wscore(
    const _Float16* __restrict__ ch, const _Float16* __restrict__ cl,
    const int* __restrict__ posb, const int* __restrict__ idxt,
    const _Float16* __restrict__ Bh, const _Float16* __restrict__ Bl,
    const float* __restrict__ bd1, const float* __restrict__ u512,
    const float* __restrict__ bd2, float* __restrict__ w, int Spairs)
{
    __shared__ __align__(16) _Float16 lds[4 * 4096];
    __shared__ float wsum[128];
    const int t = threadIdx.x, wave = t >> 6, lane = t & 63;
    const int bm = blockIdx.x * 128, ncol0 = blockIdx.y * 128;
    const int wm = (wave >> 1) * 64, wn = (wave & 1) * 64;
    const int rsub = lane >> 2, seg = lane & 3;
    const int fm = lane & 15, quad = lane >> 4, fko = quad * 8;
    if (t < 128) wsum[t] = 0.f;

    size_t lb[2], rb[2];
    #pragma unroll
    for (int j = 0; j < 2; ++j) {
        const int q = wave * 2 + j;
        const int rowm = bm + q*16 + rsub;
        if (MODE == 0) {
            const int n = rowm / 31, s = rowm - n * 31;
            lb[j] = (size_t)(n*32 + s) * 512;
            rb[j] = lb[j] + 512;
        } else {
            const int nk = rowm >> 1, slot = rowm & 1;
            const int s = posb[nk];
            int jw = s - 1 + slot;
            int jc = jw < 0 ? 0 : (jw > Spairs - 1 ? Spairs - 1 : jw);
            lb[j] = (size_t)idxt[nk*31 + jc] * 512;
            rb[j] = (size_t)idxt[nk*31 + jc + 1] * 512;
        }
    }

    f32x4 acc0[4][4], acc1[4][4];
    #pragma unroll
    for (int i = 0; i < 4; ++i)
        #pragma unroll
        for (int j = 0; j < 4; ++j) {
            acc0[i][j] = (f32x4){0.f, 0.f, 0.f, 0.f};
            acc1[i][j] = (f32x4){0.f, 0.f, 0.f, 0.f};
        }
    for (int k0 = 0; k0 < 1024; k0 += 32) {
        __syncthreads();
        #pragma unroll
        for (int j = 0; j < 2; ++j) {
            const int q = wave * 2 + j;
            const size_t aoff = (k0 < 512 ? lb[j] + k0 : rb[j] + (k0 - 512)) + seg * 8;
            const size_t boff = (size_t)(ncol0 + q*16 + rsub) * 1024 + k0 + seg * 8;
            gload_lds16(ch + aoff, &lds[0*4096 + q*512]);
            gload_lds16(cl + aoff, &lds[1*4096 + q*512]);
            gload_lds16(Bh + boff, &lds[2*4096 + q*512]);
            gload_lds16(Bl + boff, &lds[3*4096 + q*512]);
        }
        __syncthreads();
        f16x8 ah[4], al[4];
        #pragma unroll
        for (int i = 0; i < 4; ++i) {
            const int ar = wm + i*16 + fm;
            ah[i] = *(const f16x8*)&lds[0*4096 + ar*32 + fko];
            al[i] = *(const f16x8*)&lds[1*4096 + ar*32 + fko];
        }
        #pragma unroll
        for (int j = 0; j < 4; ++j) {
            const int br = wn + j*16 + fm;
            f16x8 bh = *(const f16x8*)&lds[2*4096 + br*32 + fko];
            f16x8 bl = *(const f16x8*)&lds[3*4096 + br*32 + fko];
            #pragma unroll
            for (int i = 0; i < 4; ++i) {
                acc0[i][j] = __builtin_amdgcn_mfma_f32_16x16x32_f16(ah[i], bh, acc0[i][j], 0, 0, 0);
                acc1[i][j] = __builtin_amdgcn_mfma_f32_16x16x32_f16(ah[i], bl, acc1[i][j], 0, 0, 0);
                acc1[i][j] = __builtin_amdgcn_mfma_f32_16x16x32_f16(al[i], bh, acc1[i][j], 0, 0, 0);
            }
        }
    }
    float part[16];
    #pragma unroll
    for (int i = 0; i < 16; ++i) part[i] = 0.f;
    #pragma unroll
    for (int i = 0; i < 4; ++i)
        #pragma unroll
        for (int j = 0; j < 4; ++j) {
            const int col = ncol0 + wn + j*16 + fm;
            const float bv = bd1[col], uv = u512[col];
            #pragma unroll
            for (int r = 0; r < 4; ++r) {
                float v = acc0[i][j][r] + acc1[i][j][r] * RINV + bv;
                part[i*4 + r] += gelu_f(v) * uv;
            }
        }
    #pragma unroll
    for (int i = 0; i < 16; ++i) {
        float s = part[i];
        s += __shfl_xor(s, 1); s += __shfl_xor(s, 2);
        s += __shfl_xor(s, 4); s += __shfl_xor(s, 8);
        part[i] = s;
    }
    if (fm == 0) {
        #pragma unroll
        for (int i = 0; i < 4; ++i)
            #pragma unroll
            for (int r = 0; r < 4; ++r)
                atomicAdd(&wsum[wm + i*16 + quad*4 + r], part[i*4 + r]);
    }
    __syncthreads();
    if (t < 128) {
        const int rowm = bm + t;
        int wi = -1;
        if (MODE == 0) {
            const int n = rowm / 31, s = rowm - n * 31;
            wi = n * BEAM * S0 + s;
        } else {
            const int nk = rowm >> 1, slot = rowm & 1;
            const int jw = posb[nk] - 1 + slot;
            if (jw >= 0 && jw < Spairs) wi = nk * S0 + jw;
        }
        if (wi >= 0)
            atomicAdd(&w[wi], wsum[t] + ((blockIdx.y == 0) ? bd2[0] : 0.f));
    }
}

// ============ weight transpose + fp16 split ============
__global__ __launch_bounds__(256) void k_tsplit(
    const float* __restrict__ in, _Float16* __restrict__ oh,
    _Float16* __restrict__ ol, int K, int N)
{
    __shared__ float tile[32][33];
    const int bx = blockIdx.x * 32, by = blockIdx.y * 32;
    const int t = threadIdx.x, r = t >> 5, c = t & 31;
    #pragma unroll
    for (int p = 0; p < 4; ++p)
        tile[r + p*8][c] = in[(size_t)(by + r + p*8) * N + bx + c];
    __syncthreads();
    #pragma unroll
    for (int p = 0; p < 4; ++p) {
        const int nl = r + p*8;
        float v = tile[c][nl];
        _Float16 h = hi16(v);
        oh[(size_t)(bx + nl) * K + by + c] = h;
        ol[(size_t)(bx + nl) * K + by + c] = lo16(v, h);
    }
}

// ============ elementwise fp16 split (x rows, init only) ============
__global__ __launch_bounds__(256) void k_xsplit(
    const float* __restrict__ in, _Float16* __restrict__ oh,
    _Float16* __restrict__ ol)
{
    const size_t i = ((size_t)blockIdx.x * 256 + threadIdx.x) * 4;
    float4 v = *(const float4*)(in + i);
    _Float16 h0 = hi16(v.x), h1 = hi16(v.y), h2 = hi16(v.z), h3 = hi16(v.w);
    typedef __attribute__((ext_vector_type(4))) _Float16 f16x4v;
    f16x4v h = {h0, h1, h2, h3};
    f16x4v l = {lo16(v.x,h0), lo16(v.y,h1), lo16(v.z,h2), lo16(v.w,h3)};
    *(f16x4v*)(oh + i) = h;
    *(f16x4v*)(ol + i) = l;
}

// ============ init layernorm -> split arena rows ============
__global__ __launch_bounds__(256) void k_ln_init(
    const float* __restrict__ y, const float* __restrict__ g,
    const float* __restrict__ b, _Float16* __restrict__ cha,
    _Float16* __restrict__ cla, int rowoff)
{
    const int row = rowoff + blockIdx.x;
    const float* yr = y + (size_t)blockIdx.x * DD;
    const int t = threadIdx.x;
    float v0 = yr[t], v1 = yr[t + 256];
    __shared__ float sb[8];
    float s1 = block_reduce_sum(v0 + v1, sb);
    float s2 = block_reduce_sum(v0*v0 + v1*v1, sb);
    float mu = s1 * (1.f/512.f);
    float rstd = rsqrtf(s2 * (1.f/512.f) - mu*mu + 1e-5f);
    float a0 = (v0 - mu) * rstd * g[t]       + b[t];
    float a1 = (v1 - mu) * rstd * g[t + 256] + b[t + 256];
    _Float16 h0 = hi16(a0), h1 = hi16(a1);
    cha[(size_t)row*DD + t]       = h0;
    cla[(size_t)row*DD + t]       = lo16(a0, h0);
    cha[(size_t)row*DD + t + 256] = h1;
    cla[(size_t)row*DD + t + 256] = lo16(a1, h1);
}

// zero wA, identity idx0, accu=0 bm=1
__global__ void k_init_state(float* accu, float* bm, int* idx0, float* wz) {
    int i = blockIdx.x * blockDim.x + threadIdx.x;
    if (i < NB*S0) wz[i] = 0.f;
    if (i < AR_INIT) idx0[i] = i;
    if (i < NB) { accu[i] = 0.f; bm[i] = 1.f; }
}

// ============ top-k + beam select + score-cache gather + l/r row ids ========
__global__ __launch_bounds__(64) void k_topk(
    const float* __restrict__ w, const float* __restrict__ accu,
    const float* __restrict__ bmask, const float* __restrict__ maskg,
    int iiter, int B, int S, int topk, int do_bsel,
    const int* __restrict__ idxold, int BAo, int STo,
    int* __restrict__ parent, int* __restrict__ posb,
    int* __restrict__ lrid, int* __restrict__ rrid,
    float* __restrict__ accu_out, float* __restrict__ bm_out,
    float* __restrict__ wnew, int Snew, int dow)
{
    const int n = blockIdx.x, lane = threadIdx.x;
    __shared__ int   selpos_s[BEAM][BEAM];
    __shared__ float nscore_s[BEAM][BEAM];
    __shared__ int   par_s[BEAM], pos_s[BEAM];
    const float* mrow = maskg + n*S0 + (iiter + 1);
    const float mk   = (lane < S) ? mrow[lane] : 0.f;
    const float done = 1.f - mrow[0];
    for (int b = 0; b < B; ++b) {
        float ml;
        if (lane < S) {
            float wv = w[(n*BEAM + b)*S0 + lane];
            ml = (mk > 0.f) ? wv : -1e9f;
        } else ml = -INFINITY;
        float mx = ml;
        #pragma unroll
        for (int o = 32; o > 0; o >>= 1) mx = fmaxf(mx, __shfl_xor(mx, o));
        float e = (lane < S) ? expf(ml - mx) * mk : 0.f;
        float es = e;
        #pragma unroll
        for (int o = 32; o > 0; o >>= 1) es += __shfl_xor(es, o);
        const float den = es + 1e-20f;
        float mlc = ml;
        for (int ts = 0; ts < topk; ++ts) {
            unsigned int fb = __float_as_uint(mlc);
            unsigned int ok = (fb & 0x80000000u) ? ~fb : (fb | 0x80000000u);
            unsigned long long key =
                ((unsigned long long)ok << 32) | (unsigned int)(63 - lane);
            if (lane >= S) key = 0ull;
            unsigned long long km = key;
            #pragma unroll
            for (int o = 32; o > 0; o >>= 1) {
                unsigned long long oth = __shfl_xor(km, o);
                km = (oth > km) ? oth : km;
            }
            int sidx = 63 - (int)(km & 0xffffffffull);
            float esel = __shfl(e, sidx);
            if (lane == 0) {
                selpos_s[b][ts] = sidx;
                nscore_s[b][ts] = logf(esel / den + 1e-20f);
            }
            if (lane == sidx) mlc = -INFINITY;
        }
    }
    __syncthreads();
    if (lane == 0) {
        float acand[BEAM*BEAM], bcand[BEAM*BEAM];
        const int C = B * topk;
        for (int b = 0; b < B; ++b)
            for (int tt = 0; tt < topk; ++tt) {
                int c = b*topk + tt;
                acand[c] = accu[n*BEAM + b] + nscore_s[b][tt];
                float nb = done * ((tt == 0) ? 1.f : 0.f) + (1.f - done);
                bcand[c] = bmask[n*BEAM + b] * nb;
            }
        bool used[BEAM*BEAM];
        for (int c = 0; c < C; ++c) used[c] = false;
        for (int k = 0; k < BEAM; ++k) {
            int bestc;
            if (do_bsel) {
                bestc = 0; float bv = -INFINITY;
                for (int c = 0; c < C; ++c) {
                    if (used[c]) continue;
                    float v = (bcand[c] > 0.f) ? acand[c] : -1e9f;
                    if (v > bv) { bv = v; bestc = c; }
                }
                used[bestc] = true;
            } else bestc = k;
            const int pp = bestc / topk, ss = selpos_s[bestc / topk][bestc % topk];
            parent[n*BEAM + k] = pp;
            posb[n*BEAM + k]   = ss;
            par_s[k] = pp; pos_s[k] = ss;
            accu_out[n*BEAM + k] = acand[bestc];
            bm_out[n*BEAM + k]   = bcand[bestc];
        }
    }
    __syncthreads();
    if (lane < BEAM) {
        const int base = (n*BAo + par_s[lane]) * STo + pos_s[lane];
        lrid[n*BEAM + lane] = idxold[base];
        rrid[n*BEAM + lane] = idxold[base + 1];
    }
    if (dow) {   // cache gather; slots [s-1, s] are left at 0 for k_wscore
        for (int k = 0; k < BEAM; ++k) {
            const int p = par_s[k], s = pos_s[k];
            if (lane < Snew) {
                float v = 0.f;
                if (lane < s - 1)      v = w[(n*BEAM + p)*S0 + lane];
                else if (lane > s)     v = w[(n*BEAM + p)*S0 + lane + 1];
                wnew[(n*BEAM + k)*S0 + lane] = v;
            }
        }
    }
}

// ============ compose: gate softmax + mix + LN -> arena append + table ======
__global__ __launch_bounds__(256) void k_compose(
    const float* __restrict__ cc,
    const _Float16* __restrict__ cha_r, const _Float16* __restrict__ cla_r,
    const int* __restrict__ lrid, const int* __restrict__ rrid,
    const int* __restrict__ parent, const int* __restrict__ posb,
    const int* __restrict__ idxold, int BAo, int STo,
    const float* __restrict__ maskg, int iiter, int Spnew,
    const float* __restrict__ gp, const float* __restrict__ bp,
    _Float16* __restrict__ cha_w, _Float16* __restrict__ cla_w, int newbase,
    int* __restrict__ idxnew, int finalflag, float* __restrict__ nvout)
{
    __shared__ float sb[8];
    const int nk = blockIdx.x, t = threadIdx.x;
    const int n = nk / BEAM;
    size_t lbase, rbase;
    if (finalflag) {
        lbase = (size_t)idxold[nk*31 + 0] * 512;
        rbase = (size_t)idxold[nk*31 + 1] * 512;
    } else {
        lbase = (size_t)lrid[nk] * 512;
        rbase = (size_t)rrid[nk] * 512;
    }
    const float* c = cc + (size_t)nk * CHID;
    float o[2];
    #pragma unroll
    for (int e = 0; e < 2; ++e) {
        const int d = t + 256*e;
        const float lv = recon(cha_r[lbase + d], cla_r[lbase + d]);
        const float rv = recon(cha_r[rbase + d], cla_r[rbase + d]);
        float c0 = c[d], c1 = c[DD + d], c2 = c[2*DD + d], c3 = c[3*DD + d];
        float m = fmaxf(c0, fmaxf(c1, c2));
        float e0 = expf(c0 - m), e1 = expf(c1 - m), e2 = expf(c2 - m);
        float inv = 1.f / (e0 + e1 + e2);
        o[e] = (e0*lv + e1*rv + e2*c3) * inv;
    }
    float s1 = block_reduce_sum(o[0] + o[1], sb);
    float s2 = block_reduce_sum(o[0]*o[0] + o[1]*o[1], sb);
    float mu = s1 * (1.f/512.f);
    float rstd = rsqrtf(s2 * (1.f/512.f) - mu*mu + 1e-5f);
    if (finalflag) {
        #pragma unroll
        for (int e = 0; e < 2; ++e) {
            const int d = t + 256*e;
            nvout[(size_t)nk*DD + d] = (o[e] - mu) * rstd * gp[d] + bp[d];
        }
        return;
    }
    const int arow = newbase + nk;
    #pragma unroll
    for (int e = 0; e < 2; ++e) {
        const int d = t + 256*e;
        float v = (o[e] - mu) * rstd * gp[d] + bp[d];
        _Float16 h = hi16(v);
        cha_w[(size_t)arow*512 + d] = h;
        cla_w[(size_t)arow*512 + d] = lo16(v, h);
    }
    // index-table splice (mask is binary: done==1 splice, done==0 truncate)
    if (t < Spnew) {
        const float done = maskg[n*S0 + iiter + 1];
        const int p = parent[nk], s = posb[nk];
        const int src = (n*BAo + p) * STo;
        int val;
        if (done > 0.5f)
            val = (t < s) ? idxold[src + t] : (t == s ? arow : idxold[src + t + 1]);
        else
            val = idxold[src + t];
        idxnew[nk*31 + t] = val;
    }
}

// ============ final beam softmax mix ============
__global__ __launch_bounds__(256) void k_final(
    const float* __restrict__ nv,
    const _Float16* __restrict__ cha, const _Float16* __restrict__ cla,
    const int* __restrict__ idxt, const float* __restrict__ maskg,
    const float* __restrict__ accu, const float* __restrict__ bmv,
    float* __restrict__ out)
{
    const int n = blockIdx.x, t = threadIdx.x;
    const float done = maskg[n*S0 + 31];
    float sc[BEAM];
    #pragma unroll
    for (int k = 0; k < BEAM; ++k) {
        float m = bmv[n*BEAM + k];
        sc[k] = m * accu[n*BEAM + k] + (1.f - m) * (-999999.f);
    }
    float mx = sc[0];
    #pragma unroll
    for (int k = 1; k < BEAM; ++k) mx = fmaxf(mx, sc[k]);
    float e[BEAM], den = 0.f;
    #pragma unroll
    for (int k = 0; k < BEAM; ++k) { e[k] = expf(sc[k] - mx); den += e[k]; }
    const float inv = 1.f / den;
    #pragma unroll
    for (int i2 = 0; i2 < 2; ++i2) {
        const int d = t + 256*i2;
        float s = 0.f;
        #pragma unroll
        for (int k = 0; k < BEAM; ++k) {
            const int nk = n*BEAM + k;
            const size_t ob = (size_t)idxt[nk*31] * 512;
            const float nvv  = nv[(size_t)nk*DD + d];
            const float oldv = recon(cha[ob + d], cla[ob + d]);
            s += e[k]*inv * (done*nvv + (1.f - done)*oldv);
        }
        out[(size_t)n*DD + d] = s;
    }
}

extern "C" void kernel_launch(void* const* d_in, const int* in_sizes, int n_in,
                              void* d_out, int out_size, void* d_ws, size_t ws_size,
                              hipStream_t stream) {
    (void)in_sizes; (void)n_in; (void)out_size; (void)ws_size;
    const float* x    = (const float*)d_in[0];
    const float* mask = (const float*)d_in[1];
    const float* Wi   = (const float*)d_in[2];
    const float* bi   = (const float*)d_in[3];
    const float* g1   = (const float*)d_in[4];
    const float* b1   = (const float*)d_in[5];
    const float* Wd1  = (const float*)d_in[6];
    const float* bd1  = (const float*)d_in[7];
    const float* Wd2  = (const float*)d_in[8];
    const float* bd2  = (const float*)d_in[9];
    const float* Wc1  = (const float*)d_in[10];
    const float* bc1  = (const float*)d_in[11];
    const float* Wc2  = (const float*)d_in[12];
    const float* bc2  = (const float*)d_in[13];
    const float* g2   = (const float*)d_in[14];
    const float* b2   = (const float*)d_in[15];
    float* out = (float*)d_out;

    // ---- workspace carve-up (bytes), ~150 MB ----
    char* p = (char*)d_ws;
    _Float16* cha = (_Float16*)p;        p += (size_t)AR_TOT*512*2;   // 47.7 MB
    _Float16* cla = (_Float16*)p;        p += (size_t)AR_TOT*512*2;
    _Float16* Wc1th = (_Float16*)p;      p += (size_t)CHID*1024*2;
    _Float16* Wc1tl = (_Float16*)p;      p += (size_t)CHID*1024*2;
    _Float16* Wc2th = (_Float16*)p;      p += (size_t)CHID*CHID*2;
    _Float16* Wc2tl = (_Float16*)p;      p += (size_t)CHID*CHID*2;
    _Float16* Wd1th = (_Float16*)p;      p += (size_t)512*1024*2;
    _Float16* Wd1tl = (_Float16*)p;      p += (size_t)512*1024*2;
    _Float16* Wih = (_Float16*)p;        p += (size_t)WDIM*DD*2;
    _Float16* Wil = (_Float16*)p;        p += (size_t)WDIM*DD*2;
    _Float16* Hh  = (_Float16*)p;        p += (size_t)NB*CHID*2;
    _Float16* Hl  = (_Float16*)p;        p += (size_t)NB*CHID*2;
    float* cb   = (float*)p;             p += (size_t)NB*CHID*4;
    float* nvb  = (float*)p;             p += (size_t)NB*DD*4;
    float* wA   = (float*)p;             p += (size_t)NB*S0*4;
    float* wB   = (float*)p;             p += (size_t)NB*S0*4;
    float* accA = (float*)p;             p += NB*4;
    float* accB = (float*)p;             p += NB*4;
    float* bmA  = (float*)p;             p += NB*4;
    float* bmB  = (float*)p;             p += NB*4;
    int* parent = (int*)p;               p += NB*4;
    int* posb   = (int*)p;               p += NB*4;
    int* lrid   = (int*)p;               p += NB*4;
    int* rrid   = (int*)p;               p += NB*4;
    int* idx0   = (int*)p;               p += AR_INIT*4;
    int* idxA   = (int*)p;               p += NB*31*4;
    int* idxB   = (int*)p;               p += NB*31*4;
    // init-only aliases:
    _Float16* xh = Hh;                   // 4096x512 halfs <= Hh size
    _Float16* xl = Hl;
    float* ybufc = cb;                   // 4096x512 fp32 <= cb size

    // ---- prep ----
    k_tsplit<<<dim3(CHID/32, 1024/32), 256, 0, stream>>>(Wc1, Wc1th, Wc1tl, 1024, CHID);
    k_tsplit<<<dim3(CHID/32, CHID/32), 256, 0, stream>>>(Wc2, Wc2th, Wc2tl, CHID, CHID);
    k_tsplit<<<dim3(512/32, 1024/32), 256, 0, stream>>>(Wd1, Wd1th, Wd1tl, 1024, 512);
    k_tsplit<<<dim3(DD/32, WDIM/32), 256, 0, stream>>>(Wi, Wih, Wil, WDIM, DD);
    k_init_state<<<(NB*S0 + 255)/256, 256, 0, stream>>>(accA, bmA, idx0, wA);

    // ---- init: arena rows 0..8191 = LN(x@Wi+bi), 2 chunks of 4096 ----
    for (int c = 0; c < 2; ++c) {
        const float* xc = x + (size_t)c*4096*WDIM;
        k_xsplit<<<(4096*WDIM)/1024, 256, 0, stream>>>(xc, xh, xl);
        k_mfma_gemm<0,0><<<dim3(DD/128, 4096/128), 256, 0, stream>>>(
            xh, xl, Wih, Wil, bi, ybufc, nullptr, nullptr,
            nullptr, nullptr, nullptr, 4096, DD, WDIM);
        k_ln_init<<<4096, 256, 0, stream>>>(ybufc, g1, b1, cha, cla, c*4096);
    }
    // full scores at i=0: 7936 rows x 4 col-chunks
    k_wscore<0><<<dim3(NN*31/128, 4), 256, 0, stream>>>(
        cha, cla, nullptr, nullptr, Wd1th, Wd1tl, bd1, Wd2, bd2, wA, 31);

    const int* idxcur = idx0;
    int* idxnxt = idxA;
    int BAo = 1, STo = 32;
    float *wcur = wA, *wnxt = wB;
    float *acur = accA, *anxt = accB, *bcur = bmA, *bnxt = bmB;
    for (int i = 0; i < 30; ++i) {
        const int B  = (i == 0) ? 1 : BEAM;
        const int S  = 31 - i;
        const int tk = (S < BEAM) ? S : BEAM;
        const int dob = (B*tk > BEAM) ? 1 : 0;
        const int newbase = AR_INIT + i*NB;
        k_topk<<<NN, 64, 0, stream>>>(wcur, acur, bcur, mask, i, B, S, tk, dob,
                                      idxcur, BAo, STo, parent, posb, lrid, rrid,
                                      anxt, bnxt, wnxt, S - 1, (i < 29) ? 1 : 0);
        k_mfma_gemm<1,1><<<dim3(CHID/128, NB/128), 256, 0, stream>>>(
            cha, cla, Wc1th, Wc1tl, bc1, nullptr, Hh, Hl,
            lrid, rrid, nullptr, NB, CHID, 2*DD);
        k_mfma_gemm<0,0><<<dim3(CHID/128, NB/128), 256, 0, stream>>>(
            Hh, Hl, Wc2th, Wc2tl, bc2, cb, nullptr, nullptr,
            nullptr, nullptr, nullptr, NB, CHID, CHID);
        k_compose<<<NB, 256, 0, stream>>>(cb, cha, cla, lrid, rrid, parent, posb,
                                          idxcur, BAo, STo, mask, i, 31 - i,
                                          g2, b2, cha, cla, newbase, idxnxt,
                                          0, nullptr);
        if (i < 29)
            k_wscore<1><<<dim3(NB*2/128, 4), 256, 0, stream>>>(
                cha, cla, posb, idxnxt, Wd1th, Wd1tl, bd1, Wd2, bd2, wnxt, S - 1);
        // swap
        idxcur = idxnxt;
        idxnxt = (idxnxt == idxA) ? idxB : idxA;
        BAo = BEAM; STo = 31;
        float* tp;
        tp = wcur; wcur = wnxt; wnxt = tp;
        tp = acur; acur = anxt; anxt = tp;
        tp = bcur; bcur = bnxt; bnxt = tp;
    }
    // final compose: l,r = table positions 0,1
    k_mfma_gemm<1,2><<<dim3(CHID/128, NB/128), 256, 0, stream>>>(
        cha, cla, Wc1th, Wc1tl, bc1, nullptr, Hh, Hl,
        nullptr, nullptr, idxcur, NB, CHID, 2*DD);
    k_mfma_gemm<0,0><<<dim3(CHID/128, NB/128), 256, 0, stream>>>(
        Hh, Hl, Wc2th, Wc2tl, bc2, cb, nullptr, nullptr,
        nullptr, nullptr, nullptr, NB, CHID, CHID);
    k_compose<<<NB, 256, 0, stream>>>(cb, cha, cla, nullptr, nullptr, parent, posb,
                                      idxcur, BEAM, 31, mask, 30, 0,
                                      g2, b2, nullptr, nullptr, 0,
                                      nullptr, 1, nvb);
    k_final<<<NN, 256, 0, stream>>>(nvb, cha, cla, idxcur, mask, acur, bcur, out);
}

// Round 8
// 7302.037 us; speedup vs baseline: 1.6800x; 1.1034x over previous
//
#include <hip/hip_runtime.h>
#include <math.h>

// EBT_GRC beam-search forward, round 8: split-K GEMMs (2 blocks/CU co-residency
// to hide the vmcnt(0) barrier drain that capped MfmaUtil at 13.5%), 64x64
// wscore tiles (320-992 blocks). Arena + index tables from round 7 retained.
// N=256, S=32, D=512, CH=2048, BEAM=5. WS ~185 MB.

#define NN   256
#define S0   32
#define WDIM 512
#define DD   512
#define CHID 2048
#define BEAM 5
#define NB   (NN*BEAM)   // 1280
#define RSCALE 2048.0f
#define RINV  (1.0f/2048.0f)
#define AR_INIT 8192
#define AR_TOT  (AR_INIT + 30*NB)    // 46592 rows
#define MN2 ((size_t)NB*CHID)        // 2,621,440: partial-buffer slice stride

typedef __attribute__((ext_vector_type(8))) _Float16 f16x8;
typedef __attribute__((ext_vector_type(4))) float f32x4;

__device__ __forceinline__ float gelu_f(float x) {
    return 0.5f * x * (1.0f + erff(x * 0.7071067811865475f));
}
__device__ __forceinline__ _Float16 hi16(float v) { return (_Float16)v; }
__device__ __forceinline__ _Float16 lo16(float v, _Float16 h) {
    return (_Float16)((v - (float)h) * RSCALE);
}
__device__ __forceinline__ float recon(_Float16 h, _Float16 l) {
    return (float)h + RINV * (float)l;
}

__device__ __forceinline__ void gload_lds16(const void* g, void* l) {
    __builtin_amdgcn_global_load_lds(
        (const __attribute__((address_space(1))) unsigned*)g,
        (__attribute__((address_space(3))) unsigned*)l, 16, 0, 0);
}

__device__ __forceinline__ float block_reduce_sum(float v, float* sb) {
    #pragma unroll
    for (int o = 32; o > 0; o >>= 1) v += __shfl_down(v, o);
    const int lane = threadIdx.x & 63, wid = threadIdx.x >> 6;
    __syncthreads();
    if (lane == 0) sb[wid] = v;
    __syncthreads();
    return sb[0] + sb[1] + sb[2] + sb[3];
}

// ================= fp16x2 scaled-split MFMA GEMM, split-K =================
// A = Ah + RINV*Al. B^T = Bh + RINV*Bl (N x Ktot). blockIdx.z picks K-chunk
// [z*Kchunk, z*Kchunk+Kchunk); partial fp32 written to Cf + z*M*N. z==0 adds
// bias. AIDX 0: A row m at Ah[m*Ktot]. AIDX 1: cat rows lrid[m]/rrid[m]
// (Ktot=1024, k<512 l-row else r-row). AIDX 2: rows idxt[m*31+{0,1}].
template<int AIDX>
__global__ __launch_bounds__(256, 1) void k_gemm(
    const _Float16* __restrict__ Ah, const _Float16* __restrict__ Al,
    const _Float16* __restrict__ Bh, const _Float16* __restrict__ Bl,
    const float* __restrict__ bias, float* __restrict__ Cf,
    const int* __restrict__ lrid, const int* __restrict__ rrid,
    const int* __restrict__ idxt,
    int M, int N, int Ktot, int Kchunk)
{
    __shared__ __align__(16) _Float16 lds[4 * 4096];
    const int t = threadIdx.x, wave = t >> 6, lane = t & 63;
    const int bm = blockIdx.y * 128, bn = blockIdx.x * 128;
    const int koff = blockIdx.z * Kchunk;
    const int wm = (wave >> 1) * 64, wn = (wave & 1) * 64;
    const int rsub = lane >> 2, seg = lane & 3;
    const int fm = lane & 15, fko = (lane >> 4) * 8;

    size_t lb[2], rb[2];
    #pragma unroll
    for (int j = 0; j < 2; ++j) {
        const int q = wave * 2 + j;
        const int rowm = bm + q*16 + rsub;
        if (AIDX == 0) { lb[j] = (size_t)rowm * Ktot; rb[j] = 0; }
        else if (AIDX == 1) {
            lb[j] = (size_t)lrid[rowm] * 512;
            rb[j] = (size_t)rrid[rowm] * 512;
        } else {
            lb[j] = (size_t)idxt[rowm*31 + 0] * 512;
            rb[j] = (size_t)idxt[rowm*31 + 1] * 512;
        }
    }

    f32x4 acc0[4][4], acc1[4][4];
    #pragma unroll
    for (int i = 0; i < 4; ++i)
        #pragma unroll
        for (int j = 0; j < 4; ++j) {
            acc0[i][j] = (f32x4){0.f, 0.f, 0.f, 0.f};
            acc1[i][j] = (f32x4){0.f, 0.f, 0.f, 0.f};
        }

    for (int k0 = 0; k0 < Kchunk; k0 += 32) {
        const int k = koff + k0;
        __syncthreads();
        #pragma unroll
        for (int j = 0; j < 2; ++j) {
            const int q = wave * 2 + j;
            const size_t aoff = ((AIDX == 0) ? lb[j] + k
                                : (k < 512 ? lb[j] + k : rb[j] + (k - 512)))
                                + seg * 8;
            const size_t boff = (size_t)(bn + q*16 + rsub) * Ktot + k + seg * 8;
            gload_lds16(Ah + aoff, &lds[0*4096 + q*512]);
            gload_lds16(Al + aoff, &lds[1*4096 + q*512]);
            gload_lds16(Bh + boff, &lds[2*4096 + q*512]);
            gload_lds16(Bl + boff, &lds[3*4096 + q*512]);
        }
        __syncthreads();
        f16x8 ah[4], al[4];
        #pragma unroll
        for (int i = 0; i < 4; ++i) {
            const int ar = wm + i*16 + fm;
            ah[i] = *(const f16x8*)&lds[0*4096 + ar*32 + fko];
            al[i] = *(const f16x8*)&lds[1*4096 + ar*32 + fko];
        }
        #pragma unroll
        for (int j = 0; j < 4; ++j) {
            const int br = wn + j*16 + fm;
            f16x8 bh = *(const f16x8*)&lds[2*4096 + br*32 + fko];
            f16x8 bl = *(const f16x8*)&lds[3*4096 + br*32 + fko];
            #pragma unroll
            for (int i = 0; i < 4; ++i) {
                acc0[i][j] = __builtin_amdgcn_mfma_f32_16x16x32_f16(ah[i], bh, acc0[i][j], 0, 0, 0);
                acc1[i][j] = __builtin_amdgcn_mfma_f32_16x16x32_f16(ah[i], bl, acc1[i][j], 0, 0, 0);
                acc1[i][j] = __builtin_amdgcn_mfma_f32_16x16x32_f16(al[i], bh, acc1[i][j], 0, 0, 0);
            }
        }
    }
    float* dst = Cf + (size_t)blockIdx.z * M * N;
    #pragma unroll
    for (int i = 0; i < 4; ++i)
        #pragma unroll
        for (int j = 0; j < 4; ++j) {
            const int col = bn + wn + j*16 + fm;
            const float bv = (blockIdx.z == 0) ? bias[col] : 0.f;
            #pragma unroll
            for (int r = 0; r < 4; ++r) {
                const int row = bm + wm + i*16 + (lane >> 4)*4 + r;
                dst[(size_t)row * N + col] = acc0[i][j][r] + acc1[i][j][r] * RINV + bv;
            }
        }
}

// ============ GEMM1 epilogue: H = gelu(P0+P1) -> fp16 h/l ============
__global__ __launch_bounds__(256) void k_hact(
    const float* __restrict__ P, _Float16* __restrict__ Oh,
    _Float16* __restrict__ Ol)
{
    const size_t b = (size_t)blockIdx.x * CHID + threadIdx.x * 8;
    float4 a0 = *(const float4*)(P + b);
    float4 a1 = *(const float4*)(P + b + 4);
    float4 q0 = *(const float4*)(P + MN2 + b);
    float4 q1 = *(const float4*)(P + MN2 + b + 4);
    float v[8] = {a0.x+q0.x, a0.y+q0.y, a0.z+q0.z, a0.w+q0.w,
                  a1.x+q1.x, a1.y+q1.y, a1.z+q1.z, a1.w+q1.w};
    f16x8 h, l;
    #pragma unroll
    for (int e = 0; e < 8; ++e) {
        float g = gelu_f(v[e]);
        _Float16 hh = hi16(g);
        h[e] = hh; l[e] = lo16(g, hh);
    }
    *(f16x8*)(Oh + b) = h;
    *(f16x8*)(Ol + b) = l;
}

// ============ fused score: w += partial of gelu(cat@Wd1+bd1)@Wd2 ============
// 64 rows x 64 cols per block; blockIdx.y = col chunk (0..7). Target w slots
// pre-zeroed. ny==0 adds bd2.
// MODE 0 (init): row r -> n=r/31, s=r%31; arena rows n*32+s, +1.
// MODE 1 (incr): r -> nk=r>>1, jw=posb[nk]-1+(r&1); rows from idxt.
template<int MODE>
__global__ __launch_bounds__(256, 2) void k_wscore(
    const _Float16* __restrict__ ch, const _Float16* __restrict__ cl,
    const int* __restrict__ posb, const int* __restrict__ idxt,
    const _Float16* __restrict__ Bh, const _Float16* __restrict__ Bl,
    const float* __restrict__ bd1, const float* __restrict__ u512,
    const float* __restrict__ bd2, float* __restrict__ w, int Spairs)
{
    __shared__ __align__(16) _Float16 lds[4 * 2048];   // A h/l 64x32, B h/l 64x32
    const int t = threadIdx.x, wave = t >> 6, lane = t & 63;
    const int bm = blockIdx.x * 64, ncol0 = blockIdx.y * 64;
    const int rsub = lane >> 2, seg = lane & 3;
    const int fm = lane & 15, quad = lane >> 4, fko = quad * 8;

    // wave's A slab = its own 16 rows (rows bm+wave*16 .. +16)
    size_t lb, rb;
    {
        const int rowm = bm + wave*16 + rsub;
        int lrow, rrow;
        if (MODE == 0) {
            const int n = rowm / 31, s = rowm - n * 31;
            lrow = n*32 + s; rrow = lrow + 1;
        } else {
            const int nk = rowm >> 1, slot = rowm & 1;
            const int s = posb[nk];
            int jw = s - 1 + slot;
            int jc = jw < 0 ? 0 : (jw > Spairs - 1 ? Spairs - 1 : jw);
            lrow = idxt[nk*31 + jc]; rrow = idxt[nk*31 + jc + 1];
        }
        lb = (size_t)lrow * 512; rb = (size_t)rrow * 512;
    }
    const size_t bbase = (size_t)(ncol0 + wave*16 + rsub) * 1024;

    f32x4 acc0[4], acc1[4];
    #pragma unroll
    for (int j = 0; j < 4; ++j) {
        acc0[j] = (f32x4){0.f, 0.f, 0.f, 0.f};
        acc1[j] = (f32x4){0.f, 0.f, 0.f, 0.f};
    }
    for (int k0 = 0; k0 < 1024; k0 += 32) {
        __syncthreads();
        const size_t aoff = (k0 < 512 ? lb + k0 : rb + (k0 - 512)) + seg * 8;
        gload_lds16(ch + aoff, &lds[0*2048 + wave*512]);
        gload_lds16(cl + aoff, &lds[1*2048 + wave*512]);
        gload_lds16(Bh + bbase + k0 + seg*8, &lds[2*2048 + wave*512]);
        gload_lds16(Bl + bbase + k0 + seg*8, &lds[3*2048 + wave*512]);
        __syncthreads();
        const int ar = wave*16 + fm;
        f16x8 ah = *(const f16x8*)&lds[0*2048 + ar*32 + fko];
        f16x8 al = *(const f16x8*)&lds[1*2048 + ar*32 + fko];
        #pragma unroll
        for (int j = 0; j < 4; ++j) {
            const int br = j*16 + fm;
            f16x8 bh = *(const f16x8*)&lds[2*2048 + br*32 + fko];
            f16x8 bl = *(const f16x8*)&lds[3*2048 + br*32 + fko];
            acc0[j] = __builtin_amdgcn_mfma_f32_16x16x32_f16(ah, bh, acc0[j], 0, 0, 0);
            acc1[j] = __builtin_amdgcn_mfma_f32_16x16x32_f16(ah, bl, acc1[j], 0, 0, 0);
            acc1[j] = __builtin_amdgcn_mfma_f32_16x16x32_f16(al, bh, acc1[j], 0, 0, 0);
        }
    }
    float part[4] = {0.f, 0.f, 0.f, 0.f};
    #pragma unroll
    for (int j = 0; j < 4; ++j) {
        const int col = ncol0 + j*16 + fm;
        const float bv = bd1[col], uv = u512[col];
        #pragma unroll
        for (int r = 0; r < 4; ++r) {
            float v = acc0[j][r] + acc1[j][r] * RINV + bv;
            part[r] += gelu_f(v) * uv;
        }
    }
    #pragma unroll
    for (int r = 0; r < 4; ++r) {
        float s = part[r];
        s += __shfl_xor(s, 1); s += __shfl_xor(s, 2);
        s += __shfl_xor(s, 4); s += __shfl_xor(s, 8);
        part[r] = s;
    }
    if (fm == 0) {
        const float bd2v = (blockIdx.y == 0) ? bd2[0] : 0.f;
        #pragma unroll
        for (int r = 0; r < 4; ++r) {
            const int rowm = bm + wave*16 + quad*4 + r;
            int wi = -1;
            if (MODE == 0) {
                const int n = rowm / 31, s = rowm - n * 31;
                wi = n * BEAM * S0 + s;
            } else {
                const int nk = rowm >> 1, slot = rowm & 1;
                const int jw = posb[nk] - 1 + slot;
                if (jw >= 0 && jw < Spairs) wi = nk * S0 + jw;
            }
            if (wi >= 0) atomicAdd(&w[wi], part[r] + bd2v);
        }
    }
}

// ============ weight transpose + fp16 split ============
__global__ __launch_bounds__(256) void k_tsplit(
    const float* __restrict__ in, _Float16* __restrict__ oh,
    _Float16* __restrict__ ol, int K, int N)
{
    __shared__ float tile[32][33];
    const int bx = blockIdx.x * 32, by = blockIdx.y * 32;
    const int t = threadIdx.x, r = t >> 5, c = t & 31;
    #pragma unroll
    for (int p = 0; p < 4; ++p)
        tile[r + p*8][c] = in[(size_t)(by + r + p*8) * N + bx + c];
    __syncthreads();
    #pragma unroll
    for (int p = 0; p < 4; ++p) {
        const int nl = r + p*8;
        float v = tile[c][nl];
        _Float16 h = hi16(v);
        oh[(size_t)(bx + nl) * K + by + c] = h;
        ol[(size_t)(bx + nl) * K + by + c] = lo16(v, h);
    }
}

// ============ elementwise fp16 split (x rows, init only) ============
__global__ __launch_bounds__(256) void k_xsplit(
    const float* __restrict__ in, _Float16* __restrict__ oh,
    _Float16* __restrict__ ol)
{
    const size_t i = ((size_t)blockIdx.x * 256 + threadIdx.x) * 4;
    float4 v = *(const float4*)(in + i);
    _Float16 h0 = hi16(v.x), h1 = hi16(v.y), h2 = hi16(v.z), h3 = hi16(v.w);
    typedef __attribute__((ext_vector_type(4))) _Float16 f16x4v;
    f16x4v h = {h0, h1, h2, h3};
    f16x4v l = {lo16(v.x,h0), lo16(v.y,h1), lo16(v.z,h2), lo16(v.w,h3)};
    *(f16x4v*)(oh + i) = h;
    *(f16x4v*)(ol + i) = l;
}

// ============ init layernorm -> split arena rows ============
__global__ __launch_bounds__(256) void k_ln_init(
    const float* __restrict__ y, const float* __restrict__ g,
    const float* __restrict__ b, _Float16* __restrict__ cha,
    _Float16* __restrict__ cla)
{
    const int row = blockIdx.x;
    const float* yr = y + (size_t)row * DD;
    const int t = threadIdx.x;
    float v0 = yr[t], v1 = yr[t + 256];
    __shared__ float sb[8];
    float s1 = block_reduce_sum(v0 + v1, sb);
    float s2 = block_reduce_sum(v0*v0 + v1*v1, sb);
    float mu = s1 * (1.f/512.f);
    float rstd = rsqrtf(s2 * (1.f/512.f) - mu*mu + 1e-5f);
    float a0 = (v0 - mu) * rstd * g[t]       + b[t];
    float a1 = (v1 - mu) * rstd * g[t + 256] + b[t + 256];
    _Float16 h0 = hi16(a0), h1 = hi16(a1);
    cha[(size_t)row*DD + t]       = h0;
    cla[(size_t)row*DD + t]       = lo16(a0, h0);
    cha[(size_t)row*DD + t + 256] = h1;
    cla[(size_t)row*DD + t + 256] = lo16(a1, h1);
}

__global__ void k_init_state(float* accu, float* bm, int* idx0, float* wz) {
    int i = blockIdx.x * blockDim.x + threadIdx.x;
    if (i < NB*S0) wz[i] = 0.f;
    if (i < AR_INIT) idx0[i] = i;
    if (i < NB) { accu[i] = 0.f; bm[i] = 1.f; }
}

// ============ top-k + beam select + score-cache gather + l/r row ids ========
__global__ __launch_bounds__(64) void k_topk(
    const float* __restrict__ w, const float* __restrict__ accu,
    const float* __restrict__ bmask, const float* __restrict__ maskg,
    int iiter, int B, int S, int topk, int do_bsel,
    const int* __restrict__ idxold, int BAo, int STo,
    int* __restrict__ parent, int* __restrict__ posb,
    int* __restrict__ lrid, int* __restrict__ rrid,
    float* __restrict__ accu_out, float* __restrict__ bm_out,
    float* __restrict__ wnew, int Snew, int dow)
{
    const int n = blockIdx.x, lane = threadIdx.x;
    __shared__ int   selpos_s[BEAM][BEAM];
    __shared__ float nscore_s[BEAM][BEAM];
    __shared__ int   par_s[BEAM], pos_s[BEAM];
    const float* mrow = maskg + n*S0 + (iiter + 1);
    const float mk   = (lane < S) ? mrow[lane] : 0.f;
    const float done = 1.f - mrow[0];
    for (int b = 0; b < B; ++b) {
        float ml;
        if (lane < S) {
            float wv = w[(n*BEAM + b)*S0 + lane];
            ml = (mk > 0.f) ? wv : -1e9f;
        } else ml = -INFINITY;
        float mx = ml;
        #pragma unroll
        for (int o = 32; o > 0; o >>= 1) mx = fmaxf(mx, __shfl_xor(mx, o));
        float e = (lane < S) ? expf(ml - mx) * mk : 0.f;
        float es = e;
        #pragma unroll
        for (int o = 32; o > 0; o >>= 1) es += __shfl_xor(es, o);
        const float den = es + 1e-20f;
        float mlc = ml;
        for (int ts = 0; ts < topk; ++ts) {
            unsigned int fb = __float_as_uint(mlc);
            unsigned int ok = (fb & 0x80000000u) ? ~fb : (fb | 0x80000000u);
            unsigned long long key =
                ((unsigned long long)ok << 32) | (unsigned int)(63 - lane);
            if (lane >= S) key = 0ull;
            unsigned long long km = key;
            #pragma unroll
            for (int o = 32; o > 0; o >>= 1) {
                unsigned long long oth = __shfl_xor(km, o);
                km = (oth > km) ? oth : km;
            }
            int sidx = 63 - (int)(km & 0xffffffffull);
            float esel = __shfl(e, sidx);
            if (lane == 0) {
                selpos_s[b][ts] = sidx;
                nscore_s[b][ts] = logf(esel / den + 1e-20f);
            }
            if (lane == sidx) mlc = -INFINITY;
        }
    }
    __syncthreads();
    if (lane == 0) {
        float acand[BEAM*BEAM], bcand[BEAM*BEAM];
        const int C = B * topk;
        for (int b = 0; b < B; ++b)
            for (int tt = 0; tt < topk; ++tt) {
                int c = b*topk + tt;
                acand[c] = accu[n*BEAM + b] + nscore_s[b][tt];
                float nb = done * ((tt == 0) ? 1.f : 0.f) + (1.f - done);
                bcand[c] = bmask[n*BEAM + b] * nb;
            }
        bool used[BEAM*BEAM];
        for (int c = 0; c < C; ++c) used[c] = false;
        for (int k = 0; k < BEAM; ++k) {
            int bestc;
            if (do_bsel) {
                bestc = 0; float bv = -INFINITY;
                for (int c = 0; c < C; ++c) {
                    if (used[c]) continue;
                    float v = (bcand[c] > 0.f) ? acand[c] : -1e9f;
                    if (v > bv) { bv = v; bestc = c; }
                }
                used[bestc] = true;
            } else bestc = k;
            const int pp = bestc / topk, ss = selpos_s[bestc / topk][bestc % topk];
            parent[n*BEAM + k] = pp;
            posb[n*BEAM + k]   = ss;
            par_s[k] = pp; pos_s[k] = ss;
            accu_out[n*BEAM + k] = acand[bestc];
            bm_out[n*BEAM + k]   = bcand[bestc];
        }
    }
    __syncthreads();
    if (lane < BEAM) {
        const int base = (n*BAo + par_s[lane]) * STo + pos_s[lane];
        lrid[n*BEAM + lane] = idxold[base];
        rrid[n*BEAM + lane] = idxold[base + 1];
    }
    if (dow) {   // cache gather; slots [s-1, s] zeroed for k_wscore's atomics
        for (int k = 0; k < BEAM; ++k) {
            const int p = par_s[k], s = pos_s[k];
            if (lane < Snew) {
                float v = 0.f;
                if (lane < s - 1)      v = w[(n*BEAM + p)*S0 + lane];
                else if (lane > s)     v = w[(n*BEAM + p)*S0 + lane + 1];
                wnew[(n*BEAM + k)*S0 + lane] = v;
            }
        }
    }
}

// ============ compose: sum 4 partials + gate softmax + mix + LN -> arena ====
__global__ __launch_bounds__(256) void k_compose(
    const float* __restrict__ P,
    const _Float16* __restrict__ cha_r, const _Float16* __restrict__ cla_r,
    const int* __restrict__ lrid, const int* __restrict__ rrid,
    const int* __restrict__ parent, const int* __restrict__ posb,
    const int* __restrict__ idxold, int BAo, int STo,
    const float* __restrict__ maskg, int iiter, int Spnew,
    const float* __restrict__ gp, const float* __restrict__ bp,
    _Float16* __restrict__ cha_w, _Float16* __restrict__ cla_w, int newbase,
    int* __restrict__ idxnew, int finalflag, float* __restrict__ nvout)
{
    __shared__ float sb[8];
    const int nk = blockIdx.x, t = threadIdx.x;
    const int n = nk / BEAM;
    size_t lbase, rbase;
    if (finalflag) {
        lbase = (size_t)idxold[nk*31 + 0] * 512;
        rbase = (size_t)idxold[nk*31 + 1] * 512;
    } else {
        lbase = (size_t)lrid[nk] * 512;
        rbase = (size_t)rrid[nk] * 512;
    }
    const float* c = P + (size_t)nk * CHID;
    float o[2];
    #pragma unroll
    for (int e = 0; e < 2; ++e) {
        const int d = t + 256*e;
        const float lv = recon(cha_r[lbase + d], cla_r[lbase + d]);
        const float rv = recon(cha_r[rbase + d], cla_r[rbase + d]);
        float c0 = ((c[d]         + c[MN2 + d])         + c[2*MN2 + d])         + c[3*MN2 + d];
        float c1 = ((c[DD + d]    + c[MN2 + DD + d])    + c[2*MN2 + DD + d])    + c[3*MN2 + DD + d];
        float c2 = ((c[2*DD + d]  + c[MN2 + 2*DD + d])  + c[2*MN2 + 2*DD + d])  + c[3*MN2 + 2*DD + d];
        float c3 = ((c[3*DD + d]  + c[MN2 + 3*DD + d])  + c[2*MN2 + 3*DD + d])  + c[3*MN2 + 3*DD + d];
        float m = fmaxf(c0, fmaxf(c1, c2));
        float e0 = expf(c0 - m), e1 = expf(c1 - m), e2 = expf(c2 - m);
        float inv = 1.f / (e0 + e1 + e2);
        o[e] = (e0*lv + e1*rv + e2*c3) * inv;
    }
    float s1 = block_reduce_sum(o[0] + o[1], sb);
    float s2 = block_reduce_sum(o[0]*o[0] + o[1]*o[1], sb);
    float mu = s1 * (1.f/512.f);
    float rstd = rsqrtf(s2 * (1.f/512.f) - mu*mu + 1e-5f);
    if (finalflag) {
        #pragma unroll
        for (int e = 0; e < 2; ++e) {
            const int d = t + 256*e;
            nvout[(size_t)nk*DD + d] = (o[e] - mu) * rstd * gp[d] + bp[d];
        }
        return;
    }
    const int arow = newbase + nk;
    #pragma unroll
    for (int e = 0; e < 2; ++e) {
        const int d = t + 256*e;
        float v = (o[e] - mu) * rstd * gp[d] + bp[d];
        _Float16 h = hi16(v);
        cha_w[(size_t)arow*512 + d] = h;
        cla_w[(size_t)arow*512 + d] = lo16(v, h);
    }
    if (t < Spnew) {
        const float done = maskg[n*S0 + iiter + 1];
        const int p = parent[nk], s = posb[nk];
        const int src = (n*BAo + p) * STo;
        int val;
        if (done > 0.5f)
            val = (t < s) ? idxold[src + t] : (t == s ? arow : idxold[src + t + 1]);
        else
            val = idxold[src + t];
        idxnew[nk*31 + t] = val;
    }
}

// ============ final beam softmax mix ============
__global__ __launch_bounds__(256) void k_final(
    const float* __restrict__ nv,
    const _Float16* __restrict__ cha, const _Float16* __restrict__ cla,
    const int* __restrict__ idxt, const float* __restrict__ maskg,
    const float* __restrict__ accu, const float* __restrict__ bmv,
    float* __restrict__ out)
{
    const int n = blockIdx.x, t = threadIdx.x;
    const float done = maskg[n*S0 + 31];
    float sc[BEAM];
    #pragma unroll
    for (int k = 0; k < BEAM; ++k) {
        float m = bmv[n*BEAM + k];
        sc[k] = m * accu[n*BEAM + k] + (1.f - m) * (-999999.f);
    }
    float mx = sc[0];
    #pragma unroll
    for (int k = 1; k < BEAM; ++k) mx = fmaxf(mx, sc[k]);
    float e[BEAM], den = 0.f;
    #pragma unroll
    for (int k = 0; k < BEAM; ++k) { e[k] = expf(sc[k] - mx); den += e[k]; }
    const float inv = 1.f / den;
    #pragma unroll
    for (int i2 = 0; i2 < 2; ++i2) {
        const int d = t + 256*i2;
        float s = 0.f;
        #pragma unroll
        for (int k = 0; k < BEAM; ++k) {
            const int nk = n*BEAM + k;
            const size_t ob = (size_t)idxt[nk*31] * 512;
            const float nvv  = nv[(size_t)nk*DD + d];
            const float oldv = recon(cha[ob + d], cla[ob + d]);
            s += e[k]*inv * (done*nvv + (1.f - done)*oldv);
        }
        out[(size_t)n*DD + d] = s;
    }
}

extern "C" void kernel_launch(void* const* d_in, const int* in_sizes, int n_in,
                              void* d_out, int out_size, void* d_ws, size_t ws_size,
                              hipStream_t stream) {
    (void)in_sizes; (void)n_in; (void)out_size; (void)ws_size;
    const float* x    = (const float*)d_in[0];
    const float* mask = (const float*)d_in[1];
    const float* Wi   = (const float*)d_in[2];
    const float* bi   = (const float*)d_in[3];
    const float* g1   = (const float*)d_in[4];
    const float* b1   = (const float*)d_in[5];
    const float* Wd1  = (const float*)d_in[6];
    const float* bd1  = (const float*)d_in[7];
    const float* Wd2  = (const float*)d_in[8];
    const float* bd2  = (const float*)d_in[9];
    const float* Wc1  = (const float*)d_in[10];
    const float* bc1  = (const float*)d_in[11];
    const float* Wc2  = (const float*)d_in[12];
    const float* bc2  = (const float*)d_in[13];
    const float* g2   = (const float*)d_in[14];
    const float* b2   = (const float*)d_in[15];
    float* out = (float*)d_out;

    // ---- workspace carve-up (bytes), ~185 MB ----
    char* p = (char*)d_ws;
    _Float16* cha = (_Float16*)p;        p += (size_t)AR_TOT*512*2;   // 47.7 MB
    _Float16* cla = (_Float16*)p;        p += (size_t)AR_TOT*512*2;
    _Float16* Wc1th = (_Float16*)p;      p += (size_t)CHID*1024*2;
    _Float16* Wc1tl = (_Float16*)p;      p += (size_t)CHID*1024*2;
    _Float16* Wc2th = (_Float16*)p;      p += (size_t)CHID*CHID*2;
    _Float16* Wc2tl = (_Float16*)p;      p += (size_t)CHID*CHID*2;
    _Float16* Wd1th = (_Float16*)p;      p += (size_t)512*1024*2;
    _Float16* Wd1tl = (_Float16*)p;      p += (size_t)512*1024*2;
    _Float16* Wih = (_Float16*)p;        p += (size_t)WDIM*DD*2;
    _Float16* Wil = (_Float16*)p;        p += (size_t)WDIM*DD*2;
    _Float16* Hh  = (_Float16*)p;        p += (size_t)NB*CHID*2;
    _Float16* Hl  = (_Float16*)p;        p += (size_t)NB*CHID*2;
    float* Pb   = (float*)p;             p += MN2*4*4;                // 42 MB (4 slices)
    float* nvb  = (float*)p;             p += (size_t)NB*DD*4;
    float* wA   = (float*)p;             p += (size_t)NB*S0*4;
    float* wB   = (float*)p;             p += (size_t)NB*S0*4;
    float* accA = (float*)p;             p += NB*4;
    float* accB = (float*)p;             p += NB*4;
    float* bmA  = (float*)p;             p += NB*4;
    float* bmB  = (float*)p;             p += NB*4;
    int* parent = (int*)p;               p += NB*4;
    int* posb   = (int*)p;               p += NB*4;
    int* lrid   = (int*)p;               p += NB*4;
    int* rrid   = (int*)p;               p += NB*4;
    int* idx0   = (int*)p;               p += AR_INIT*4;
    int* idxA   = (int*)p;               p += NB*31*4;
    int* idxB   = (int*)p;               p += NB*31*4;
    // init-only aliases inside Pb (42 MB): xh 8.4 + xl 8.4 + ybuf 16.8 = 33.6
    _Float16* xh = (_Float16*)Pb;
    _Float16* xl = (_Float16*)((char*)Pb + (size_t)AR_INIT*512*2);
    float* ybuf  = (float*)((char*)Pb + (size_t)AR_INIT*512*4);

    // ---- prep ----
    k_tsplit<<<dim3(CHID/32, 1024/32), 256, 0, stream>>>(Wc1, Wc1th, Wc1tl, 1024, CHID);
    k_tsplit<<<dim3(CHID/32, CHID/32), 256, 0, stream>>>(Wc2, Wc2th, Wc2tl, CHID, CHID);
    k_tsplit<<<dim3(512/32, 1024/32), 256, 0, stream>>>(Wd1, Wd1th, Wd1tl, 1024, 512);
    k_tsplit<<<dim3(DD/32, WDIM/32), 256, 0, stream>>>(Wi, Wih, Wil, WDIM, DD);
    k_init_state<<<(NB*S0 + 255)/256, 256, 0, stream>>>(accA, bmA, idx0, wA);

    // ---- init: arena rows 0..8191 = LN(x@Wi+bi), single 8192-row GEMM ----
    k_xsplit<<<(AR_INIT*WDIM)/1024, 256, 0, stream>>>(x, xh, xl);
    k_gemm<0><<<dim3(DD/128, AR_INIT/128, 1), 256, 0, stream>>>(
        xh, xl, Wih, Wil, bi, ybuf, nullptr, nullptr, nullptr,
        AR_INIT, DD, WDIM, WDIM);
    k_ln_init<<<AR_INIT, 256, 0, stream>>>(ybuf, g1, b1, cha, cla);
    // full scores at i=0: 7936 rows x 8 col-chunks = 992 blocks
    k_wscore<0><<<dim3(NN*31/64, 8), 256, 0, stream>>>(
        cha, cla, nullptr, nullptr, Wd1th, Wd1tl, bd1, Wd2, bd2, wA, 31);

    const int* idxcur = idx0;
    int* idxnxt = idxA;
    int BAo = 1, STo = 32;
    float *wcur = wA, *wnxt = wB;
    float *acur = accA, *anxt = accB, *bcur = bmA, *bnxt = bmB;
    for (int i = 0; i < 30; ++i) {
        const int B  = (i == 0) ? 1 : BEAM;
        const int S  = 31 - i;
        const int tk = (S < BEAM) ? S : BEAM;
        const int dob = (B*tk > BEAM) ? 1 : 0;
        const int newbase = AR_INIT + i*NB;
        k_topk<<<NN, 64, 0, stream>>>(wcur, acur, bcur, mask, i, B, S, tk, dob,
                                      idxcur, BAo, STo, parent, posb, lrid, rrid,
                                      anxt, bnxt, wnxt, S - 1, (i < 29) ? 1 : 0);
        k_gemm<1><<<dim3(CHID/128, NB/128, 2), 256, 0, stream>>>(
            cha, cla, Wc1th, Wc1tl, bc1, Pb, lrid, rrid, nullptr,
            NB, CHID, 2*DD, DD);
        k_hact<<<NB, 256, 0, stream>>>(Pb, Hh, Hl);
        k_gemm<0><<<dim3(CHID/128, NB/128, 4), 256, 0, stream>>>(
            Hh, Hl, Wc2th, Wc2tl, bc2, Pb, nullptr, nullptr, nullptr,
            NB, CHID, CHID, DD);
        k_compose<<<NB, 256, 0, stream>>>(Pb, cha, cla, lrid, rrid, parent, posb,
                                          idxcur, BAo, STo, mask, i, 31 - i,
                                          g2, b2, cha, cla, newbase, idxnxt,
                                          0, nullptr);
        if (i < 29)
            k_wscore<1><<<dim3(NB*2/64, 8), 256, 0, stream>>>(
                cha, cla, posb, idxnxt, Wd1th, Wd1tl, bd1, Wd2, bd2, wnxt, S - 1);
        idxcur = idxnxt;
        idxnxt = (idxnxt == idxA) ? idxB : idxA;
        BAo = BEAM; STo = 31;
        float* tp;
        tp = wcur; wcur = wnxt; wnxt = tp;
        tp = acur; acur = anxt; anxt = tp;
        tp = bcur; bcur = bnxt; bnxt = tp;
    }
    // final compose: l,r = table positions 0,1
    k_gemm<2><<<dim3(CHID/128, NB/128, 2), 256, 0, stream>>>(
        cha, cla, Wc1th, Wc1tl, bc1, Pb, nullptr, nullptr, idxcur,
        NB, CHID, 2*DD, DD);
    k_hact<<<NB, 256, 0, stream>>>(Pb, Hh, Hl);
    k_gemm<0><<<dim3(CHID/128, NB/128, 4), 256, 0, stream>>>(
        Hh, Hl, Wc2th, Wc2tl, bc2, Pb, nullptr, nullptr, nullptr,
        NB, CHID, CHID, DD);
    k_compose<<<NB, 256, 0, stream>>>(Pb, cha, cla, nullptr, nullptr, parent, posb,
                                      idxcur, BEAM, 31, mask, 30, 0,
                                      g2, b2, nullptr, nullptr, 0,
                                      nullptr, 1, nvb);
    k_final<<<NN, 256, 0, stream>>>(nvb, cha, cla, idxcur, mask, acur, bcur, out);
}

// Round 9
// 7087.794 us; speedup vs baseline: 1.7308x; 1.0302x over previous
//
#include <hip/hip_runtime.h>
#include <math.h>

// EBT_GRC beam-search forward, round 9: cut split-K partial traffic (GEMM2
// z=4->2: 41->20.5 MB writes) and fuse GEMM1 epilogue (128x64 tiles, no
// split-K, no k_hact, no partials). Arena + index tables retained.
// N=256, S=32, D=512, CH=2048, BEAM=5. WS ~185 MB.

#define NN   256
#define S0   32
#define WDIM 512
#define DD   512
#define CHID 2048
#define BEAM 5
#define NB   (NN*BEAM)   // 1280
#define RSCALE 2048.0f
#define RINV  (1.0f/2048.0f)
#define AR_INIT 8192
#define AR_TOT  (AR_INIT + 30*NB)    // 46592 rows
#define MN2 ((size_t)NB*CHID)        // partial-buffer slice stride

typedef __attribute__((ext_vector_type(8))) _Float16 f16x8;
typedef __attribute__((ext_vector_type(4))) float f32x4;

__device__ __forceinline__ float gelu_f(float x) {
    return 0.5f * x * (1.0f + erff(x * 0.7071067811865475f));
}
__device__ __forceinline__ _Float16 hi16(float v) { return (_Float16)v; }
__device__ __forceinline__ _Float16 lo16(float v, _Float16 h) {
    return (_Float16)((v - (float)h) * RSCALE);
}
__device__ __forceinline__ float recon(_Float16 h, _Float16 l) {
    return (float)h + RINV * (float)l;
}

__device__ __forceinline__ void gload_lds16(const void* g, void* l) {
    __builtin_amdgcn_global_load_lds(
        (const __attribute__((address_space(1))) unsigned*)g,
        (__attribute__((address_space(3))) unsigned*)l, 16, 0, 0);
}

__device__ __forceinline__ float block_reduce_sum(float v, float* sb) {
    #pragma unroll
    for (int o = 32; o > 0; o >>= 1) v += __shfl_down(v, o);
    const int lane = threadIdx.x & 63, wid = threadIdx.x >> 6;
    __syncthreads();
    if (lane == 0) sb[wid] = v;
    __syncthreads();
    return sb[0] + sb[1] + sb[2] + sb[3];
}

// ================= fp16x2 scaled-split MFMA GEMM, split-K =================
// blockIdx.z picks K-chunk; partial fp32 -> Cf + z*M*N; z==0 adds bias.
// AIDX 0: A row m at Ah[m*Ktot].
template<int AIDX>
__global__ __launch_bounds__(256, 1) void k_gemm(
    const _Float16* __restrict__ Ah, const _Float16* __restrict__ Al,
    const _Float16* __restrict__ Bh, const _Float16* __restrict__ Bl,
    const float* __restrict__ bias, float* __restrict__ Cf,
    int M, int N, int Ktot, int Kchunk)
{
    __shared__ __align__(16) _Float16 lds[4 * 4096];
    const int t = threadIdx.x, wave = t >> 6, lane = t & 63;
    const int bm = blockIdx.y * 128, bn = blockIdx.x * 128;
    const int koff = blockIdx.z * Kchunk;
    const int wm = (wave >> 1) * 64, wn = (wave & 1) * 64;
    const int rsub = lane >> 2, seg = lane & 3;
    const int fm = lane & 15, fko = (lane >> 4) * 8;

    f32x4 acc0[4][4], acc1[4][4];
    #pragma unroll
    for (int i = 0; i < 4; ++i)
        #pragma unroll
        for (int j = 0; j < 4; ++j) {
            acc0[i][j] = (f32x4){0.f, 0.f, 0.f, 0.f};
            acc1[i][j] = (f32x4){0.f, 0.f, 0.f, 0.f};
        }

    for (int k0 = 0; k0 < Kchunk; k0 += 32) {
        const int k = koff + k0;
        __syncthreads();
        #pragma unroll
        for (int j = 0; j < 2; ++j) {
            const int q = wave * 2 + j;
            const size_t aoff = (size_t)(bm + q*16 + rsub) * Ktot + k + seg * 8;
            const size_t boff = (size_t)(bn + q*16 + rsub) * Ktot + k + seg * 8;
            gload_lds16(Ah + aoff, &lds[0*4096 + q*512]);
            gload_lds16(Al + aoff, &lds[1*4096 + q*512]);
            gload_lds16(Bh + boff, &lds[2*4096 + q*512]);
            gload_lds16(Bl + boff, &lds[3*4096 + q*512]);
        }
        __syncthreads();
        f16x8 ah[4], al[4];
        #pragma unroll
        for (int i = 0; i < 4; ++i) {
            const int ar = wm + i*16 + fm;
            ah[i] = *(const f16x8*)&lds[0*4096 + ar*32 + fko];
            al[i] = *(const f16x8*)&lds[1*4096 + ar*32 + fko];
        }
        #pragma unroll
        for (int j = 0; j < 4; ++j) {
            const int br = wn + j*16 + fm;
            f16x8 bh = *(const f16x8*)&lds[2*4096 + br*32 + fko];
            f16x8 bl = *(const f16x8*)&lds[3*4096 + br*32 + fko];
            #pragma unroll
            for (int i = 0; i < 4; ++i) {
                acc0[i][j] = __builtin_amdgcn_mfma_f32_16x16x32_f16(ah[i], bh, acc0[i][j], 0, 0, 0);
                acc1[i][j] = __builtin_amdgcn_mfma_f32_16x16x32_f16(ah[i], bl, acc1[i][j], 0, 0, 0);
                acc1[i][j] = __builtin_amdgcn_mfma_f32_16x16x32_f16(al[i], bh, acc1[i][j], 0, 0, 0);
            }
        }
    }
    float* dst = Cf + (size_t)blockIdx.z * M * N;
    #pragma unroll
    for (int i = 0; i < 4; ++i)
        #pragma unroll
        for (int j = 0; j < 4; ++j) {
            const int col = bn + wn + j*16 + fm;
            const float bv = (blockIdx.z == 0) ? bias[col] : 0.f;
            #pragma unroll
            for (int r = 0; r < 4; ++r) {
                const int row = bm + wm + i*16 + (lane >> 4)*4 + r;
                dst[(size_t)row * N + col] = acc0[i][j][r] + acc1[i][j][r] * RINV + bv;
            }
        }
}

// ========== GEMM1 fused: H = gelu(cat@Wc1+bc1) -> fp16 h/l, 128x64 tiles ====
// AIDX 1: cat rows lrid/rrid. AIDX 2: rows idxt[m*31+{0,1}]. K=1024 fixed.
// Grid (N/64, M/128). Wave w: rows [w*32,w*32+32) x 64 cols. No partials.
template<int AIDX>
__global__ __launch_bounds__(256, 1) void k_gemm1(
    const _Float16* __restrict__ Ah, const _Float16* __restrict__ Al,
    const _Float16* __restrict__ Bh, const _Float16* __restrict__ Bl,
    const float* __restrict__ bias,
    _Float16* __restrict__ Oh, _Float16* __restrict__ Ol,
    const int* __restrict__ lrid, const int* __restrict__ rrid,
    const int* __restrict__ idxt, int N)
{
    __shared__ __align__(16) _Float16 lds[12288];  // Ah[128x32] Al Bh[64x32] Bl
    const int t = threadIdx.x, wave = t >> 6, lane = t & 63;
    const int bm = blockIdx.y * 128, bn = blockIdx.x * 64;
    const int rsub = lane >> 2, seg = lane & 3;
    const int fm = lane & 15, quad = lane >> 4, fko = quad * 8;

    // this wave stages A slabs {2w, 2w+1} (16 rows each) and B slabs h/l #w
    size_t lb[2], rb[2];
    #pragma unroll
    for (int j = 0; j < 2; ++j) {
        const int rowm = bm + (wave*2 + j)*16 + rsub;
        if (AIDX == 1) {
            lb[j] = (size_t)lrid[rowm] * 512;
            rb[j] = (size_t)rrid[rowm] * 512;
        } else {
            lb[j] = (size_t)idxt[rowm*31 + 0] * 512;
            rb[j] = (size_t)idxt[rowm*31 + 1] * 512;
        }
    }
    const size_t bbase = (size_t)(bn + wave*16 + rsub) * 1024;

    f32x4 acc0[2][4], acc1[2][4];
    #pragma unroll
    for (int i = 0; i < 2; ++i)
        #pragma unroll
        for (int j = 0; j < 4; ++j) {
            acc0[i][j] = (f32x4){0.f, 0.f, 0.f, 0.f};
            acc1[i][j] = (f32x4){0.f, 0.f, 0.f, 0.f};
        }

    for (int k0 = 0; k0 < 1024; k0 += 32) {
        __syncthreads();
        #pragma unroll
        for (int j = 0; j < 2; ++j) {
            const int q = wave*2 + j;
            const size_t aoff = (k0 < 512 ? lb[j] + k0 : rb[j] + (k0 - 512)) + seg*8;
            gload_lds16(Ah + aoff, &lds[q*512]);            // A_h
            gload_lds16(Al + aoff, &lds[4096 + q*512]);     // A_l
        }
        gload_lds16(Bh + bbase + k0 + seg*8, &lds[8192 + wave*512]);
        gload_lds16(Bl + bbase + k0 + seg*8, &lds[10240 + wave*512]);
        __syncthreads();
        f16x8 ah[2], al[2];
        #pragma unroll
        for (int i = 0; i < 2; ++i) {
            const int ar = wave*32 + i*16 + fm;
            ah[i] = *(const f16x8*)&lds[ar*32 + fko];
            al[i] = *(const f16x8*)&lds[4096 + ar*32 + fko];
        }
        #pragma unroll
        for (int j = 0; j < 4; ++j) {
            const int br = j*16 + fm;
            f16x8 bh = *(const f16x8*)&lds[8192 + br*32 + fko];
            f16x8 bl = *(const f16x8*)&lds[10240 + br*32 + fko];
            #pragma unroll
            for (int i = 0; i < 2; ++i) {
                acc0[i][j] = __builtin_amdgcn_mfma_f32_16x16x32_f16(ah[i], bh, acc0[i][j], 0, 0, 0);
                acc1[i][j] = __builtin_amdgcn_mfma_f32_16x16x32_f16(ah[i], bl, acc1[i][j], 0, 0, 0);
                acc1[i][j] = __builtin_amdgcn_mfma_f32_16x16x32_f16(al[i], bh, acc1[i][j], 0, 0, 0);
            }
        }
    }
    #pragma unroll
    for (int i = 0; i < 2; ++i)
        #pragma unroll
        for (int j = 0; j < 4; ++j) {
            const int col = bn + j*16 + fm;
            const float bv = bias[col];
            #pragma unroll
            for (int r = 0; r < 4; ++r) {
                const int row = bm + wave*32 + i*16 + quad*4 + r;
                float v = gelu_f(acc0[i][j][r] + acc1[i][j][r] * RINV + bv);
                _Float16 h = hi16(v);
                Oh[(size_t)row * N + col] = h;
                Ol[(size_t)row * N + col] = lo16(v, h);
            }
        }
}

// ============ fused score: w += partial of gelu(cat@Wd1+bd1)@Wd2 ============
template<int MODE>
__global__ __launch_bounds__(256, 2) void k_wscore(
    const _Float16* __restrict__ ch, const _Float16* __restrict__ cl,
    const int* __restrict__ posb, const int* __restrict__ idxt,
    const _Float16* __restrict__ Bh, const _Float16* __restrict__ Bl,
    const float* __restrict__ bd1, const float* __restrict__ u512,
    const float* __restrict__ bd2, float* __restrict__ w, int Spairs)
{
    __shared__ __align__(16) _Float16 lds[4 * 2048];
    const int t = threadIdx.x, wave = t >> 6, lane = t & 63;
    const int bm = blockIdx.x * 64, ncol0 = blockIdx.y * 64;
    const int rsub = lane >> 2, seg = lane & 3;
    const int fm = lane & 15, quad = lane >> 4, fko = quad * 8;

    size_t lb, rb;
    {
        const int rowm = bm + wave*16 + rsub;
        int lrow, rrow;
        if (MODE == 0) {
            const int n = rowm / 31, s = rowm - n * 31;
            lrow = n*32 + s; rrow = lrow + 1;
        } else {
            const int nk = rowm >> 1, slot = rowm & 1;
            const int s = posb[nk];
            int jw = s - 1 + slot;
            int jc = jw < 0 ? 0 : (jw > Spairs - 1 ? Spairs - 1 : jw);
            lrow = idxt[nk*31 + jc]; rrow = idxt[nk*31 + jc + 1];
        }
        lb = (size_t)lrow * 512; rb = (size_t)rrow * 512;
    }
    const size_t bbase = (size_t)(ncol0 + wave*16 + rsub) * 1024;

    f32x4 acc0[4], acc1[4];
    #pragma unroll
    for (int j = 0; j < 4; ++j) {
        acc0[j] = (f32x4){0.f, 0.f, 0.f, 0.f};
        acc1[j] = (f32x4){0.f, 0.f, 0.f, 0.f};
    }
    for (int k0 = 0; k0 < 1024; k0 += 32) {
        __syncthreads();
        const size_t aoff = (k0 < 512 ? lb + k0 : rb + (k0 - 512)) + seg * 8;
        gload_lds16(ch + aoff, &lds[0*2048 + wave*512]);
        gload_lds16(cl + aoff, &lds[1*2048 + wave*512]);
        gload_lds16(Bh + bbase + k0 + seg*8, &lds[2*2048 + wave*512]);
        gload_lds16(Bl + bbase + k0 + seg*8, &lds[3*2048 + wave*512]);
        __syncthreads();
        const int ar = wave*16 + fm;
        f16x8 ah = *(const f16x8*)&lds[0*2048 + ar*32 + fko];
        f16x8 al = *(const f16x8*)&lds[1*2048 + ar*32 + fko];
        #pragma unroll
        for (int j = 0; j < 4; ++j) {
            const int br = j*16 + fm;
            f16x8 bh = *(const f16x8*)&lds[2*2048 + br*32 + fko];
            f16x8 bl = *(const f16x8*)&lds[3*2048 + br*32 + fko];
            acc0[j] = __builtin_amdgcn_mfma_f32_16x16x32_f16(ah, bh, acc0[j], 0, 0, 0);
            acc1[j] = __builtin_amdgcn_mfma_f32_16x16x32_f16(ah, bl, acc1[j], 0, 0, 0);
            acc1[j] = __builtin_amdgcn_mfma_f32_16x16x32_f16(al, bh, acc1[j], 0, 0, 0);
        }
    }
    float part[4] = {0.f, 0.f, 0.f, 0.f};
    #pragma unroll
    for (int j = 0; j < 4; ++j) {
        const int col = ncol0 + j*16 + fm;
        const float bv = bd1[col], uv = u512[col];
        #pragma unroll
        for (int r = 0; r < 4; ++r) {
            float v = acc0[j][r] + acc1[j][r] * RINV + bv;
            part[r] += gelu_f(v) * uv;
        }
    }
    #pragma unroll
    for (int r = 0; r < 4; ++r) {
        float s = part[r];
        s += __shfl_xor(s, 1); s += __shfl_xor(s, 2);
        s += __shfl_xor(s, 4); s += __shfl_xor(s, 8);
        part[r] = s;
    }
    if (fm == 0) {
        const float bd2v = (blockIdx.y == 0) ? bd2[0] : 0.f;
        #pragma unroll
        for (int r = 0; r < 4; ++r) {
            const int rowm = bm + wave*16 + quad*4 + r;
            int wi = -1;
            if (MODE == 0) {
                const int n = rowm / 31, s = rowm - n * 31;
                wi = n * BEAM * S0 + s;
            } else {
                const int nk = rowm >> 1, slot = rowm & 1;
                const int jw = posb[nk] - 1 + slot;
                if (jw >= 0 && jw < Spairs) wi = nk * S0 + jw;
            }
            if (wi >= 0) atomicAdd(&w[wi], part[r] + bd2v);
        }
    }
}

// ============ weight transpose + fp16 split ============
__global__ __launch_bounds__(256) void k_tsplit(
    const float* __restrict__ in, _Float16* __restrict__ oh,
    _Float16* __restrict__ ol, int K, int N)
{
    __shared__ float tile[32][33];
    const int bx = blockIdx.x * 32, by = blockIdx.y * 32;
    const int t = threadIdx.x, r = t >> 5, c = t & 31;
    #pragma unroll
    for (int p = 0; p < 4; ++p)
        tile[r + p*8][c] = in[(size_t)(by + r + p*8) * N + bx + c];
    __syncthreads();
    #pragma unroll
    for (int p = 0; p < 4; ++p) {
        const int nl = r + p*8;
        float v = tile[c][nl];
        _Float16 h = hi16(v);
        oh[(size_t)(bx + nl) * K + by + c] = h;
        ol[(size_t)(bx + nl) * K + by + c] = lo16(v, h);
    }
}

// ============ elementwise fp16 split (x rows, init only) ============
__global__ __launch_bounds__(256) void k_xsplit(
    const float* __restrict__ in, _Float16* __restrict__ oh,
    _Float16* __restrict__ ol)
{
    const size_t i = ((size_t)blockIdx.x * 256 + threadIdx.x) * 4;
    float4 v = *(const float4*)(in + i);
    _Float16 h0 = hi16(v.x), h1 = hi16(v.y), h2 = hi16(v.z), h3 = hi16(v.w);
    typedef __attribute__((ext_vector_type(4))) _Float16 f16x4v;
    f16x4v h = {h0, h1, h2, h3};
    f16x4v l = {lo16(v.x,h0), lo16(v.y,h1), lo16(v.z,h2), lo16(v.w,h3)};
    *(f16x4v*)(oh + i) = h;
    *(f16x4v*)(ol + i) = l;
}

// ============ init layernorm -> split arena rows ============
__global__ __launch_bounds__(256) void k_ln_init(
    const float* __restrict__ y, const float* __restrict__ g,
    const float* __restrict__ b, _Float16* __restrict__ cha,
    _Float16* __restrict__ cla)
{
    const int row = blockIdx.x;
    const float* yr = y + (size_t)row * DD;
    const int t = threadIdx.x;
    float v0 = yr[t], v1 = yr[t + 256];
    __shared__ float sb[8];
    float s1 = block_reduce_sum(v0 + v1, sb);
    float s2 = block_reduce_sum(v0*v0 + v1*v1, sb);
    float mu = s1 * (1.f/512.f);
    float rstd = rsqrtf(s2 * (1.f/512.f) - mu*mu + 1e-5f);
    float a0 = (v0 - mu) * rstd * g[t]       + b[t];
    float a1 = (v1 - mu) * rstd * g[t + 256] + b[t + 256];
    _Float16 h0 = hi16(a0), h1 = hi16(a1);
    cha[(size_t)row*DD + t]       = h0;
    cla[(size_t)row*DD + t]       = lo16(a0, h0);
    cha[(size_t)row*DD + t + 256] = h1;
    cla[(size_t)row*DD + t + 256] = lo16(a1, h1);
}

__global__ void k_init_state(float* accu, float* bm, int* idx0, float* wz) {
    int i = blockIdx.x * blockDim.x + threadIdx.x;
    if (i < NB*S0) wz[i] = 0.f;
    if (i < AR_INIT) idx0[i] = i;
    if (i < NB) { accu[i] = 0.f; bm[i] = 1.f; }
}

// ============ top-k + beam select + score-cache gather + l/r row ids ========
__global__ __launch_bounds__(64) void k_topk(
    const float* __restrict__ w, const float* __restrict__ accu,
    const float* __restrict__ bmask, const float* __restrict__ maskg,
    int iiter, int B, int S, int topk, int do_bsel,
    const int* __restrict__ idxold, int BAo, int STo,
    int* __restrict__ parent, int* __restrict__ posb,
    int* __restrict__ lrid, int* __restrict__ rrid,
    float* __restrict__ accu_out, float* __restrict__ bm_out,
    float* __restrict__ wnew, int Snew, int dow)
{
    const int n = blockIdx.x, lane = threadIdx.x;
    __shared__ int   selpos_s[BEAM][BEAM];
    __shared__ float nscore_s[BEAM][BEAM];
    __shared__ int   par_s[BEAM], pos_s[BEAM];
    const float* mrow = maskg + n*S0 + (iiter + 1);
    const float mk   = (lane < S) ? mrow[lane] : 0.f;
    const float done = 1.f - mrow[0];
    for (int b = 0; b < B; ++b) {
        float ml;
        if (lane < S) {
            float wv = w[(n*BEAM + b)*S0 + lane];
            ml = (mk > 0.f) ? wv : -1e9f;
        } else ml = -INFINITY;
        float mx = ml;
        #pragma unroll
        for (int o = 32; o > 0; o >>= 1) mx = fmaxf(mx, __shfl_xor(mx, o));
        float e = (lane < S) ? expf(ml - mx) * mk : 0.f;
        float es = e;
        #pragma unroll
        for (int o = 32; o > 0; o >>= 1) es += __shfl_xor(es, o);
        const float den = es + 1e-20f;
        float mlc = ml;
        for (int ts = 0; ts < topk; ++ts) {
            unsigned int fb = __float_as_uint(mlc);
            unsigned int ok = (fb & 0x80000000u) ? ~fb : (fb | 0x80000000u);
            unsigned long long key =
                ((unsigned long long)ok << 32) | (unsigned int)(63 - lane);
            if (lane >= S) key = 0ull;
            unsigned long long km = key;
            #pragma unroll
            for (int o = 32; o > 0; o >>= 1) {
                unsigned long long oth = __shfl_xor(km, o);
                km = (oth > km) ? oth : km;
            }
            int sidx = 63 - (int)(km & 0xffffffffull);
            float esel = __shfl(e, sidx);
            if (lane == 0) {
                selpos_s[b][ts] = sidx;
                nscore_s[b][ts] = logf(esel / den + 1e-20f);
            }
            if (lane == sidx) mlc = -INFINITY;
        }
    }
    __syncthreads();
    if (lane == 0) {
        float acand[BEAM*BEAM], bcand[BEAM*BEAM];
        const int C = B * topk;
        for (int b = 0; b < B; ++b)
            for (int tt = 0; tt < topk; ++tt) {
                int c = b*topk + tt;
                acand[c] = accu[n*BEAM + b] + nscore_s[b][tt];
                float nb = done * ((tt == 0) ? 1.f : 0.f) + (1.f - done);
                bcand[c] = bmask[n*BEAM + b] * nb;
            }
        bool used[BEAM*BEAM];
        for (int c = 0; c < C; ++c) used[c] = false;
        for (int k = 0; k < BEAM; ++k) {
            int bestc;
            if (do_bsel) {
                bestc = 0; float bv = -INFINITY;
                for (int c = 0; c < C; ++c) {
                    if (used[c]) continue;
                    float v = (bcand[c] > 0.f) ? acand[c] : -1e9f;
                    if (v > bv) { bv = v; bestc = c; }
                }
                used[bestc] = true;
            } else bestc = k;
            const int pp = bestc / topk, ss = selpos_s[bestc / topk][bestc % topk];
            parent[n*BEAM + k] = pp;
            posb[n*BEAM + k]   = ss;
            par_s[k] = pp; pos_s[k] = ss;
            accu_out[n*BEAM + k] = acand[bestc];
            bm_out[n*BEAM + k]   = bcand[bestc];
        }
    }
    __syncthreads();
    if (lane < BEAM) {
        const int base = (n*BAo + par_s[lane]) * STo + pos_s[lane];
        lrid[n*BEAM + lane] = idxold[base];
        rrid[n*BEAM + lane] = idxold[base + 1];
    }
    if (dow) {
        for (int k = 0; k < BEAM; ++k) {
            const int p = par_s[k], s = pos_s[k];
            if (lane < Snew) {
                float v = 0.f;
                if (lane < s - 1)      v = w[(n*BEAM + p)*S0 + lane];
                else if (lane > s)     v = w[(n*BEAM + p)*S0 + lane + 1];
                wnew[(n*BEAM + k)*S0 + lane] = v;
            }
        }
    }
}

// ======== compose: sum 2 partials + gate softmax + mix + LN -> arena ========
__global__ __launch_bounds__(256) void k_compose(
    const float* __restrict__ P,
    const _Float16* __restrict__ cha_r, const _Float16* __restrict__ cla_r,
    const int* __restrict__ lrid, const int* __restrict__ rrid,
    const int* __restrict__ parent, const int* __restrict__ posb,
    const int* __restrict__ idxold, int BAo, int STo,
    const float* __restrict__ maskg, int iiter, int Spnew,
    const float* __restrict__ gp, const float* __restrict__ bp,
    _Float16* __restrict__ cha_w, _Float16* __restrict__ cla_w, int newbase,
    int* __restrict__ idxnew, int finalflag, float* __restrict__ nvout)
{
    __shared__ float sb[8];
    const int nk = blockIdx.x, t = threadIdx.x;
    const int n = nk / BEAM;
    size_t lbase, rbase;
    if (finalflag) {
        lbase = (size_t)idxold[nk*31 + 0] * 512;
        rbase = (size_t)idxold[nk*31 + 1] * 512;
    } else {
        lbase = (size_t)lrid[nk] * 512;
        rbase = (size_t)rrid[nk] * 512;
    }
    const float* c = P + (size_t)nk * CHID;
    float o[2];
    #pragma unroll
    for (int e = 0; e < 2; ++e) {
        const int d = t + 256*e;
        const float lv = recon(cha_r[lbase + d], cla_r[lbase + d]);
        const float rv = recon(cha_r[rbase + d], cla_r[rbase + d]);
        float c0 = c[d]        + c[MN2 + d];
        float c1 = c[DD + d]   + c[MN2 + DD + d];
        float c2 = c[2*DD + d] + c[MN2 + 2*DD + d];
        float c3 = c[3*DD + d] + c[MN2 + 3*DD + d];
        float m = fmaxf(c0, fmaxf(c1, c2));
        float e0 = expf(c0 - m), e1 = expf(c1 - m), e2 = expf(c2 - m);
        float inv = 1.f / (e0 + e1 + e2);
        o[e] = (e0*lv + e1*rv + e2*c3) * inv;
    }
    float s1 = block_reduce_sum(o[0] + o[1], sb);
    float s2 = block_reduce_sum(o[0]*o[0] + o[1]*o[1], sb);
    float mu = s1 * (1.f/512.f);
    float rstd = rsqrtf(s2 * (1.f/512.f) - mu*mu + 1e-5f);
    if (finalflag) {
        #pragma unroll
        for (int e = 0; e < 2; ++e) {
            const int d = t + 256*e;
            nvout[(size_t)nk*DD + d] = (o[e] - mu) * rstd * gp[d] + bp[d];
        }
        return;
    }
    const int arow = newbase + nk;
    #pragma unroll
    for (int e = 0; e < 2; ++e) {
        const int d = t + 256*e;
        float v = (o[e] - mu) * rstd * gp[d] + bp[d];
        _Float16 h = hi16(v);
        cha_w[(size_t)arow*512 + d] = h;
        cla_w[(size_t)arow*512 + d] = lo16(v, h);
    }
    if (t < Spnew) {
        const float done = maskg[n*S0 + iiter + 1];
        const int p = parent[nk], s = posb[nk];
        const int src = (n*BAo + p) * STo;
        int val;
        if (done > 0.5f)
            val = (t < s) ? idxold[src + t] : (t == s ? arow : idxold[src + t + 1]);
        else
            val = idxold[src + t];
        idxnew[nk*31 + t] = val;
    }
}

// ============ final beam softmax mix ============
__global__ __launch_bounds__(256) void k_final(
    const float* __restrict__ nv,
    const _Float16* __restrict__ cha, const _Float16* __restrict__ cla,
    const int* __restrict__ idxt, const float* __restrict__ maskg,
    const float* __restrict__ accu, const float* __restrict__ bmv,
    float* __restrict__ out)
{
    const int n = blockIdx.x, t = threadIdx.x;
    const float done = maskg[n*S0 + 31];
    float sc[BEAM];
    #pragma unroll
    for (int k = 0; k < BEAM; ++k) {
        float m = bmv[n*BEAM + k];
        sc[k] = m * accu[n*BEAM + k] + (1.f - m) * (-999999.f);
    }
    float mx = sc[0];
    #pragma unroll
    for (int k = 1; k < BEAM; ++k) mx = fmaxf(mx, sc[k]);
    float e[BEAM], den = 0.f;
    #pragma unroll
    for (int k = 0; k < BEAM; ++k) { e[k] = expf(sc[k] - mx); den += e[k]; }
    const float inv = 1.f / den;
    #pragma unroll
    for (int i2 = 0; i2 < 2; ++i2) {
        const int d = t + 256*i2;
        float s = 0.f;
        #pragma unroll
        for (int k = 0; k < BEAM; ++k) {
            const int nk = n*BEAM + k;
            const size_t ob = (size_t)idxt[nk*31] * 512;
            const float nvv  = nv[(size_t)nk*DD + d];
            const float oldv = recon(cha[ob + d], cla[ob + d]);
            s += e[k]*inv * (done*nvv + (1.f - done)*oldv);
        }
        out[(size_t)n*DD + d] = s;
    }
}

extern "C" void kernel_launch(void* const* d_in, const int* in_sizes, int n_in,
                              void* d_out, int out_size, void* d_ws, size_t ws_size,
                              hipStream_t stream) {
    (void)in_sizes; (void)n_in; (void)out_size; (void)ws_size;
    const float* x    = (const float*)d_in[0];
    const float* mask = (const float*)d_in[1];
    const float* Wi   = (const float*)d_in[2];
    const float* bi   = (const float*)d_in[3];
    const float* g1   = (const float*)d_in[4];
    const float* b1   = (const float*)d_in[5];
    const float* Wd1  = (const float*)d_in[6];
    const float* bd1  = (const float*)d_in[7];
    const float* Wd2  = (const float*)d_in[8];
    const float* bd2  = (const float*)d_in[9];
    const float* Wc1  = (const float*)d_in[10];
    const float* bc1  = (const float*)d_in[11];
    const float* Wc2  = (const float*)d_in[12];
    const float* bc2  = (const float*)d_in[13];
    const float* g2   = (const float*)d_in[14];
    const float* b2   = (const float*)d_in[15];
    float* out = (float*)d_out;

    // ---- workspace carve-up (bytes), ~185 MB ----
    char* p = (char*)d_ws;
    _Float16* cha = (_Float16*)p;        p += (size_t)AR_TOT*512*2;
    _Float16* cla = (_Float16*)p;        p += (size_t)AR_TOT*512*2;
    _Float16* Wc1th = (_Float16*)p;      p += (size_t)CHID*1024*2;
    _Float16* Wc1tl = (_Float16*)p;      p += (size_t)CHID*1024*2;
    _Float16* Wc2th = (_Float16*)p;      p += (size_t)CHID*CHID*2;
    _Float16* Wc2tl = (_Float16*)p;      p += (size_t)CHID*CHID*2;
    _Float16* Wd1th = (_Float16*)p;      p += (size_t)512*1024*2;
    _Float16* Wd1tl = (_Float16*)p;      p += (size_t)512*1024*2;
    _Float16* Wih = (_Float16*)p;        p += (size_t)WDIM*DD*2;
    _Float16* Wil = (_Float16*)p;        p += (size_t)WDIM*DD*2;
    _Float16* Hh  = (_Float16*)p;        p += (size_t)NB*CHID*2;
    _Float16* Hl  = (_Float16*)p;        p += (size_t)NB*CHID*2;
    float* Pb   = (float*)p;             p += MN2*4*4;                // 4 slices alloc (2 used)
    float* nvb  = (float*)p;             p += (size_t)NB*DD*4;
    float* wA   = (float*)p;             p += (size_t)NB*S0*4;
    float* wB   = (float*)p;             p += (size_t)NB*S0*4;
    float* accA = (float*)p;             p += NB*4;
    float* accB = (float*)p;             p += NB*4;
    float* bmA  = (float*)p;             p += NB*4;
    float* bmB  = (float*)p;             p += NB*4;
    int* parent = (int*)p;               p += NB*4;
    int* posb   = (int*)p;               p += NB*4;
    int* lrid   = (int*)p;               p += NB*4;
    int* rrid   = (int*)p;               p += NB*4;
    int* idx0   = (int*)p;               p += AR_INIT*4;
    int* idxA   = (int*)p;               p += NB*31*4;
    int* idxB   = (int*)p;               p += NB*31*4;
    // init-only aliases inside Pb
    _Float16* xh = (_Float16*)Pb;
    _Float16* xl = (_Float16*)((char*)Pb + (size_t)AR_INIT*512*2);
    float* ybuf  = (float*)((char*)Pb + (size_t)AR_INIT*512*4);

    // ---- prep ----
    k_tsplit<<<dim3(CHID/32, 1024/32), 256, 0, stream>>>(Wc1, Wc1th, Wc1tl, 1024, CHID);
    k_tsplit<<<dim3(CHID/32, CHID/32), 256, 0, stream>>>(Wc2, Wc2th, Wc2tl, CHID, CHID);
    k_tsplit<<<dim3(512/32, 1024/32), 256, 0, stream>>>(Wd1, Wd1th, Wd1tl, 1024, 512);
    k_tsplit<<<dim3(DD/32, WDIM/32), 256, 0, stream>>>(Wi, Wih, Wil, WDIM, DD);
    k_init_state<<<(NB*S0 + 255)/256, 256, 0, stream>>>(accA, bmA, idx0, wA);

    // ---- init: arena rows 0..8191 = LN(x@Wi+bi) ----
    k_xsplit<<<(AR_INIT*WDIM)/1024, 256, 0, stream>>>(x, xh, xl);
    k_gemm<0><<<dim3(DD/128, AR_INIT/128, 1), 256, 0, stream>>>(
        xh, xl, Wih, Wil, bi, ybuf, AR_INIT, DD, WDIM, WDIM);
    k_ln_init<<<AR_INIT, 256, 0, stream>>>(ybuf, g1, b1, cha, cla);
    k_wscore<0><<<dim3(NN*31/64, 8), 256, 0, stream>>>(
        cha, cla, nullptr, nullptr, Wd1th, Wd1tl, bd1, Wd2, bd2, wA, 31);

    const int* idxcur = idx0;
    int* idxnxt = idxA;
    int BAo = 1, STo = 32;
    float *wcur = wA, *wnxt = wB;
    float *acur = accA, *anxt = accB, *bcur = bmA, *bnxt = bmB;
    for (int i = 0; i < 30; ++i) {
        const int B  = (i == 0) ? 1 : BEAM;
        const int S  = 31 - i;
        const int tk = (S < BEAM) ? S : BEAM;
        const int dob = (B*tk > BEAM) ? 1 : 0;
        const int newbase = AR_INIT + i*NB;
        k_topk<<<NN, 64, 0, stream>>>(wcur, acur, bcur, mask, i, B, S, tk, dob,
                                      idxcur, BAo, STo, parent, posb, lrid, rrid,
                                      anxt, bnxt, wnxt, S - 1, (i < 29) ? 1 : 0);
        k_gemm1<1><<<dim3(CHID/64, NB/128), 256, 0, stream>>>(
            cha, cla, Wc1th, Wc1tl, bc1, Hh, Hl, lrid, rrid, nullptr, CHID);
        k_gemm<0><<<dim3(CHID/128, NB/128, 2), 256, 0, stream>>>(
            Hh, Hl, Wc2th, Wc2tl, bc2, Pb, NB, CHID, CHID, 1024);
        k_compose<<<NB, 256, 0, stream>>>(Pb, cha, cla, lrid, rrid, parent, posb,
                                          idxcur, BAo, STo, mask, i, 31 - i,
                                          g2, b2, cha, cla, newbase, idxnxt,
                                          0, nullptr);
        if (i < 29)
            k_wscore<1><<<dim3(NB*2/64, 8), 256, 0, stream>>>(
                cha, cla, posb, idxnxt, Wd1th, Wd1tl, bd1, Wd2, bd2, wnxt, S - 1);
        idxcur = idxnxt;
        idxnxt = (idxnxt == idxA) ? idxB : idxA;
        BAo = BEAM; STo = 31;
        float* tp;
        tp = wcur; wcur = wnxt; wnxt = tp;
        tp = acur; acur = anxt; anxt = tp;
        tp = bcur; bcur = bnxt; bnxt = tp;
    }
    // final compose: l,r = table positions 0,1
    k_gemm1<2><<<dim3(CHID/64, NB/128), 256, 0, stream>>>(
        cha, cla, Wc1th, Wc1tl, bc1, Hh, Hl, nullptr, nullptr, idxcur, CHID);
    k_gemm<0><<<dim3(CHID/128, NB/128, 2), 256, 0, stream>>>(
        Hh, Hl, Wc2th, Wc2tl, bc2, Pb, NB, CHID, CHID, 1024);
    k_compose<<<NB, 256, 0, stream>>>(Pb, cha, cla, nullptr, nullptr, parent, posb,
                                      idxcur, BEAM, 31, mask, 30, 0,
                                      g2, b2, nullptr, nullptr, 0,
                                      nullptr, 1, nvb);
    k_final<<<NN, 256, 0, stream>>>(nvb, cha, cla, idxcur, mask, acur, bcur, out);
}

// Round 10
// 5762.749 us; speedup vs baseline: 2.1288x; 1.2299x over previous
//
#include <hip/hip_runtime.h>
#include <math.h>

// EBT_GRC beam-search forward, round 10: double-buffered LDS staging in all
// MFMA kernels (barrier -> prefetch(next) -> compute(cur), overlapping the
// ~900-cyc staging latency that left GEMM2 at 13% MfmaUtil / 7% occupancy),
// GEMM2 back to z=4 (640 blocks). Arena + index tables retained.
// N=256, S=32, D=512, CH=2048, BEAM=5. WS ~185 MB.

#define NN   256
#define S0   32
#define WDIM 512
#define DD   512
#define CHID 2048
#define BEAM 5
#define NB   (NN*BEAM)   // 1280
#define RSCALE 2048.0f
#define RINV  (1.0f/2048.0f)
#define AR_INIT 8192
#define AR_TOT  (AR_INIT + 30*NB)    // 46592 rows
#define MN2 ((size_t)NB*CHID)        // partial-buffer slice stride

typedef __attribute__((ext_vector_type(8))) _Float16 f16x8;
typedef __attribute__((ext_vector_type(4))) float f32x4;

__device__ __forceinline__ float gelu_f(float x) {
    return 0.5f * x * (1.0f + erff(x * 0.7071067811865475f));
}
__device__ __forceinline__ _Float16 hi16(float v) { return (_Float16)v; }
__device__ __forceinline__ _Float16 lo16(float v, _Float16 h) {
    return (_Float16)((v - (float)h) * RSCALE);
}
__device__ __forceinline__ float recon(_Float16 h, _Float16 l) {
    return (float)h + RINV * (float)l;
}

__device__ __forceinline__ void gload_lds16(const void* g, void* l) {
    __builtin_amdgcn_global_load_lds(
        (const __attribute__((address_space(1))) unsigned*)g,
        (__attribute__((address_space(3))) unsigned*)l, 16, 0, 0);
}

__device__ __forceinline__ float block_reduce_sum(float v, float* sb) {
    #pragma unroll
    for (int o = 32; o > 0; o >>= 1) v += __shfl_down(v, o);
    const int lane = threadIdx.x & 63, wid = threadIdx.x >> 6;
    __syncthreads();
    if (lane == 0) sb[wid] = v;
    __syncthreads();
    return sb[0] + sb[1] + sb[2] + sb[3];
}

// ================= fp16x2 split MFMA GEMM, split-K, LDS dbuf =================
// blockIdx.z picks K-chunk; partial fp32 -> Cf + z*M*N; z==0 adds bias.
// AIDX 0: A row m at Ah[m*Ktot].
template<int AIDX>
__global__ __launch_bounds__(256, 1) void k_gemm(
    const _Float16* __restrict__ Ah, const _Float16* __restrict__ Al,
    const _Float16* __restrict__ Bh, const _Float16* __restrict__ Bl,
    const float* __restrict__ bias, float* __restrict__ Cf,
    int M, int N, int Ktot, int Kchunk)
{
    __shared__ __align__(16) _Float16 lds[2][4 * 4096];   // 64 KB
    const int t = threadIdx.x, wave = t >> 6, lane = t & 63;
    const int bm = blockIdx.y * 128, bn = blockIdx.x * 128;
    const int koff = blockIdx.z * Kchunk;
    const int wm = (wave >> 1) * 64, wn = (wave & 1) * 64;
    const int rsub = lane >> 2, seg = lane & 3;
    const int fm = lane & 15, fko = (lane >> 4) * 8;

    f32x4 acc0[4][4], acc1[4][4];
    #pragma unroll
    for (int i = 0; i < 4; ++i)
        #pragma unroll
        for (int j = 0; j < 4; ++j) {
            acc0[i][j] = (f32x4){0.f, 0.f, 0.f, 0.f};
            acc1[i][j] = (f32x4){0.f, 0.f, 0.f, 0.f};
        }

    const int iters = Kchunk >> 5;
    // stage(it -> buf): issue 8 global_load_lds per wave
    #define STAGE_G(IT, BUF) {                                                 \
        const int k = koff + (IT)*32;                                          \
        _Float16* Lb = &lds[BUF][0];                                           \
        _Pragma("unroll")                                                      \
        for (int j = 0; j < 2; ++j) {                                          \
            const int q = wave * 2 + j;                                        \
            const size_t aoff = (size_t)(bm + q*16 + rsub) * Ktot + k + seg*8; \
            const size_t boff = (size_t)(bn + q*16 + rsub) * Ktot + k + seg*8; \
            gload_lds16(Ah + aoff, Lb + 0*4096 + q*512);                       \
            gload_lds16(Al + aoff, Lb + 1*4096 + q*512);                       \
            gload_lds16(Bh + boff, Lb + 2*4096 + q*512);                       \
            gload_lds16(Bl + boff, Lb + 3*4096 + q*512);                       \
        } }

    STAGE_G(0, 0);
    for (int it = 0; it < iters; ++it) {
        __syncthreads();                      // drains stage(it); prev reads done
        if (it + 1 < iters) STAGE_G(it + 1, (it + 1) & 1);   // overlap w/ compute
        const _Float16* L = &lds[it & 1][0];
        f16x8 ah[4], al[4];
        #pragma unroll
        for (int i = 0; i < 4; ++i) {
            const int ar = wm + i*16 + fm;
            ah[i] = *(const f16x8*)&L[0*4096 + ar*32 + fko];
            al[i] = *(const f16x8*)&L[1*4096 + ar*32 + fko];
        }
        #pragma unroll
        for (int j = 0; j < 4; ++j) {
            const int br = wn + j*16 + fm;
            f16x8 bh = *(const f16x8*)&L[2*4096 + br*32 + fko];
            f16x8 bl = *(const f16x8*)&L[3*4096 + br*32 + fko];
            #pragma unroll
            for (int i = 0; i < 4; ++i) {
                acc0[i][j] = __builtin_amdgcn_mfma_f32_16x16x32_f16(ah[i], bh, acc0[i][j], 0, 0, 0);
                acc1[i][j] = __builtin_amdgcn_mfma_f32_16x16x32_f16(ah[i], bl, acc1[i][j], 0, 0, 0);
                acc1[i][j] = __builtin_amdgcn_mfma_f32_16x16x32_f16(al[i], bh, acc1[i][j], 0, 0, 0);
            }
        }
    }
    float* dst = Cf + (size_t)blockIdx.z * M * N;
    #pragma unroll
    for (int i = 0; i < 4; ++i)
        #pragma unroll
        for (int j = 0; j < 4; ++j) {
            const int col = bn + wn + j*16 + fm;
            const float bv = (blockIdx.z == 0) ? bias[col] : 0.f;
            #pragma unroll
            for (int r = 0; r < 4; ++r) {
                const int row = bm + wm + i*16 + (lane >> 4)*4 + r;
                dst[(size_t)row * N + col] = acc0[i][j][r] + acc1[i][j][r] * RINV + bv;
            }
        }
    #undef STAGE_G
}

// ==== GEMM1 fused: H = gelu(cat@Wc1+bc1) -> fp16 h/l, 128x64 tiles, dbuf ====
// AIDX 1: cat rows lrid/rrid. AIDX 2: rows idxt[m*31+{0,1}]. K=1024 fixed.
template<int AIDX>
__global__ __launch_bounds__(256, 1) void k_gemm1(
    const _Float16* __restrict__ Ah, const _Float16* __restrict__ Al,
    const _Float16* __restrict__ Bh, const _Float16* __restrict__ Bl,
    const float* __restrict__ bias,
    _Float16* __restrict__ Oh, _Float16* __restrict__ Ol,
    const int* __restrict__ lrid, const int* __restrict__ rrid,
    const int* __restrict__ idxt, int N)
{
    __shared__ __align__(16) _Float16 lds[2][12288];   // 48 KB
    const int t = threadIdx.x, wave = t >> 6, lane = t & 63;
    const int bm = blockIdx.y * 128, bn = blockIdx.x * 64;
    const int rsub = lane >> 2, seg = lane & 3;
    const int fm = lane & 15, quad = lane >> 4, fko = quad * 8;

    size_t lb[2], rb[2];
    #pragma unroll
    for (int j = 0; j < 2; ++j) {
        const int rowm = bm + (wave*2 + j)*16 + rsub;
        if (AIDX == 1) {
            lb[j] = (size_t)lrid[rowm] * 512;
            rb[j] = (size_t)rrid[rowm] * 512;
        } else {
            lb[j] = (size_t)idxt[rowm*31 + 0] * 512;
            rb[j] = (size_t)idxt[rowm*31 + 1] * 512;
        }
    }
    const size_t bbase = (size_t)(bn + wave*16 + rsub) * 1024;

    f32x4 acc0[2][4], acc1[2][4];
    #pragma unroll
    for (int i = 0; i < 2; ++i)
        #pragma unroll
        for (int j = 0; j < 4; ++j) {
            acc0[i][j] = (f32x4){0.f, 0.f, 0.f, 0.f};
            acc1[i][j] = (f32x4){0.f, 0.f, 0.f, 0.f};
        }

    #define STAGE_G1(IT, BUF) {                                                 \
        const int k0 = (IT)*32;                                                 \
        _Float16* Lb = &lds[BUF][0];                                            \
        _Pragma("unroll")                                                       \
        for (int j = 0; j < 2; ++j) {                                           \
            const int q = wave*2 + j;                                           \
            const size_t aoff = (k0 < 512 ? lb[j] + k0 : rb[j] + (k0-512)) + seg*8; \
            gload_lds16(Ah + aoff, Lb + q*512);                                 \
            gload_lds16(Al + aoff, Lb + 4096 + q*512);                          \
        }                                                                       \
        gload_lds16(Bh + bbase + k0 + seg*8, Lb + 8192 + wave*512);             \
        gload_lds16(Bl + bbase + k0 + seg*8, Lb + 10240 + wave*512); }

    STAGE_G1(0, 0);
    for (int it = 0; it < 32; ++it) {
        __syncthreads();
        if (it + 1 < 32) STAGE_G1(it + 1, (it + 1) & 1);
        const _Float16* L = &lds[it & 1][0];
        f16x8 ah[2], al[2];
        #pragma unroll
        for (int i = 0; i < 2; ++i) {
            const int ar = wave*32 + i*16 + fm;
            ah[i] = *(const f16x8*)&L[ar*32 + fko];
            al[i] = *(const f16x8*)&L[4096 + ar*32 + fko];
        }
        #pragma unroll
        for (int j = 0; j < 4; ++j) {
            const int br = j*16 + fm;
            f16x8 bh = *(const f16x8*)&L[8192 + br*32 + fko];
            f16x8 bl = *(const f16x8*)&L[10240 + br*32 + fko];
            #pragma unroll
            for (int i = 0; i < 2; ++i) {
                acc0[i][j] = __builtin_amdgcn_mfma_f32_16x16x32_f16(ah[i], bh, acc0[i][j], 0, 0, 0);
                acc1[i][j] = __builtin_amdgcn_mfma_f32_16x16x32_f16(ah[i], bl, acc1[i][j], 0, 0, 0);
                acc1[i][j] = __builtin_amdgcn_mfma_f32_16x16x32_f16(al[i], bh, acc1[i][j], 0, 0, 0);
            }
        }
    }
    #pragma unroll
    for (int i = 0; i < 2; ++i)
        #pragma unroll
        for (int j = 0; j < 4; ++j) {
            const int col = bn + j*16 + fm;
            const float bv = bias[col];
            #pragma unroll
            for (int r = 0; r < 4; ++r) {
                const int row = bm + wave*32 + i*16 + quad*4 + r;
                float v = gelu_f(acc0[i][j][r] + acc1[i][j][r] * RINV + bv);
                _Float16 h = hi16(v);
                Oh[(size_t)row * N + col] = h;
                Ol[(size_t)row * N + col] = lo16(v, h);
            }
        }
    #undef STAGE_G1
}

// ====== fused score (64x64 tiles, dbuf): w += gelu(cat@Wd1+bd1)@Wd2 ======
template<int MODE>
__global__ __launch_bounds__(256, 2) void k_wscore(
    const _Float16* __restrict__ ch, const _Float16* __restrict__ cl,
    const int* __restrict__ posb, const int* __restrict__ idxt,
    const _Float16* __restrict__ Bh, const _Float16* __restrict__ Bl,
    const float* __restrict__ bd1, const float* __restrict__ u512,
    const float* __restrict__ bd2, float* __restrict__ w, int Spairs)
{
    __shared__ __align__(16) _Float16 lds[2][8192];   // 32 KB
    const int t = threadIdx.x, wave = t >> 6, lane = t & 63;
    const int bm = blockIdx.x * 64, ncol0 = blockIdx.y * 64;
    const int rsub = lane >> 2, seg = lane & 3;
    const int fm = lane & 15, quad = lane >> 4, fko = quad * 8;

    size_t lb, rb;
    {
        const int rowm = bm + wave*16 + rsub;
        int lrow, rrow;
        if (MODE == 0) {
            const int n = rowm / 31, s = rowm - n * 31;
            lrow = n*32 + s; rrow = lrow + 1;
        } else {
            const int nk = rowm >> 1, slot = rowm & 1;
            const int s = posb[nk];
            int jw = s - 1 + slot;
            int jc = jw < 0 ? 0 : (jw > Spairs - 1 ? Spairs - 1 : jw);
            lrow = idxt[nk*31 + jc]; rrow = idxt[nk*31 + jc + 1];
        }
        lb = (size_t)lrow * 512; rb = (size_t)rrow * 512;
    }
    const size_t bbase = (size_t)(ncol0 + wave*16 + rsub) * 1024;

    f32x4 acc0[4], acc1[4];
    #pragma unroll
    for (int j = 0; j < 4; ++j) {
        acc0[j] = (f32x4){0.f, 0.f, 0.f, 0.f};
        acc1[j] = (f32x4){0.f, 0.f, 0.f, 0.f};
    }
    #define STAGE_WS(IT, BUF) {                                                \
        const int k0 = (IT)*32;                                                \
        _Float16* Lb = &lds[BUF][0];                                           \
        const size_t aoff = (k0 < 512 ? lb + k0 : rb + (k0-512)) + seg*8;      \
        gload_lds16(ch + aoff, Lb + 0*2048 + wave*512);                        \
        gload_lds16(cl + aoff, Lb + 1*2048 + wave*512);                        \
        gload_lds16(Bh + bbase + k0 + seg*8, Lb + 2*2048 + wave*512);          \
        gload_lds16(Bl + bbase + k0 + seg*8, Lb + 3*2048 + wave*512); }

    STAGE_WS(0, 0);
    for (int it = 0; it < 32; ++it) {
        __syncthreads();
        if (it + 1 < 32) STAGE_WS(it + 1, (it + 1) & 1);
        const _Float16* L = &lds[it & 1][0];
        const int ar = wave*16 + fm;
        f16x8 ah = *(const f16x8*)&L[0*2048 + ar*32 + fko];
        f16x8 al = *(const f16x8*)&L[1*2048 + ar*32 + fko];
        #pragma unroll
        for (int j = 0; j < 4; ++j) {
            const int br = j*16 + fm;
            f16x8 bh = *(const f16x8*)&L[2*2048 + br*32 + fko];
            f16x8 bl = *(const f16x8*)&L[3*2048 + br*32 + fko];
            acc0[j] = __builtin_amdgcn_mfma_f32_16x16x32_f16(ah, bh, acc0[j], 0, 0, 0);
            acc1[j] = __builtin_amdgcn_mfma_f32_16x16x32_f16(ah, bl, acc1[j], 0, 0, 0);
            acc1[j] = __builtin_amdgcn_mfma_f32_16x16x32_f16(al, bh, acc1[j], 0, 0, 0);
        }
    }
    float part[4] = {0.f, 0.f, 0.f, 0.f};
    #pragma unroll
    for (int j = 0; j < 4; ++j) {
        const int col = ncol0 + j*16 + fm;
        const float bv = bd1[col], uv = u512[col];
        #pragma unroll
        for (int r = 0; r < 4; ++r) {
            float v = acc0[j][r] + acc1[j][r] * RINV + bv;
            part[r] += gelu_f(v) * uv;
        }
    }
    #pragma unroll
    for (int r = 0; r < 4; ++r) {
        float s = part[r];
        s += __shfl_xor(s, 1); s += __shfl_xor(s, 2);
        s += __shfl_xor(s, 4); s += __shfl_xor(s, 8);
        part[r] = s;
    }
    if (fm == 0) {
        const float bd2v = (blockIdx.y == 0) ? bd2[0] : 0.f;
        #pragma unroll
        for (int r = 0; r < 4; ++r) {
            const int rowm = bm + wave*16 + quad*4 + r;
            int wi = -1;
            if (MODE == 0) {
                const int n = rowm / 31, s = rowm - n * 31;
                wi = n * BEAM * S0 + s;
            } else {
                const int nk = rowm >> 1, slot = rowm & 1;
                const int jw = posb[nk] - 1 + slot;
                if (jw >= 0 && jw < Spairs) wi = nk * S0 + jw;
            }
            if (wi >= 0) atomicAdd(&w[wi], part[r] + bd2v);
        }
    }
    #undef STAGE_WS
}

// ============ weight transpose + fp16 split ============
__global__ __launch_bounds__(256) void k_tsplit(
    const float* __restrict__ in, _Float16* __restrict__ oh,
    _Float16* __restrict__ ol, int K, int N)
{
    __shared__ float tile[32][33];
    const int bx = blockIdx.x * 32, by = blockIdx.y * 32;
    const int t = threadIdx.x, r = t >> 5, c = t & 31;
    #pragma unroll
    for (int p = 0; p < 4; ++p)
        tile[r + p*8][c] = in[(size_t)(by + r + p*8) * N + bx + c];
    __syncthreads();
    #pragma unroll
    for (int p = 0; p < 4; ++p) {
        const int nl = r + p*8;
        float v = tile[c][nl];
        _Float16 h = hi16(v);
        oh[(size_t)(bx + nl) * K + by + c] = h;
        ol[(size_t)(bx + nl) * K + by + c] = lo16(v, h);
    }
}

// ============ elementwise fp16 split (x rows, init only) ============
__global__ __launch_bounds__(256) void k_xsplit(
    const float* __restrict__ in, _Float16* __restrict__ oh,
    _Float16* __restrict__ ol)
{
    const size_t i = ((size_t)blockIdx.x * 256 + threadIdx.x) * 4;
    float4 v = *(const float4*)(in + i);
    _Float16 h0 = hi16(v.x), h1 = hi16(v.y), h2 = hi16(v.z), h3 = hi16(v.w);
    typedef __attribute__((ext_vector_type(4))) _Float16 f16x4v;
    f16x4v h = {h0, h1, h2, h3};
    f16x4v l = {lo16(v.x,h0), lo16(v.y,h1), lo16(v.z,h2), lo16(v.w,h3)};
    *(f16x4v*)(oh + i) = h;
    *(f16x4v*)(ol + i) = l;
}

// ============ init layernorm -> split arena rows ============
__global__ __launch_bounds__(256) void k_ln_init(
    const float* __restrict__ y, const float* __restrict__ g,
    const float* __restrict__ b, _Float16* __restrict__ cha,
    _Float16* __restrict__ cla)
{
    const int row = blockIdx.x;
    const float* yr = y + (size_t)row * DD;
    const int t = threadIdx.x;
    float v0 = yr[t], v1 = yr[t + 256];
    __shared__ float sb[8];
    float s1 = block_reduce_sum(v0 + v1, sb);
    float s2 = block_reduce_sum(v0*v0 + v1*v1, sb);
    float mu = s1 * (1.f/512.f);
    float rstd = rsqrtf(s2 * (1.f/512.f) - mu*mu + 1e-5f);
    float a0 = (v0 - mu) * rstd * g[t]       + b[t];
    float a1 = (v1 - mu) * rstd * g[t + 256] + b[t + 256];
    _Float16 h0 = hi16(a0), h1 = hi16(a1);
    cha[(size_t)row*DD + t]       = h0;
    cla[(size_t)row*DD + t]       = lo16(a0, h0);
    cha[(size_t)row*DD + t + 256] = h1;
    cla[(size_t)row*DD + t + 256] = lo16(a1, h1);
}

__global__ void k_init_state(float* accu, float* bm, int* idx0, float* wz) {
    int i = blockIdx.x * blockDim.x + threadIdx.x;
    if (i < NB*S0) wz[i] = 0.f;
    if (i < AR_INIT) idx0[i] = i;
    if (i < NB) { accu[i] = 0.f; bm[i] = 1.f; }
}

// ============ top-k + beam select + score-cache gather + l/r row ids ========
__global__ __launch_bounds__(64) void k_topk(
    const float* __restrict__ w, const float* __restrict__ accu,
    const float* __restrict__ bmask, const float* __restrict__ maskg,
    int iiter, int B, int S, int topk, int do_bsel,
    const int* __restrict__ idxold, int BAo, int STo,
    int* __restrict__ parent, int* __restrict__ posb,
    int* __restrict__ lrid, int* __restrict__ rrid,
    float* __restrict__ accu_out, float* __restrict__ bm_out,
    float* __restrict__ wnew, int Snew, int dow)
{
    const int n = blockIdx.x, lane = threadIdx.x;
    __shared__ int   selpos_s[BEAM][BEAM];
    __shared__ float nscore_s[BEAM][BEAM];
    __shared__ int   par_s[BEAM], pos_s[BEAM];
    const float* mrow = maskg + n*S0 + (iiter + 1);
    const float mk   = (lane < S) ? mrow[lane] : 0.f;
    const float done = 1.f - mrow[0];
    for (int b = 0; b < B; ++b) {
        float ml;
        if (lane < S) {
            float wv = w[(n*BEAM + b)*S0 + lane];
            ml = (mk > 0.f) ? wv : -1e9f;
        } else ml = -INFINITY;
        float mx = ml;
        #pragma unroll
        for (int o = 32; o > 0; o >>= 1) mx = fmaxf(mx, __shfl_xor(mx, o));
        float e = (lane < S) ? expf(ml - mx) * mk : 0.f;
        float es = e;
        #pragma unroll
        for (int o = 32; o > 0; o >>= 1) es += __shfl_xor(es, o);
        const float den = es + 1e-20f;
        float mlc = ml;
        for (int ts = 0; ts < topk; ++ts) {
            unsigned int fb = __float_as_uint(mlc);
            unsigned int ok = (fb & 0x80000000u) ? ~fb : (fb | 0x80000000u);
            unsigned long long key =
                ((unsigned long long)ok << 32) | (unsigned int)(63 - lane);
            if (lane >= S) key = 0ull;
            unsigned long long km = key;
            #pragma unroll
            for (int o = 32; o > 0; o >>= 1) {
                unsigned long long oth = __shfl_xor(km, o);
                km = (oth > km) ? oth : km;
            }
            int sidx = 63 - (int)(km & 0xffffffffull);
            float esel = __shfl(e, sidx);
            if (lane == 0) {
                selpos_s[b][ts] = sidx;
                nscore_s[b][ts] = logf(esel / den + 1e-20f);
            }
            if (lane == sidx) mlc = -INFINITY;
        }
    }
    __syncthreads();
    if (lane == 0) {
        float acand[BEAM*BEAM], bcand[BEAM*BEAM];
        const int C = B * topk;
        for (int b = 0; b < B; ++b)
            for (int tt = 0; tt < topk; ++tt) {
                int c = b*topk + tt;
                acand[c] = accu[n*BEAM + b] + nscore_s[b][tt];
                float nb = done * ((tt == 0) ? 1.f : 0.f) + (1.f - done);
                bcand[c] = bmask[n*BEAM + b] * nb;
            }
        bool used[BEAM*BEAM];
        for (int c = 0; c < C; ++c) used[c] = false;
        for (int k = 0; k < BEAM; ++k) {
            int bestc;
            if (do_bsel) {
                bestc = 0; float bv = -INFINITY;
                for (int c = 0; c < C; ++c) {
                    if (used[c]) continue;
                    float v = (bcand[c] > 0.f) ? acand[c] : -1e9f;
                    if (v > bv) { bv = v; bestc = c; }
                }
                used[bestc] = true;
            } else bestc = k;
            const int pp = bestc / topk, ss = selpos_s[bestc / topk][bestc % topk];
            parent[n*BEAM + k] = pp;
            posb[n*BEAM + k]   = ss;
            par_s[k] = pp; pos_s[k] = ss;
            accu_out[n*BEAM + k] = acand[bestc];
            bm_out[n*BEAM + k]   = bcand[bestc];
        }
    }
    __syncthreads();
    if (lane < BEAM) {
        const int base = (n*BAo + par_s[lane]) * STo + pos_s[lane];
        lrid[n*BEAM + lane] = idxold[base];
        rrid[n*BEAM + lane] = idxold[base + 1];
    }
    if (dow) {
        for (int k = 0; k < BEAM; ++k) {
            const int p = par_s[k], s = pos_s[k];
            if (lane < Snew) {
                float v = 0.f;
                if (lane < s - 1)      v = w[(n*BEAM + p)*S0 + lane];
                else if (lane > s)     v = w[(n*BEAM + p)*S0 + lane + 1];
                wnew[(n*BEAM + k)*S0 + lane] = v;
            }
        }
    }
}

// ======== compose: sum 4 partials + gate softmax + mix + LN -> arena ========
__global__ __launch_bounds__(256) void k_compose(
    const float* __restrict__ P,
    const _Float16* __restrict__ cha_r, const _Float16* __restrict__ cla_r,
    const int* __restrict__ lrid, const int* __restrict__ rrid,
    const int* __restrict__ parent, const int* __restrict__ posb,
    const int* __restrict__ idxold, int BAo, int STo,
    const float* __restrict__ maskg, int iiter, int Spnew,
    const float* __restrict__ gp, const float* __restrict__ bp,
    _Float16* __restrict__ cha_w, _Float16* __restrict__ cla_w, int newbase,
    int* __restrict__ idxnew, int finalflag, float* __restrict__ nvout)
{
    __shared__ float sb[8];
    const int nk = blockIdx.x, t = threadIdx.x;
    const int n = nk / BEAM;
    size_t lbase, rbase;
    if (finalflag) {
        lbase = (size_t)idxold[nk*31 + 0] * 512;
        rbase = (size_t)idxold[nk*31 + 1] * 512;
    } else {
        lbase = (size_t)lrid[nk] * 512;
        rbase = (size_t)rrid[nk] * 512;
    }
    const float* c = P + (size_t)nk * CHID;
    float o[2];
    #pragma unroll
    for (int e = 0; e < 2; ++e) {
        const int d = t + 256*e;
        const float lv = recon(cha_r[lbase + d], cla_r[lbase + d]);
        const float rv = recon(cha_r[rbase + d], cla_r[rbase + d]);
        float c0 = ((c[d]        + c[MN2 + d])        + c[2*MN2 + d])        + c[3*MN2 + d];
        float c1 = ((c[DD + d]   + c[MN2 + DD + d])   + c[2*MN2 + DD + d])   + c[3*MN2 + DD + d];
        float c2 = ((c[2*DD + d] + c[MN2 + 2*DD + d]) + c[2*MN2 + 2*DD + d]) + c[3*MN2 + 2*DD + d];
        float c3 = ((c[3*DD + d] + c[MN2 + 3*DD + d]) + c[2*MN2 + 3*DD + d]) + c[3*MN2 + 3*DD + d];
        float m = fmaxf(c0, fmaxf(c1, c2));
        float e0 = expf(c0 - m), e1 = expf(c1 - m), e2 = expf(c2 - m);
        float inv = 1.f / (e0 + e1 + e2);
        o[e] = (e0*lv + e1*rv + e2*c3) * inv;
    }
    float s1 = block_reduce_sum(o[0] + o[1], sb);
    float s2 = block_reduce_sum(o[0]*o[0] + o[1]*o[1], sb);
    float mu = s1 * (1.f/512.f);
    float rstd = rsqrtf(s2 * (1.f/512.f) - mu*mu + 1e-5f);
    if (finalflag) {
        #pragma unroll
        for (int e = 0; e < 2; ++e) {
            const int d = t + 256*e;
            nvout[(size_t)nk*DD + d] = (o[e] - mu) * rstd * gp[d] + bp[d];
        }
        return;
    }
    const int arow = newbase + nk;
    #pragma unroll
    for (int e = 0; e < 2; ++e) {
        const int d = t + 256*e;
        float v = (o[e] - mu) * rstd * gp[d] + bp[d];
        _Float16 h = hi16(v);
        cha_w[(size_t)arow*512 + d] = h;
        cla_w[(size_t)arow*512 + d] = lo16(v, h);
    }
    if (t < Spnew) {
        const float done = maskg[n*S0 + iiter + 1];
        const int p = parent[nk], s = posb[nk];
        const int src = (n*BAo + p) * STo;
        int val;
        if (done > 0.5f)
            val = (t < s) ? idxold[src + t] : (t == s ? arow : idxold[src + t + 1]);
        else
            val = idxold[src + t];
        idxnew[nk*31 + t] = val;
    }
}

// ============ final beam softmax mix ============
__global__ __launch_bounds__(256) void k_final(
    const float* __restrict__ nv,
    const _Float16* __restrict__ cha, const _Float16* __restrict__ cla,
    const int* __restrict__ idxt, const float* __restrict__ maskg,
    const float* __restrict__ accu, const float* __restrict__ bmv,
    float* __restrict__ out)
{
    const int n = blockIdx.x, t = threadIdx.x;
    const float done = maskg[n*S0 + 31];
    float sc[BEAM];
    #pragma unroll
    for (int k = 0; k < BEAM; ++k) {
        float m = bmv[n*BEAM + k];
        sc[k] = m * accu[n*BEAM + k] + (1.f - m) * (-999999.f);
    }
    float mx = sc[0];
    #pragma unroll
    for (int k = 1; k < BEAM; ++k) mx = fmaxf(mx, sc[k]);
    float e[BEAM], den = 0.f;
    #pragma unroll
    for (int k = 0; k < BEAM; ++k) { e[k] = expf(sc[k] - mx); den += e[k]; }
    const float inv = 1.f / den;
    #pragma unroll
    for (int i2 = 0; i2 < 2; ++i2) {
        const int d = t + 256*i2;
        float s = 0.f;
        #pragma unroll
        for (int k = 0; k < BEAM; ++k) {
            const int nk = n*BEAM + k;
            const size_t ob = (size_t)idxt[nk*31] * 512;
            const float nvv  = nv[(size_t)nk*DD + d];
            const float oldv = recon(cha[ob + d], cla[ob + d]);
            s += e[k]*inv * (done*nvv + (1.f - done)*oldv);
        }
        out[(size_t)n*DD + d] = s;
    }
}

extern "C" void kernel_launch(void* const* d_in, const int* in_sizes, int n_in,
                              void* d_out, int out_size, void* d_ws, size_t ws_size,
                              hipStream_t stream) {
    (void)in_sizes; (void)n_in; (void)out_size; (void)ws_size;
    const float* x    = (const float*)d_in[0];
    const float* mask = (const float*)d_in[1];
    const float* Wi   = (const float*)d_in[2];
    const float* bi   = (const float*)d_in[3];
    const float* g1   = (const float*)d_in[4];
    const float* b1   = (const float*)d_in[5];
    const float* Wd1  = (const float*)d_in[6];
    const float* bd1  = (const float*)d_in[7];
    const float* Wd2  = (const float*)d_in[8];
    const float* bd2  = (const float*)d_in[9];
    const float* Wc1  = (const float*)d_in[10];
    const float* bc1  = (const float*)d_in[11];
    const float* Wc2  = (const float*)d_in[12];
    const float* bc2  = (const float*)d_in[13];
    const float* g2   = (const float*)d_in[14];
    const float* b2   = (const float*)d_in[15];
    float* out = (float*)d_out;

    // ---- workspace carve-up (bytes), ~185 MB ----
    char* p = (char*)d_ws;
    _Float16* cha = (_Float16*)p;        p += (size_t)AR_TOT*512*2;
    _Float16* cla = (_Float16*)p;        p += (size_t)AR_TOT*512*2;
    _Float16* Wc1th = (_Float16*)p;      p += (size_t)CHID*1024*2;
    _Float16* Wc1tl = (_Float16*)p;      p += (size_t)CHID*1024*2;
    _Float16* Wc2th = (_Float16*)p;      p += (size_t)CHID*CHID*2;
    _Float16* Wc2tl = (_Float16*)p;      p += (size_t)CHID*CHID*2;
    _Float16* Wd1th = (_Float16*)p;      p += (size_t)512*1024*2;
    _Float16* Wd1tl = (_Float16*)p;      p += (size_t)512*1024*2;
    _Float16* Wih = (_Float16*)p;        p += (size_t)WDIM*DD*2;
    _Float16* Wil = (_Float16*)p;        p += (size_t)WDIM*DD*2;
    _Float16* Hh  = (_Float16*)p;        p += (size_t)NB*CHID*2;
    _Float16* Hl  = (_Float16*)p;        p += (size_t)NB*CHID*2;
    float* Pb   = (float*)p;             p += MN2*4*4;                // 4 slices
    float* nvb  = (float*)p;             p += (size_t)NB*DD*4;
    float* wA   = (float*)p;             p += (size_t)NB*S0*4;
    float* wB   = (float*)p;             p += (size_t)NB*S0*4;
    float* accA = (float*)p;             p += NB*4;
    float* accB = (float*)p;             p += NB*4;
    float* bmA  = (float*)p;             p += NB*4;
    float* bmB  = (float*)p;             p += NB*4;
    int* parent = (int*)p;               p += NB*4;
    int* posb   = (int*)p;               p += NB*4;
    int* lrid   = (int*)p;               p += NB*4;
    int* rrid   = (int*)p;               p += NB*4;
    int* idx0   = (int*)p;               p += AR_INIT*4;
    int* idxA   = (int*)p;               p += NB*31*4;
    int* idxB   = (int*)p;               p += NB*31*4;
    // init-only aliases inside Pb
    _Float16* xh = (_Float16*)Pb;
    _Float16* xl = (_Float16*)((char*)Pb + (size_t)AR_INIT*512*2);
    float* ybuf  = (float*)((char*)Pb + (size_t)AR_INIT*512*4);

    // ---- prep ----
    k_tsplit<<<dim3(CHID/32, 1024/32), 256, 0, stream>>>(Wc1, Wc1th, Wc1tl, 1024, CHID);
    k_tsplit<<<dim3(CHID/32, CHID/32), 256, 0, stream>>>(Wc2, Wc2th, Wc2tl, CHID, CHID);
    k_tsplit<<<dim3(512/32, 1024/32), 256, 0, stream>>>(Wd1, Wd1th, Wd1tl, 1024, 512);
    k_tsplit<<<dim3(DD/32, WDIM/32), 256, 0, stream>>>(Wi, Wih, Wil, WDIM, DD);
    k_init_state<<<(NB*S0 + 255)/256, 256, 0, stream>>>(accA, bmA, idx0, wA);

    // ---- init: arena rows 0..8191 = LN(x@Wi+bi) ----
    k_xsplit<<<(AR_INIT*WDIM)/1024, 256, 0, stream>>>(x, xh, xl);
    k_gemm<0><<<dim3(DD/128, AR_INIT/128, 1), 256, 0, stream>>>(
        xh, xl, Wih, Wil, bi, ybuf, AR_INIT, DD, WDIM, WDIM);
    k_ln_init<<<AR_INIT, 256, 0, stream>>>(ybuf, g1, b1, cha, cla);
    k_wscore<0><<<dim3(NN*31/64, 8), 256, 0, stream>>>(
        cha, cla, nullptr, nullptr, Wd1th, Wd1tl, bd1, Wd2, bd2, wA, 31);

    const int* idxcur = idx0;
    int* idxnxt = idxA;
    int BAo = 1, STo = 32;
    float *wcur = wA, *wnxt = wB;
    float *acur = accA, *anxt = accB, *bcur = bmA, *bnxt = bmB;
    for (int i = 0; i < 30; ++i) {
        const int B  = (i == 0) ? 1 : BEAM;
        const int S  = 31 - i;
        const int tk = (S < BEAM) ? S : BEAM;
        const int dob = (B*tk > BEAM) ? 1 : 0;
        const int newbase = AR_INIT + i*NB;
        k_topk<<<NN, 64, 0, stream>>>(wcur, acur, bcur, mask, i, B, S, tk, dob,
                                      idxcur, BAo, STo, parent, posb, lrid, rrid,
                                      anxt, bnxt, wnxt, S - 1, (i < 29) ? 1 : 0);
        k_gemm1<1><<<dim3(CHID/64, NB/128), 256, 0, stream>>>(
            cha, cla, Wc1th, Wc1tl, bc1, Hh, Hl, lrid, rrid, nullptr, CHID);
        k_gemm<0><<<dim3(CHID/128, NB/128, 4), 256, 0, stream>>>(
            Hh, Hl, Wc2th, Wc2tl, bc2, Pb, NB, CHID, CHID, 512);
        k_compose<<<NB, 256, 0, stream>>>(Pb, cha, cla, lrid, rrid, parent, posb,
                                          idxcur, BAo, STo, mask, i, 31 - i,
                                          g2, b2, cha, cla, newbase, idxnxt,
                                          0, nullptr);
        if (i < 29)
            k_wscore<1><<<dim3(NB*2/64, 8), 256, 0, stream>>>(
                cha, cla, posb, idxnxt, Wd1th, Wd1tl, bd1, Wd2, bd2, wnxt, S - 1);
        idxcur = idxnxt;
        idxnxt = (idxnxt == idxA) ? idxB : idxA;
        BAo = BEAM; STo = 31;
        float* tp;
        tp = wcur; wcur = wnxt; wnxt = tp;
        tp = acur; acur = anxt; anxt = tp;
        tp = bcur; bcur = bnxt; bnxt = tp;
    }
    // final compose: l,r = table positions 0,1
    k_gemm1<2><<<dim3(CHID/64, NB/128), 256, 0, stream>>>(
        cha, cla, Wc1th, Wc1tl, bc1, Hh, Hl, nullptr, nullptr, idxcur, CHID);
    k_gemm<0><<<dim3(CHID/128, NB/128, 4), 256, 0, stream>>>(
        Hh, Hl, Wc2th, Wc2tl, bc2, Pb, NB, CHID, CHID, 512);
    k_compose<<<NB, 256, 0, stream>>>(Pb, cha, cla, nullptr, nullptr, parent, posb,
                                      idxcur, BEAM, 31, mask, 30, 0,
                                      g2, b2, nullptr, nullptr, 0,
                                      nullptr, 1, nvb);
    k_final<<<NN, 256, 0, stream>>>(nvb, cha, cla, idxcur, mask, acur, bcur, out);
}

// Round 11
// 4301.296 us; speedup vs baseline: 2.8520x; 1.3398x over previous
//
#include <hip/hip_runtime.h>
#include <math.h>

// EBT_GRC beam-search forward, round 11: lane-parallel beam select in k_topk
// (round-10 profile: scratch-spilled acand[25]/used[25] + serial lane-0 loop
// = 78us x 30 = 2.3ms, 40% of wall). All MFMA kernels keep round-10 LDS
// double-buffering. N=256, S=32, D=512, CH=2048, BEAM=5. WS ~185 MB.

#define NN   256
#define S0   32
#define WDIM 512
#define DD   512
#define CHID 2048
#define BEAM 5
#define NB   (NN*BEAM)   // 1280
#define RSCALE 2048.0f
#define RINV  (1.0f/2048.0f)
#define AR_INIT 8192
#define AR_TOT  (AR_INIT + 30*NB)    // 46592 rows
#define MN2 ((size_t)NB*CHID)        // partial-buffer slice stride

typedef __attribute__((ext_vector_type(8))) _Float16 f16x8;
typedef __attribute__((ext_vector_type(4))) float f32x4;

__device__ __forceinline__ float gelu_f(float x) {
    return 0.5f * x * (1.0f + erff(x * 0.7071067811865475f));
}
__device__ __forceinline__ _Float16 hi16(float v) { return (_Float16)v; }
__device__ __forceinline__ _Float16 lo16(float v, _Float16 h) {
    return (_Float16)((v - (float)h) * RSCALE);
}
__device__ __forceinline__ float recon(_Float16 h, _Float16 l) {
    return (float)h + RINV * (float)l;
}

__device__ __forceinline__ void gload_lds16(const void* g, void* l) {
    __builtin_amdgcn_global_load_lds(
        (const __attribute__((address_space(1))) unsigned*)g,
        (__attribute__((address_space(3))) unsigned*)l, 16, 0, 0);
}

__device__ __forceinline__ float block_reduce_sum(float v, float* sb) {
    #pragma unroll
    for (int o = 32; o > 0; o >>= 1) v += __shfl_down(v, o);
    const int lane = threadIdx.x & 63, wid = threadIdx.x >> 6;
    __syncthreads();
    if (lane == 0) sb[wid] = v;
    __syncthreads();
    return sb[0] + sb[1] + sb[2] + sb[3];
}

// ================= fp16x2 split MFMA GEMM, split-K, LDS dbuf =================
template<int AIDX>
__global__ __launch_bounds__(256, 1) void k_gemm(
    const _Float16* __restrict__ Ah, const _Float16* __restrict__ Al,
    const _Float16* __restrict__ Bh, const _Float16* __restrict__ Bl,
    const float* __restrict__ bias, float* __restrict__ Cf,
    int M, int N, int Ktot, int Kchunk)
{
    __shared__ __align__(16) _Float16 lds[2][4 * 4096];   // 64 KB
    const int t = threadIdx.x, wave = t >> 6, lane = t & 63;
    const int bm = blockIdx.y * 128, bn = blockIdx.x * 128;
    const int koff = blockIdx.z * Kchunk;
    const int wm = (wave >> 1) * 64, wn = (wave & 1) * 64;
    const int rsub = lane >> 2, seg = lane & 3;
    const int fm = lane & 15, fko = (lane >> 4) * 8;

    f32x4 acc0[4][4], acc1[4][4];
    #pragma unroll
    for (int i = 0; i < 4; ++i)
        #pragma unroll
        for (int j = 0; j < 4; ++j) {
            acc0[i][j] = (f32x4){0.f, 0.f, 0.f, 0.f};
            acc1[i][j] = (f32x4){0.f, 0.f, 0.f, 0.f};
        }

    const int iters = Kchunk >> 5;
    #define STAGE_G(IT, BUF) {                                                 \
        const int k = koff + (IT)*32;                                          \
        _Float16* Lb = &lds[BUF][0];                                           \
        _Pragma("unroll")                                                      \
        for (int j = 0; j < 2; ++j) {                                          \
            const int q = wave * 2 + j;                                        \
            const size_t aoff = (size_t)(bm + q*16 + rsub) * Ktot + k + seg*8; \
            const size_t boff = (size_t)(bn + q*16 + rsub) * Ktot + k + seg*8; \
            gload_lds16(Ah + aoff, Lb + 0*4096 + q*512);                       \
            gload_lds16(Al + aoff, Lb + 1*4096 + q*512);                       \
            gload_lds16(Bh + boff, Lb + 2*4096 + q*512);                       \
            gload_lds16(Bl + boff, Lb + 3*4096 + q*512);                       \
        } }

    STAGE_G(0, 0);
    for (int it = 0; it < iters; ++it) {
        __syncthreads();
        if (it + 1 < iters) STAGE_G(it + 1, (it + 1) & 1);
        const _Float16* L = &lds[it & 1][0];
        f16x8 ah[4], al[4];
        #pragma unroll
        for (int i = 0; i < 4; ++i) {
            const int ar = wm + i*16 + fm;
            ah[i] = *(const f16x8*)&L[0*4096 + ar*32 + fko];
            al[i] = *(const f16x8*)&L[1*4096 + ar*32 + fko];
        }
        #pragma unroll
        for (int j = 0; j < 4; ++j) {
            const int br = wn + j*16 + fm;
            f16x8 bh = *(const f16x8*)&L[2*4096 + br*32 + fko];
            f16x8 bl = *(const f16x8*)&L[3*4096 + br*32 + fko];
            #pragma unroll
            for (int i = 0; i < 4; ++i) {
                acc0[i][j] = __builtin_amdgcn_mfma_f32_16x16x32_f16(ah[i], bh, acc0[i][j], 0, 0, 0);
                acc1[i][j] = __builtin_amdgcn_mfma_f32_16x16x32_f16(ah[i], bl, acc1[i][j], 0, 0, 0);
                acc1[i][j] = __builtin_amdgcn_mfma_f32_16x16x32_f16(al[i], bh, acc1[i][j], 0, 0, 0);
            }
        }
    }
    float* dst = Cf + (size_t)blockIdx.z * M * N;
    #pragma unroll
    for (int i = 0; i < 4; ++i)
        #pragma unroll
        for (int j = 0; j < 4; ++j) {
            const int col = bn + wn + j*16 + fm;
            const float bv = (blockIdx.z == 0) ? bias[col] : 0.f;
            #pragma unroll
            for (int r = 0; r < 4; ++r) {
                const int row = bm + wm + i*16 + (lane >> 4)*4 + r;
                dst[(size_t)row * N + col] = acc0[i][j][r] + acc1[i][j][r] * RINV + bv;
            }
        }
    #undef STAGE_G
}

// ==== GEMM1 fused: H = gelu(cat@Wc1+bc1) -> fp16 h/l, 128x64 tiles, dbuf ====
template<int AIDX>
__global__ __launch_bounds__(256, 1) void k_gemm1(
    const _Float16* __restrict__ Ah, const _Float16* __restrict__ Al,
    const _Float16* __restrict__ Bh, const _Float16* __restrict__ Bl,
    const float* __restrict__ bias,
    _Float16* __restrict__ Oh, _Float16* __restrict__ Ol,
    const int* __restrict__ lrid, const int* __restrict__ rrid,
    const int* __restrict__ idxt, int N)
{
    __shared__ __align__(16) _Float16 lds[2][12288];   // 48 KB
    const int t = threadIdx.x, wave = t >> 6, lane = t & 63;
    const int bm = blockIdx.y * 128, bn = blockIdx.x * 64;
    const int rsub = lane >> 2, seg = lane & 3;
    const int fm = lane & 15, quad = lane >> 4, fko = quad * 8;

    size_t lb[2], rb[2];
    #pragma unroll
    for (int j = 0; j < 2; ++j) {
        const int rowm = bm + (wave*2 + j)*16 + rsub;
        if (AIDX == 1) {
            lb[j] = (size_t)lrid[rowm] * 512;
            rb[j] = (size_t)rrid[rowm] * 512;
        } else {
            lb[j] = (size_t)idxt[rowm*31 + 0] * 512;
            rb[j] = (size_t)idxt[rowm*31 + 1] * 512;
        }
    }
    const size_t bbase = (size_t)(bn + wave*16 + rsub) * 1024;

    f32x4 acc0[2][4], acc1[2][4];
    #pragma unroll
    for (int i = 0; i < 2; ++i)
        #pragma unroll
        for (int j = 0; j < 4; ++j) {
            acc0[i][j] = (f32x4){0.f, 0.f, 0.f, 0.f};
            acc1[i][j] = (f32x4){0.f, 0.f, 0.f, 0.f};
        }

    #define STAGE_G1(IT, BUF) {                                                 \
        const int k0 = (IT)*32;                                                 \
        _Float16* Lb = &lds[BUF][0];                                            \
        _Pragma("unroll")                                                       \
        for (int j = 0; j < 2; ++j) {                                           \
            const int q = wave*2 + j;                                           \
            const size_t aoff = (k0 < 512 ? lb[j] + k0 : rb[j] + (k0-512)) + seg*8; \
            gload_lds16(Ah + aoff, Lb + q*512);                                 \
            gload_lds16(Al + aoff, Lb + 4096 + q*512);                          \
        }                                                                       \
        gload_lds16(Bh + bbase + k0 + seg*8, Lb + 8192 + wave*512);             \
        gload_lds16(Bl + bbase + k0 + seg*8, Lb + 10240 + wave*512); }

    STAGE_G1(0, 0);
    for (int it = 0; it < 32; ++it) {
        __syncthreads();
        if (it + 1 < 32) STAGE_G1(it + 1, (it + 1) & 1);
        const _Float16* L = &lds[it & 1][0];
        f16x8 ah[2], al[2];
        #pragma unroll
        for (int i = 0; i < 2; ++i) {
            const int ar = wave*32 + i*16 + fm;
            ah[i] = *(const f16x8*)&L[ar*32 + fko];
            al[i] = *(const f16x8*)&L[4096 + ar*32 + fko];
        }
        #pragma unroll
        for (int j = 0; j < 4; ++j) {
            const int br = j*16 + fm;
            f16x8 bh = *(const f16x8*)&L[8192 + br*32 + fko];
            f16x8 bl = *(const f16x8*)&L[10240 + br*32 + fko];
            #pragma unroll
            for (int i = 0; i < 2; ++i) {
                acc0[i][j] = __builtin_amdgcn_mfma_f32_16x16x32_f16(ah[i], bh, acc0[i][j], 0, 0, 0);
                acc1[i][j] = __builtin_amdgcn_mfma_f32_16x16x32_f16(ah[i], bl, acc1[i][j], 0, 0, 0);
                acc1[i][j] = __builtin_amdgcn_mfma_f32_16x16x32_f16(al[i], bh, acc1[i][j], 0, 0, 0);
            }
        }
    }
    #pragma unroll
    for (int i = 0; i < 2; ++i)
        #pragma unroll
        for (int j = 0; j < 4; ++j) {
            const int col = bn + j*16 + fm;
            const float bv = bias[col];
            #pragma unroll
            for (int r = 0; r < 4; ++r) {
                const int row = bm + wave*32 + i*16 + quad*4 + r;
                float v = gelu_f(acc0[i][j][r] + acc1[i][j][r] * RINV + bv);
                _Float16 h = hi16(v);
                Oh[(size_t)row * N + col] = h;
                Ol[(size_t)row * N + col] = lo16(v, h);
            }
        }
    #undef STAGE_G1
}

// ====== fused score (64x64 tiles, dbuf): w += gelu(cat@Wd1+bd1)@Wd2 ======
template<int MODE>
__global__ __launch_bounds__(256, 2) void k_wscore(
    const _Float16* __restrict__ ch, const _Float16* __restrict__ cl,
    const int* __restrict__ posb, const int* __restrict__ idxt,
    const _Float16* __restrict__ Bh, const _Float16* __restrict__ Bl,
    const float* __restrict__ bd1, const float* __restrict__ u512,
    const float* __restrict__ bd2, float* __restrict__ w, int Spairs)
{
    __shared__ __align__(16) _Float16 lds[2][8192];   // 32 KB
    const int t = threadIdx.x, wave = t >> 6, lane = t & 63;
    const int bm = blockIdx.x * 64, ncol0 = blockIdx.y * 64;
    const int rsub = lane >> 2, seg = lane & 3;
    const int fm = lane & 15, quad = lane >> 4, fko = quad * 8;

    size_t lb, rb;
    {
        const int rowm = bm + wave*16 + rsub;
        int lrow, rrow;
        if (MODE == 0) {
            const int n = rowm / 31, s = rowm - n * 31;
            lrow = n*32 + s; rrow = lrow + 1;
        } else {
            const int nk = rowm >> 1, slot = rowm & 1;
            const int s = posb[nk];
            int jw = s - 1 + slot;
            int jc = jw < 0 ? 0 : (jw > Spairs - 1 ? Spairs - 1 : jw);
            lrow = idxt[nk*31 + jc]; rrow = idxt[nk*31 + jc + 1];
        }
        lb = (size_t)lrow * 512; rb = (size_t)rrow * 512;
    }
    const size_t bbase = (size_t)(ncol0 + wave*16 + rsub) * 1024;

    f32x4 acc0[4], acc1[4];
    #pragma unroll
    for (int j = 0; j < 4; ++j) {
        acc0[j] = (f32x4){0.f, 0.f, 0.f, 0.f};
        acc1[j] = (f32x4){0.f, 0.f, 0.f, 0.f};
    }
    #define STAGE_WS(IT, BUF) {                                                \
        const int k0 = (IT)*32;                                                \
        _Float16* Lb = &lds[BUF][0];                                           \
        const size_t aoff = (k0 < 512 ? lb + k0 : rb + (k0-512)) + seg*8;      \
        gload_lds16(ch + aoff, Lb + 0*2048 + wave*512);                        \
        gload_lds16(cl + aoff, Lb + 1*2048 + wave*512);                        \
        gload_lds16(Bh + bbase + k0 + seg*8, Lb + 2*2048 + wave*512);          \
        gload_lds16(Bl + bbase + k0 + seg*8, Lb + 3*2048 + wave*512); }

    STAGE_WS(0, 0);
    for (int it = 0; it < 32; ++it) {
        __syncthreads();
        if (it + 1 < 32) STAGE_WS(it + 1, (it + 1) & 1);
        const _Float16* L = &lds[it & 1][0];
        const int ar = wave*16 + fm;
        f16x8 ah = *(const f16x8*)&L[0*2048 + ar*32 + fko];
        f16x8 al = *(const f16x8*)&L[1*2048 + ar*32 + fko];
        #pragma unroll
        for (int j = 0; j < 4; ++j) {
            const int br = j*16 + fm;
            f16x8 bh = *(const f16x8*)&L[2*2048 + br*32 + fko];
            f16x8 bl = *(const f16x8*)&L[3*2048 + br*32 + fko];
            acc0[j] = __builtin_amdgcn_mfma_f32_16x16x32_f16(ah, bh, acc0[j], 0, 0, 0);
            acc1[j] = __builtin_amdgcn_mfma_f32_16x16x32_f16(ah, bl, acc1[j], 0, 0, 0);
            acc1[j] = __builtin_amdgcn_mfma_f32_16x16x32_f16(al, bh, acc1[j], 0, 0, 0);
        }
    }
    float part[4] = {0.f, 0.f, 0.f, 0.f};
    #pragma unroll
    for (int j = 0; j < 4; ++j) {
        const int col = ncol0 + j*16 + fm;
        const float bv = bd1[col], uv = u512[col];
        #pragma unroll
        for (int r = 0; r < 4; ++r) {
            float v = acc0[j][r] + acc1[j][r] * RINV + bv;
            part[r] += gelu_f(v) * uv;
        }
    }
    #pragma unroll
    for (int r = 0; r < 4; ++r) {
        float s = part[r];
        s += __shfl_xor(s, 1); s += __shfl_xor(s, 2);
        s += __shfl_xor(s, 4); s += __shfl_xor(s, 8);
        part[r] = s;
    }
    if (fm == 0) {
        const float bd2v = (blockIdx.y == 0) ? bd2[0] : 0.f;
        #pragma unroll
        for (int r = 0; r < 4; ++r) {
            const int rowm = bm + wave*16 + quad*4 + r;
            int wi = -1;
            if (MODE == 0) {
                const int n = rowm / 31, s = rowm - n * 31;
                wi = n * BEAM * S0 + s;
            } else {
                const int nk = rowm >> 1, slot = rowm & 1;
                const int jw = posb[nk] - 1 + slot;
                if (jw >= 0 && jw < Spairs) wi = nk * S0 + jw;
            }
            if (wi >= 0) atomicAdd(&w[wi], part[r] + bd2v);
        }
    }
    #undef STAGE_WS
}

// ============ weight transpose + fp16 split ============
__global__ __launch_bounds__(256) void k_tsplit(
    const float* __restrict__ in, _Float16* __restrict__ oh,
    _Float16* __restrict__ ol, int K, int N)
{
    __shared__ float tile[32][33];
    const int bx = blockIdx.x * 32, by = blockIdx.y * 32;
    const int t = threadIdx.x, r = t >> 5, c = t & 31;
    #pragma unroll
    for (int p = 0; p < 4; ++p)
        tile[r + p*8][c] = in[(size_t)(by + r + p*8) * N + bx + c];
    __syncthreads();
    #pragma unroll
    for (int p = 0; p < 4; ++p) {
        const int nl = r + p*8;
        float v = tile[c][nl];
        _Float16 h = hi16(v);
        oh[(size_t)(bx + nl) * K + by + c] = h;
        ol[(size_t)(bx + nl) * K + by + c] = lo16(v, h);
    }
}

// ============ elementwise fp16 split (x rows, init only) ============
__global__ __launch_bounds__(256) void k_xsplit(
    const float* __restrict__ in, _Float16* __restrict__ oh,
    _Float16* __restrict__ ol)
{
    const size_t i = ((size_t)blockIdx.x * 256 + threadIdx.x) * 4;
    float4 v = *(const float4*)(in + i);
    _Float16 h0 = hi16(v.x), h1 = hi16(v.y), h2 = hi16(v.z), h3 = hi16(v.w);
    typedef __attribute__((ext_vector_type(4))) _Float16 f16x4v;
    f16x4v h = {h0, h1, h2, h3};
    f16x4v l = {lo16(v.x,h0), lo16(v.y,h1), lo16(v.z,h2), lo16(v.w,h3)};
    *(f16x4v*)(oh + i) = h;
    *(f16x4v*)(ol + i) = l;
}

// ============ init layernorm -> split arena rows ============
__global__ __launch_bounds__(256) void k_ln_init(
    const float* __restrict__ y, const float* __restrict__ g,
    const float* __restrict__ b, _Float16* __restrict__ cha,
    _Float16* __restrict__ cla)
{
    const int row = blockIdx.x;
    const float* yr = y + (size_t)row * DD;
    const int t = threadIdx.x;
    float v0 = yr[t], v1 = yr[t + 256];
    __shared__ float sb[8];
    float s1 = block_reduce_sum(v0 + v1, sb);
    float s2 = block_reduce_sum(v0*v0 + v1*v1, sb);
    float mu = s1 * (1.f/512.f);
    float rstd = rsqrtf(s2 * (1.f/512.f) - mu*mu + 1e-5f);
    float a0 = (v0 - mu) * rstd * g[t]       + b[t];
    float a1 = (v1 - mu) * rstd * g[t + 256] + b[t + 256];
    _Float16 h0 = hi16(a0), h1 = hi16(a1);
    cha[(size_t)row*DD + t]       = h0;
    cla[(size_t)row*DD + t]       = lo16(a0, h0);
    cha[(size_t)row*DD + t + 256] = h1;
    cla[(size_t)row*DD + t + 256] = lo16(a1, h1);
}

__global__ void k_init_state(float* accu, float* bm, int* idx0, float* wz) {
    int i = blockIdx.x * blockDim.x + threadIdx.x;
    if (i < NB*S0) wz[i] = 0.f;
    if (i < AR_INIT) idx0[i] = i;
    if (i < NB) { accu[i] = 0.f; bm[i] = 1.f; }
}

// ====== top-k + LANE-PARALLEL beam select + cache gather + l/r row ids ======
__global__ __launch_bounds__(64) void k_topk(
    const float* __restrict__ w, const float* __restrict__ accu,
    const float* __restrict__ bmask, const float* __restrict__ maskg,
    int iiter, int B, int S, int topk, int do_bsel,
    const int* __restrict__ idxold, int BAo, int STo,
    int* __restrict__ parent, int* __restrict__ posb,
    int* __restrict__ lrid, int* __restrict__ rrid,
    float* __restrict__ accu_out, float* __restrict__ bm_out,
    float* __restrict__ wnew, int Snew, int dow)
{
    const int n = blockIdx.x, lane = threadIdx.x;
    __shared__ int   selpos_s[BEAM][BEAM];
    __shared__ float nscore_s[BEAM][BEAM];
    __shared__ int   par_s[BEAM], pos_s[BEAM];
    const float* mrow = maskg + n*S0 + (iiter + 1);
    const float mk   = (lane < S) ? mrow[lane] : 0.f;
    const float done = 1.f - mrow[0];
    for (int b = 0; b < B; ++b) {
        float ml;
        if (lane < S) {
            float wv = w[(n*BEAM + b)*S0 + lane];
            ml = (mk > 0.f) ? wv : -1e9f;
        } else ml = -INFINITY;
        float mx = ml;
        #pragma unroll
        for (int o = 32; o > 0; o >>= 1) mx = fmaxf(mx, __shfl_xor(mx, o));
        float e = (lane < S) ? expf(ml - mx) * mk : 0.f;
        float es = e;
        #pragma unroll
        for (int o = 32; o > 0; o >>= 1) es += __shfl_xor(es, o);
        const float den = es + 1e-20f;
        float mlc = ml;
        for (int ts = 0; ts < topk; ++ts) {
            unsigned int fb = __float_as_uint(mlc);
            unsigned int ok = (fb & 0x80000000u) ? ~fb : (fb | 0x80000000u);
            unsigned long long key =
                ((unsigned long long)ok << 32) | (unsigned int)(63 - lane);
            if (lane >= S) key = 0ull;
            unsigned long long km = key;
            #pragma unroll
            for (int o = 32; o > 0; o >>= 1) {
                unsigned long long oth = __shfl_xor(km, o);
                km = (oth > km) ? oth : km;
            }
            int sidx = 63 - (int)(km & 0xffffffffull);
            float esel = __shfl(e, sidx);
            if (lane == 0) {
                selpos_s[b][ts] = sidx;
                nscore_s[b][ts] = logf(esel / den + 1e-20f);
            }
            if (lane == sidx) mlc = -INFINITY;
        }
    }
    __syncthreads();
    // ---- beam select: candidate c lives in lane c (C = B*topk <= 25) ----
    // Key max = value desc, index asc on ties — matches the serial strict->
    // first-index-wins loop exactly.
    {
        const int C = B * topk;
        float ac = 0.f, bc = 0.f;
        if (lane < C) {
            const int pb = lane / topk, ptt = lane - pb * topk;
            ac = accu[n*BEAM + pb] + nscore_s[pb][ptt];
            const float nb = done * ((ptt == 0) ? 1.f : 0.f) + (1.f - done);
            bc = bmask[n*BEAM + pb] * nb;
        }
        bool used = false;
        for (int k = 0; k < BEAM; ++k) {
            int bestc;
            if (do_bsel) {
                const float v = (lane < C && !used)
                                ? ((bc > 0.f) ? ac : -1e9f) : -INFINITY;
                unsigned fb = __float_as_uint(v);
                unsigned ok = (fb & 0x80000000u) ? ~fb : (fb | 0x80000000u);
                unsigned long long key =
                    ((unsigned long long)ok << 32) | (unsigned)(63 - lane);
                unsigned long long km = key;
                #pragma unroll
                for (int o = 32; o > 0; o >>= 1) {
                    unsigned long long oth = __shfl_xor(km, o);
                    km = (oth > km) ? oth : km;
                }
                bestc = 63 - (int)(km & 0xffffffffull);
            } else bestc = k;
            if (lane == bestc) used = true;
            const float av  = __shfl(ac, bestc);
            const float bv2 = __shfl(bc, bestc);
            const int pp = bestc / topk, ss = selpos_s[pp][bestc - pp * topk];
            if (lane == 0) {
                parent[n*BEAM + k] = pp;
                posb[n*BEAM + k]   = ss;
                par_s[k] = pp; pos_s[k] = ss;
                accu_out[n*BEAM + k] = av;
                bm_out[n*BEAM + k]   = bv2;
            }
        }
    }
    __syncthreads();
    if (lane < BEAM) {
        const int base = (n*BAo + par_s[lane]) * STo + pos_s[lane];
        lrid[n*BEAM + lane] = idxold[base];
        rrid[n*BEAM + lane] = idxold[base + 1];
    }
    if (dow) {
        for (int k = 0; k < BEAM; ++k) {
            const int p = par_s[k], s = pos_s[k];
            if (lane < Snew) {
                float v = 0.f;
                if (lane < s - 1)      v = w[(n*BEAM + p)*S0 + lane];
                else if (lane > s)     v = w[(n*BEAM + p)*S0 + lane + 1];
                wnew[(n*BEAM + k)*S0 + lane] = v;
            }
        }
    }
}

// ======== compose: sum 4 partials + gate softmax + mix + LN -> arena ========
__global__ __launch_bounds__(256) void k_compose(
    const float* __restrict__ P,
    const _Float16* __restrict__ cha_r, const _Float16* __restrict__ cla_r,
    const int* __restrict__ lrid, const int* __restrict__ rrid,
    const int* __restrict__ parent, const int* __restrict__ posb,
    const int* __restrict__ idxold, int BAo, int STo,
    const float* __restrict__ maskg, int iiter, int Spnew,
    const float* __restrict__ gp, const float* __restrict__ bp,
    _Float16* __restrict__ cha_w, _Float16* __restrict__ cla_w, int newbase,
    int* __restrict__ idxnew, int finalflag, float* __restrict__ nvout)
{
    __shared__ float sb[8];
    const int nk = blockIdx.x, t = threadIdx.x;
    const int n = nk / BEAM;
    size_t lbase, rbase;
    if (finalflag) {
        lbase = (size_t)idxold[nk*31 + 0] * 512;
        rbase = (size_t)idxold[nk*31 + 1] * 512;
    } else {
        lbase = (size_t)lrid[nk] * 512;
        rbase = (size_t)rrid[nk] * 512;
    }
    const float* c = P + (size_t)nk * CHID;
    float o[2];
    #pragma unroll
    for (int e = 0; e < 2; ++e) {
        const int d = t + 256*e;
        const float lv = recon(cha_r[lbase + d], cla_r[lbase + d]);
        const float rv = recon(cha_r[rbase + d], cla_r[rbase + d]);
        float c0 = ((c[d]        + c[MN2 + d])        + c[2*MN2 + d])        + c[3*MN2 + d];
        float c1 = ((c[DD + d]   + c[MN2 + DD + d])   + c[2*MN2 + DD + d])   + c[3*MN2 + DD + d];
        float c2 = ((c[2*DD + d] + c[MN2 + 2*DD + d]) + c[2*MN2 + 2*DD + d]) + c[3*MN2 + 2*DD + d];
        float c3 = ((c[3*DD + d] + c[MN2 + 3*DD + d]) + c[2*MN2 + 3*DD + d]) + c[3*MN2 + 3*DD + d];
        float m = fmaxf(c0, fmaxf(c1, c2));
        float e0 = expf(c0 - m), e1 = expf(c1 - m), e2 = expf(c2 - m);
        float inv = 1.f / (e0 + e1 + e2);
        o[e] = (e0*lv + e1*rv + e2*c3) * inv;
    }
    float s1 = block_reduce_sum(o[0] + o[1], sb);
    float s2 = block_reduce_sum(o[0]*o[0] + o[1]*o[1], sb);
    float mu = s1 * (1.f/512.f);
    float rstd = rsqrtf(s2 * (1.f/512.f) - mu*mu + 1e-5f);
    if (finalflag) {
        #pragma unroll
        for (int e = 0; e < 2; ++e) {
            const int d = t + 256*e;
            nvout[(size_t)nk*DD + d] = (o[e] - mu) * rstd * gp[d] + bp[d];
        }
        return;
    }
    const int arow = newbase + nk;
    #pragma unroll
    for (int e = 0; e < 2; ++e) {
        const int d = t + 256*e;
        float v = (o[e] - mu) * rstd * gp[d] + bp[d];
        _Float16 h = hi16(v);
        cha_w[(size_t)arow*512 + d] = h;
        cla_w[(size_t)arow*512 + d] = lo16(v, h);
    }
    if (t < Spnew) {
        const float done = maskg[n*S0 + iiter + 1];
        const int p = parent[nk], s = posb[nk];
        const int src = (n*BAo + p) * STo;
        int val;
        if (done > 0.5f)
            val = (t < s) ? idxold[src + t] : (t == s ? arow : idxold[src + t + 1]);
        else
            val = idxold[src + t];
        idxnew[nk*31 + t] = val;
    }
}

// ============ final beam softmax mix ============
__global__ __launch_bounds__(256) void k_final(
    const float* __restrict__ nv,
    const _Float16* __restrict__ cha, const _Float16* __restrict__ cla,
    const int* __restrict__ idxt, const float* __restrict__ maskg,
    const float* __restrict__ accu, const float* __restrict__ bmv,
    float* __restrict__ out)
{
    const int n = blockIdx.x, t = threadIdx.x;
    const float done = maskg[n*S0 + 31];
    float sc[BEAM];
    #pragma unroll
    for (int k = 0; k < BEAM; ++k) {
        float m = bmv[n*BEAM + k];
        sc[k] = m * accu[n*BEAM + k] + (1.f - m) * (-999999.f);
    }
    float mx = sc[0];
    #pragma unroll
    for (int k = 1; k < BEAM; ++k) mx = fmaxf(mx, sc[k]);
    float e[BEAM], den = 0.f;
    #pragma unroll
    for (int k = 0; k < BEAM; ++k) { e[k] = expf(sc[k] - mx); den += e[k]; }
    const float inv = 1.f / den;
    #pragma unroll
    for (int i2 = 0; i2 < 2; ++i2) {
        const int d = t + 256*i2;
        float s = 0.f;
        #pragma unroll
        for (int k = 0; k < BEAM; ++k) {
            const int nk = n*BEAM + k;
            const size_t ob = (size_t)idxt[nk*31] * 512;
            const float nvv  = nv[(size_t)nk*DD + d];
            const float oldv = recon(cha[ob + d], cla[ob + d]);
            s += e[k]*inv * (done*nvv + (1.f - done)*oldv);
        }
        out[(size_t)n*DD + d] = s;
    }
}

extern "C" void kernel_launch(void* const* d_in, const int* in_sizes, int n_in,
                              void* d_out, int out_size, void* d_ws, size_t ws_size,
                              hipStream_t stream) {
    (void)in_sizes; (void)n_in; (void)out_size; (void)ws_size;
    const float* x    = (const float*)d_in[0];
    const float* mask = (const float*)d_in[1];
    const float* Wi   = (const float*)d_in[2];
    const float* bi   = (const float*)d_in[3];
    const float* g1   = (const float*)d_in[4];
    const float* b1   = (const float*)d_in[5];
    const float* Wd1  = (const float*)d_in[6];
    const float* bd1  = (const float*)d_in[7];
    const float* Wd2  = (const float*)d_in[8];
    const float* bd2  = (const float*)d_in[9];
    const float* Wc1  = (const float*)d_in[10];
    const float* bc1  = (const float*)d_in[11];
    const float* Wc2  = (const float*)d_in[12];
    const float* bc2  = (const float*)d_in[13];
    const float* g2   = (const float*)d_in[14];
    const float* b2   = (const float*)d_in[15];
    float* out = (float*)d_out;

    // ---- workspace carve-up (bytes), ~185 MB ----
    char* p = (char*)d_ws;
    _Float16* cha = (_Float16*)p;        p += (size_t)AR_TOT*512*2;
    _Float16* cla = (_Float16*)p;        p += (size_t)AR_TOT*512*2;
    _Float16* Wc1th = (_Float16*)p;      p += (size_t)CHID*1024*2;
    _Float16* Wc1tl = (_Float16*)p;      p += (size_t)CHID*1024*2;
    _Float16* Wc2th = (_Float16*)p;      p += (size_t)CHID*CHID*2;
    _Float16* Wc2tl = (_Float16*)p;      p += (size_t)CHID*CHID*2;
    _Float16* Wd1th = (_Float16*)p;      p += (size_t)512*1024*2;
    _Float16* Wd1tl = (_Float16*)p;      p += (size_t)512*1024*2;
    _Float16* Wih = (_Float16*)p;        p += (size_t)WDIM*DD*2;
    _Float16* Wil = (_Float16*)p;        p += (size_t)WDIM*DD*2;
    _Float16* Hh  = (_Float16*)p;        p += (size_t)NB*CHID*2;
    _Float16* Hl  = (_Float16*)p;        p += (size_t)NB*CHID*2;
    float* Pb   = (float*)p;             p += MN2*4*4;                // 4 slices
    float* nvb  = (float*)p;             p += (size_t)NB*DD*4;
    float* wA   = (float*)p;             p += (size_t)NB*S0*4;
    float* wB   = (float*)p;             p += (size_t)NB*S0*4;
    float* accA = (float*)p;             p += NB*4;
    float* accB = (float*)p;             p += NB*4;
    float* bmA  = (float*)p;             p += NB*4;
    float* bmB  = (float*)p;             p += NB*4;
    int* parent = (int*)p;               p += NB*4;
    int* posb   = (int*)p;               p += NB*4;
    int* lrid   = (int*)p;               p += NB*4;
    int* rrid   = (int*)p;               p += NB*4;
    int* idx0   = (int*)p;               p += AR_INIT*4;
    int* idxA   = (int*)p;               p += NB*31*4;
    int* idxB   = (int*)p;               p += NB*31*4;
    // init-only aliases inside Pb
    _Float16* xh = (_Float16*)Pb;
    _Float16* xl = (_Float16*)((char*)Pb + (size_t)AR_INIT*512*2);
    float* ybuf  = (float*)((char*)Pb + (size_t)AR_INIT*512*4);

    // ---- prep ----
    k_tsplit<<<dim3(CHID/32, 1024/32), 256, 0, stream>>>(Wc1, Wc1th, Wc1tl, 1024, CHID);
    k_tsplit<<<dim3(CHID/32, CHID/32), 256, 0, stream>>>(Wc2, Wc2th, Wc2tl, CHID, CHID);
    k_tsplit<<<dim3(512/32, 1024/32), 256, 0, stream>>>(Wd1, Wd1th, Wd1tl, 1024, 512);
    k_tsplit<<<dim3(DD/32, WDIM/32), 256, 0, stream>>>(Wi, Wih, Wil, WDIM, DD);
    k_init_state<<<(NB*S0 + 255)/256, 256, 0, stream>>>(accA, bmA, idx0, wA);

    // ---- init: arena rows 0..8191 = LN(x@Wi+bi) ----
    k_xsplit<<<(AR_INIT*WDIM)/1024, 256, 0, stream>>>(x, xh, xl);
    k_gemm<0><<<dim3(DD/128, AR_INIT/128, 1), 256, 0, stream>>>(
        xh, xl, Wih, Wil, bi, ybuf, AR_INIT, DD, WDIM, WDIM);
    k_ln_init<<<AR_INIT, 256, 0, stream>>>(ybuf, g1, b1, cha, cla);
    k_wscore<0><<<dim3(NN*31/64, 8), 256, 0, stream>>>(
        cha, cla, nullptr, nullptr, Wd1th, Wd1tl, bd1, Wd2, bd2, wA, 31);

    const int* idxcur = idx0;
    int* idxnxt = idxA;
    int BAo = 1, STo = 32;
    float *wcur = wA, *wnxt = wB;
    float *acur = accA, *anxt = accB, *bcur = bmA, *bnxt = bmB;
    for (int i = 0; i < 30; ++i) {
        const int B  = (i == 0) ? 1 : BEAM;
        const int S  = 31 - i;
        const int tk = (S < BEAM) ? S : BEAM;
        const int dob = (B*tk > BEAM) ? 1 : 0;
        const int newbase = AR_INIT + i*NB;
        k_topk<<<NN, 64, 0, stream>>>(wcur, acur, bcur, mask, i, B, S, tk, dob,
                                      idxcur, BAo, STo, parent, posb, lrid, rrid,
                                      anxt, bnxt, wnxt, S - 1, (i < 29) ? 1 : 0);
        k_gemm1<1><<<dim3(CHID/64, NB/128), 256, 0, stream>>>(
            cha, cla, Wc1th, Wc1tl, bc1, Hh, Hl, lrid, rrid, nullptr, CHID);
        k_gemm<0><<<dim3(CHID/128, NB/128, 4), 256, 0, stream>>>(
            Hh, Hl, Wc2th, Wc2tl, bc2, Pb, NB, CHID, CHID, 512);
        k_compose<<<NB, 256, 0, stream>>>(Pb, cha, cla, lrid, rrid, parent, posb,
                                          idxcur, BAo, STo, mask, i, 31 - i,
                                          g2, b2, cha, cla, newbase, idxnxt,
                                          0, nullptr);
        if (i < 29)
            k_wscore<1><<<dim3(NB*2/64, 8), 256, 0, stream>>>(
                cha, cla, posb, idxnxt, Wd1th, Wd1tl, bd1, Wd2, bd2, wnxt, S - 1);
        idxcur = idxnxt;
        idxnxt = (idxnxt == idxA) ? idxB : idxA;
        BAo = BEAM; STo = 31;
        float* tp;
        tp = wcur; wcur = wnxt; wnxt = tp;
        tp = acur; acur = anxt; anxt = tp;
        tp = bcur; bcur = bnxt; bnxt = tp;
    }
    // final compose: l,r = table positions 0,1
    k_gemm1<2><<<dim3(CHID/64, NB/128), 256, 0, stream>>>(
        cha, cla, Wc1th, Wc1tl, bc1, Hh, Hl, nullptr, nullptr, idxcur, CHID);
    k_gemm<0><<<dim3(CHID/128, NB/128, 4), 256, 0, stream>>>(
        Hh, Hl, Wc2th, Wc2tl, bc2, Pb, NB, CHID, CHID, 512);
    k_compose<<<NB, 256, 0, stream>>>(Pb, cha, cla, nullptr, nullptr, parent, posb,
                                      idxcur, BEAM, 31, mask, 30, 0,
                                      g2, b2, nullptr, nullptr, 0,
                                      nullptr, 1, nvb);
    k_final<<<NN, 256, 0, stream>>>(nvb, cha, cla, idxcur, mask, acur, bcur, out);
}